// Round 8
// baseline (806.286 us; speedup 1.0000x reference)
//
#include <hip/hip_runtime.h>
#include <math.h>

// Problem constants
constexpr int cB   = 4;
constexpr int cT   = 16;
constexpr int cP   = 256;
constexpr int cE   = 768;
constexpr int cH   = 12;
constexpr int cD   = 64;
constexpr int cDFF = 3072;
constexpr int NTOK = cB * cT * cP;        // 16384
constexpr float cSCALE = 0.125f;          // 64^-0.5
constexpr float cEPS = 1e-5f;

typedef __attribute__((ext_vector_type(8))) short short8;
typedef __attribute__((ext_vector_type(4))) float f32x4;
typedef __attribute__((ext_vector_type(8))) unsigned short u16x8;
typedef __attribute__((ext_vector_type(4))) unsigned short u16x4;

#define AS1 __attribute__((address_space(1)))
#define AS3 __attribute__((address_space(3)))

__device__ inline float b2f(unsigned short u) {
    union { unsigned int i; float f; } c; c.i = ((unsigned int)u) << 16; return c.f;
}
__device__ inline unsigned short f2b(float f) {
    union { float f; unsigned int i; } c; c.f = f;
    unsigned int i = c.i;
    unsigned int r = i + 0x7FFFu + ((i >> 16) & 1u);   // RNE
    return (unsigned short)(r >> 16);
}

__device__ inline void gload16(const unsigned short* g, short* l) {
    __builtin_amdgcn_global_load_lds((AS1 const void*)g, (AS3 void*)l, 16, 0, 0);
}

// ---------------------------------------------------------------------------
// 256x128 3-deep-pipelined MFMA GEMM: C = A[M,K](bf16) @ BT[N,K]^T(bf16) + bias
// BK=64, 512 threads (8 waves, 4M x 2N, 64x64 out per wave), 3 LDS buffers.
// BLOCK ORDER (round 8 change): bn-MAJOR after XCD chunking -> each XCD works
// on ~3 N-panels (B-panel ~0.6 MB, L2-resident) sweeping all M; A streams
// from L3. Fixes 4.3x HBM over-fetch of weights (129 MB vs 30 MB ideal).
// T2 both-sides swizzle; T5 setprio; vmcnt(6) counted waits; 1 barrier/K-tile.
// SPLIT3: N=2304 QKV fusion (128 | 768, so col-block uniform).
// OUTB: 1 -> bf16 out, 0 -> fp32 out.  ACT: 1 -> exact GELU.
// ---------------------------------------------------------------------------
template<int OUTB, int ACT, int SPLIT3>
__global__ __launch_bounds__(512, 2) void gemm256_kernel(
    const unsigned short* __restrict__ A,   // [M][K] bf16
    const unsigned short* __restrict__ BT,  // [N][K] bf16
    const float* __restrict__ bias0, const float* __restrict__ bias1,
    const float* __restrict__ bias2,
    void* __restrict__ C0, void* __restrict__ C1, void* __restrict__ C2,
    int M, int N, int K, int nbm)
{
    __shared__ short LDS[3 * 24576];   // 144 KiB: 3 x (A[256][64] + B[128][64])

    const int tid = threadIdx.x;
    const int w = tid >> 6, l = tid & 63;
    const int l15 = l & 15, l16 = l >> 4;
    const int wm = w >> 1, wn = w & 1;      // 4 M-waves x 2 N-waves
    const int srow = l >> 3;                // staging: row-in-group 0..7
    const int sslot = l & 7;                // staging: 16B slot 0..7

    // bijective XCD swizzle (nwg % 8 == 0), then bn-MAJOR decomposition:
    // consecutive wg share bn (weight panel stays in this XCD's L2).
    const int nwg = gridDim.x;
    const int wg = (blockIdx.x & 7) * (nwg >> 3) + (blockIdx.x >> 3);
    const int bn = wg / nbm, bm = wg % nbm;
    const int m0 = bm * 256, n0 = bn * 128;

    const unsigned short* pA = A + (size_t)m0 * K;
    const unsigned short* pB = BT + (size_t)n0 * K;

    f32x4 acc[4][4];
    #pragma unroll
    for (int i = 0; i < 4; ++i)
        #pragma unroll
        for (int j = 0; j < 4; ++j)
            #pragma unroll
            for (int r = 0; r < 4; ++r) acc[i][j][r] = 0.f;

    const int nt = K >> 6;

    // ---- staging: linear LDS dest (lane*16B), inverse-swizzled global col ----
    #define STAGE_A(t_, buf_)                                                   \
        {                                                                       \
            const unsigned short* src_ = pA + (t_) * 64;                        \
            short* dst_ = LDS + (buf_) * 24576;                                 \
            _Pragma("unroll")                                                   \
            for (int j_ = 0; j_ < 4; ++j_) {                                    \
                const int r_ = w * 32 + j_ * 8 + srow;                          \
                gload16(src_ + (size_t)r_ * K + ((sslot ^ (r_ & 7)) << 3),      \
                        dst_ + r_ * 64 + (sslot << 3));                         \
            }                                                                   \
        }
    #define STAGE_B(t_, buf_)                                                   \
        {                                                                       \
            const unsigned short* src_ = pB + (t_) * 64;                        \
            short* dst_ = LDS + (buf_) * 24576 + 16384;                         \
            _Pragma("unroll")                                                   \
            for (int j_ = 0; j_ < 2; ++j_) {                                    \
                const int r_ = w * 8 + j_ * 64 + srow;                          \
                gload16(src_ + (size_t)r_ * K + ((sslot ^ (r_ & 7)) << 3),      \
                        dst_ + r_ * 64 + (sslot << 3));                         \
            }                                                                   \
        }

    // prologue: stage tiles 0 and 1; wait for tile 0 (6 newest stay in flight)
    STAGE_A(0, 0); STAGE_B(0, 0);
    STAGE_A(1, 1); STAGE_B(1, 1);
    asm volatile("s_waitcnt vmcnt(6)" ::: "memory");
    __builtin_amdgcn_s_barrier();

    int buf = 0;
    for (int t = 0; t < nt; ++t) {
        const short* bA = LDS + buf * 24576;
        const short* bB = bA + 16384;

        short8 aF[4][2], bF[4][2];
        // kk0 fragment reads (8 ds_read_b128)
        #pragma unroll
        for (int mm = 0; mm < 4; ++mm) {
            const int ra = wm * 64 + mm * 16 + l15;
            const char* pa = (const char*)bA + ra * 128;
            aF[mm][0] = *(const short8*)(pa + ((l16 * 16) ^ ((ra & 7) << 4)));
        }
        #pragma unroll
        for (int nf = 0; nf < 4; ++nf) {
            const int rb = wn * 64 + nf * 16 + l15;
            const char* pb = (const char*)bB + rb * 128;
            bF[nf][0] = *(const short8*)(pb + ((l16 * 16) ^ ((rb & 7) << 4)));
        }
        __builtin_amdgcn_sched_barrier(0);   // pin kk0-group issue order
        // kk1 fragment reads (8 ds_read_b128)
        #pragma unroll
        for (int mm = 0; mm < 4; ++mm) {
            const int ra = wm * 64 + mm * 16 + l15;
            const char* pa = (const char*)bA + ra * 128;
            aF[mm][1] = *(const short8*)(pa + ((64 + l16 * 16) ^ ((ra & 7) << 4)));
        }
        #pragma unroll
        for (int nf = 0; nf < 4; ++nf) {
            const int rb = wn * 64 + nf * 16 + l15;
            const char* pb = (const char*)bB + rb * 128;
            bF[nf][1] = *(const short8*)(pb + ((64 + l16 * 16) ^ ((rb & 7) << 4)));
        }

        // stage tile t+2 into the buffer freed at the end of tile t-1
        if (t + 2 < nt) {
            const int b2 = (buf == 0) ? 2 : buf - 1;
            STAGE_A(t + 2, b2); STAGE_B(t + 2, b2);
        }

        asm volatile("s_waitcnt lgkmcnt(8)" ::: "memory");   // kk0 frags ready
        __builtin_amdgcn_sched_barrier(0);
        __builtin_amdgcn_s_setprio(1);
        #pragma unroll
        for (int nf = 0; nf < 4; ++nf)
            #pragma unroll
            for (int mm = 0; mm < 4; ++mm)
                acc[mm][nf] = __builtin_amdgcn_mfma_f32_16x16x32_bf16(
                    aF[mm][0], bF[nf][0], acc[mm][nf], 0, 0, 0);
        __builtin_amdgcn_s_setprio(0);
        asm volatile("s_waitcnt lgkmcnt(0)" ::: "memory");   // kk1 frags ready
        __builtin_amdgcn_sched_barrier(0);
        __builtin_amdgcn_s_setprio(1);
        #pragma unroll
        for (int nf = 0; nf < 4; ++nf)
            #pragma unroll
            for (int mm = 0; mm < 4; ++mm)
                acc[mm][nf] = __builtin_amdgcn_mfma_f32_16x16x32_bf16(
                    aF[mm][1], bF[nf][1], acc[mm][nf], 0, 0, 0);
        __builtin_amdgcn_s_setprio(0);

        if (t + 1 < nt) {
            // retire tile t+1's loads; keep tile t+2's 6 in flight (counted!)
            if (t + 2 < nt)
                asm volatile("s_waitcnt vmcnt(6)" ::: "memory");
            else
                asm volatile("s_waitcnt vmcnt(0)" ::: "memory");
            __builtin_amdgcn_s_barrier();
        }
        buf = (buf == 2) ? 0 : buf + 1;
    }
    #undef STAGE_A
    #undef STAGE_B

    // ---- epilogue: C/D layout col = lane&15, row = (lane>>4)*4 + reg ----
    #pragma unroll
    for (int mf = 0; mf < 4; ++mf) {
        #pragma unroll
        for (int nf = 0; nf < 4; ++nf) {
            const int ng = n0 + wn * 64 + nf * 16 + l15;
            int nl = ng;
            const float* bp = bias0;
            void* Cp = C0;
            int Nout = N;
            if (SPLIT3) {
                const int which = ng / 768;      // uniform per block (128 | 768)
                nl = ng - which * 768;
                bp = (which == 0) ? bias0 : (which == 1) ? bias1 : bias2;
                Cp = (which == 0) ? C0 : (which == 1) ? C1 : C2;
                Nout = 768;
            }
            const float bs = bp[nl];
            #pragma unroll
            for (int r = 0; r < 4; ++r) {
                const int row = m0 + wm * 64 + mf * 16 + l16 * 4 + r;
                float v = acc[mf][nf][r] + bs;
                if (ACT) v = 0.5f * v * (1.f + erff(v * 0.70710678118654752f));
                if (OUTB) ((unsigned short*)Cp)[(size_t)row * Nout + nl] = f2b(v);
                else      ((float*)Cp)[(size_t)row * Nout + nl] = v;
            }
        }
    }
}

// ---------------------------------------------------------------------------
// weight prep: W[K][N] fp32 -> WT[N][K] bf16  (32x32 LDS tile transpose)
// ---------------------------------------------------------------------------
__global__ __launch_bounds__(256) void transpose_cast_kernel(
    const float* __restrict__ W, unsigned short* __restrict__ WT,
    int K, int N)
{
    __shared__ float t[32][33];
    const int k0 = blockIdx.y * 32;
    const int n0 = blockIdx.x * 32;
    const int tx = threadIdx.x & 31;
    const int ty4 = (threadIdx.x >> 5) << 2;
    #pragma unroll
    for (int i = 0; i < 4; ++i)
        t[ty4 + i][tx] = W[(size_t)(k0 + ty4 + i) * N + n0 + tx];
    __syncthreads();
    #pragma unroll
    for (int i = 0; i < 4; ++i)
        WT[(size_t)(n0 + ty4 + i) * K + k0 + tx] = f2b(t[tx][ty4 + i]);
}

// fused prep for the 8 E x E attention weights (grid.z selects weight)
struct TP8 { const float* src[8]; unsigned short* dst[8]; };
__global__ __launch_bounds__(256) void transpose_cast8_kernel(TP8 p)
{
    __shared__ float t[32][33];
    const int z = blockIdx.z;
    const float* W = p.src[z];
    unsigned short* WT = p.dst[z];
    const int k0 = blockIdx.y * 32;
    const int n0 = blockIdx.x * 32;
    const int tx = threadIdx.x & 31;
    const int ty4 = (threadIdx.x >> 5) << 2;
    #pragma unroll
    for (int i = 0; i < 4; ++i)
        t[ty4 + i][tx] = W[(size_t)(k0 + ty4 + i) * cE + n0 + tx];
    __syncthreads();
    #pragma unroll
    for (int i = 0; i < 4; ++i)
        WT[(size_t)(n0 + ty4 + i) * cE + k0 + tx] = f2b(t[tx][ty4 + i]);
}

// fp32 -> bf16 elementwise (n multiple of 4)
__global__ __launch_bounds__(256) void cast_bf16_kernel(
    const float* __restrict__ in, unsigned short* __restrict__ out, int n4)
{
    for (int i = blockIdx.x * blockDim.x + threadIdx.x; i < n4;
         i += gridDim.x * blockDim.x) {
        float4 v = ((const float4*)in)[i];
        u16x4 o;
        o[0] = f2b(v.x); o[1] = f2b(v.y); o[2] = f2b(v.z); o[3] = f2b(v.w);
        *(u16x4*)(out + (size_t)i * 4) = o;
    }
}

// ---------------------------------------------------------------------------
// residual + layernorm: out = LN(X + R) * gamma + beta  (fp32), optional bf16 copy
// ---------------------------------------------------------------------------
__global__ __launch_bounds__(256) void residual_ln_kernel(
    const float* __restrict__ X, const float* __restrict__ R,
    const float* __restrict__ gamma, const float* __restrict__ beta,
    float* __restrict__ out, unsigned short* __restrict__ outb)
{
    const int row = blockIdx.x;
    const size_t off = (size_t)row * cE;
    const int tid = threadIdx.x;

    float v[3];
    float s = 0.f, ss = 0.f;
    #pragma unroll
    for (int i = 0; i < 3; ++i) {
        const int e = tid + i * 256;
        const float t = X[off + e] + R[off + e];
        v[i] = t; s += t; ss += t * t;
    }
    #pragma unroll
    for (int o = 32; o > 0; o >>= 1) {
        s  += __shfl_down(s, o);
        ss += __shfl_down(ss, o);
    }
    __shared__ float rs[4], rss[4];
    const int wid = tid >> 6;
    if ((tid & 63) == 0) { rs[wid] = s; rss[wid] = ss; }
    __syncthreads();
    s  = rs[0] + rs[1] + rs[2] + rs[3];
    ss = rss[0] + rss[1] + rss[2] + rss[3];

    const float mean = s * (1.f / cE);
    const float var  = ss * (1.f / cE) - mean * mean;
    const float inv  = rsqrtf(var + cEPS);
    #pragma unroll
    for (int i = 0; i < 3; ++i) {
        const int e = tid + i * 256;
        const float r = (v[i] - mean) * inv * gamma[e] + beta[e];
        out[off + e] = r;
        if (outb) outb[off + e] = f2b(r);
    }
}

// ---------------------------------------------------------------------------
// Spatial attention, MFMA flash version (verified round 4).
// ---------------------------------------------------------------------------
__global__ __launch_bounds__(256) void spatial_attn_mfma_kernel(
    const unsigned short* __restrict__ Q, const unsigned short* __restrict__ K,
    const unsigned short* __restrict__ V, unsigned short* __restrict__ O)
{
    __shared__ short Ks[64 * 64];      // [j][d] swizzled, row 128B
    __shared__ short Vt[64 * 64];      // [d][j] swizzled
    __shared__ short Ps[4][64 * 64];   // per-wave [q][j] swizzled

    const int bid = blockIdx.x;        // b*T*H + t*H + h
    const int h  = bid % cH;
    const int bt = bid / cH;
    const size_t base = (size_t)bt * cP * cE + h * cD;

    const int tid = threadIdx.x;
    const int w = tid >> 6, l = tid & 63;
    const int l15 = l & 15, l16 = l >> 4;

    short8 qf[4][2];
    #pragma unroll
    for (int mf = 0; mf < 4; ++mf)
        #pragma unroll
        for (int kf = 0; kf < 2; ++kf)
            qf[mf][kf] = *(const short8*)(
                Q + base + (size_t)(w * 64 + mf * 16 + l15) * cE + kf * 32 + l16 * 8);

    f32x4 o[4][4];
    float mrun[4][4], lrun[4][4];
    #pragma unroll
    for (int mf = 0; mf < 4; ++mf)
        #pragma unroll
        for (int j = 0; j < 4; ++j) {
            #pragma unroll
            for (int r = 0; r < 4; ++r) o[mf][j][r] = 0.f;
            mrun[mf][j] = -INFINITY; lrun[mf][j] = 0.f;
        }

    const int krow = w * 8 + (l >> 3);
    const int kc16 = l & 7;
    const int vj  = tid & 31;
    const int vd0 = (tid >> 5) * 8;

    for (int c0 = 0; c0 < cP; c0 += 64) {
        __syncthreads();
        #pragma unroll
        for (int p = 0; p < 2; ++p) {
            const int row = p * 32 + krow;
            gload16(K + base + (size_t)(c0 + row) * cE + ((kc16 ^ (row & 7)) << 3),
                    Ks + row * 64 + kc16 * 8);
        }
        #pragma unroll
        for (int p = 0; p < 2; ++p) {
            const int j = p * 32 + vj;
            short8 vv = *(const short8*)(V + base + (size_t)(c0 + j) * cE + vd0);
            char* vb = (char*)Vt;
            #pragma unroll
            for (int e = 0; e < 8; ++e) {
                const int row = vd0 + e;
                *(short*)(vb + row * 128 + ((2 * j) ^ ((row & 7) << 4))) = vv[e];
            }
        }
        __syncthreads();

        f32x4 s[4][4];
        #pragma unroll
        for (int mf = 0; mf < 4; ++mf)
            #pragma unroll
            for (int nf = 0; nf < 4; ++nf)
                #pragma unroll
                for (int r = 0; r < 4; ++r) s[mf][nf][r] = 0.f;

        #pragma unroll
        for (int nf = 0; nf < 4; ++nf) {
            const int row = nf * 16 + l15;
            const char* kb = (const char*)Ks + row * 128;
            const int sw = (row & 7) << 4;
            short8 k0 = *(const short8*)(kb + ((l16 * 16) ^ sw));
            short8 k1 = *(const short8*)(kb + ((64 + l16 * 16) ^ sw));
            #pragma unroll
            for (int mf = 0; mf < 4; ++mf) {
                s[mf][nf] = __builtin_amdgcn_mfma_f32_16x16x32_bf16(qf[mf][0], k0, s[mf][nf], 0, 0, 0);
                s[mf][nf] = __builtin_amdgcn_mfma_f32_16x16x32_bf16(qf[mf][1], k1, s[mf][nf], 0, 0, 0);
            }
        }

        #pragma unroll
        for (int mf = 0; mf < 4; ++mf)
            #pragma unroll
            for (int nf = 0; nf < 4; ++nf)
                #pragma unroll
                for (int r = 0; r < 4; ++r) s[mf][nf][r] *= cSCALE;

        #pragma unroll
        for (int mf = 0; mf < 4; ++mf) {
            #pragma unroll
            for (int r = 0; r < 4; ++r) {
                float rv = fmaxf(fmaxf(s[mf][0][r], s[mf][1][r]),
                                 fmaxf(s[mf][2][r], s[mf][3][r]));
                rv = fmaxf(rv, __shfl_xor(rv, 1));
                rv = fmaxf(rv, __shfl_xor(rv, 2));
                rv = fmaxf(rv, __shfl_xor(rv, 4));
                rv = fmaxf(rv, __shfl_xor(rv, 8));
                const float mn = fmaxf(mrun[mf][r], rv);
                const float al = __expf(mrun[mf][r] - mn);
                mrun[mf][r] = mn;
                float ps = 0.f;
                #pragma unroll
                for (int nf = 0; nf < 4; ++nf) {
                    const float pe = __expf(s[mf][nf][r] - mn);
                    s[mf][nf][r] = pe;
                    ps += pe;
                }
                ps += __shfl_xor(ps, 1);
                ps += __shfl_xor(ps, 2);
                ps += __shfl_xor(ps, 4);
                ps += __shfl_xor(ps, 8);
                lrun[mf][r] = lrun[mf][r] * al + ps;
                #pragma unroll
                for (int df = 0; df < 4; ++df) o[mf][df][r] *= al;
            }
        }

        char* pw = (char*)&Ps[w][0];
        #pragma unroll
        for (int mf = 0; mf < 4; ++mf)
            #pragma unroll
            for (int nf = 0; nf < 4; ++nf)
                #pragma unroll
                for (int r = 0; r < 4; ++r) {
                    const int row = mf * 16 + l16 * 4 + r;
                    *(short*)(pw + row * 128 + (((nf * 16 + l15) * 2) ^ ((row & 7) << 4))) =
                        (short)f2b(s[mf][nf][r]);
                }

        short8 pa[4][2];
        #pragma unroll
        for (int mf = 0; mf < 4; ++mf) {
            const int prow = mf * 16 + l15;
            const char* pb = (const char*)&Ps[w][0] + prow * 128;
            const int sw = (prow & 7) << 4;
            pa[mf][0] = *(const short8*)(pb + ((l16 * 16) ^ sw));
            pa[mf][1] = *(const short8*)(pb + ((64 + l16 * 16) ^ sw));
        }
        #pragma unroll
        for (int df = 0; df < 4; ++df) {
            const int vrow = df * 16 + l15;
            const char* vbb = (const char*)Vt + vrow * 128;
            const int sw = (vrow & 7) << 4;
            short8 v0 = *(const short8*)(vbb + ((l16 * 16) ^ sw));
            short8 v1 = *(const short8*)(vbb + ((64 + l16 * 16) ^ sw));
            #pragma unroll
            for (int mf = 0; mf < 4; ++mf) {
                o[mf][df] = __builtin_amdgcn_mfma_f32_16x16x32_bf16(pa[mf][0], v0, o[mf][df], 0, 0, 0);
                o[mf][df] = __builtin_amdgcn_mfma_f32_16x16x32_bf16(pa[mf][1], v1, o[mf][df], 0, 0, 0);
            }
        }
    }

    #pragma unroll
    for (int mf = 0; mf < 4; ++mf)
        #pragma unroll
        for (int r = 0; r < 4; ++r) {
            const float inv = 1.f / lrun[mf][r];
            const size_t rowoff = base + (size_t)(w * 64 + mf * 16 + l16 * 4 + r) * cE;
            #pragma unroll
            for (int df = 0; df < 4; ++df)
                O[rowoff + df * 16 + l15] = f2b(o[mf][df][r] * inv);
        }
}

// ---------------------------------------------------------------------------
// Temporal causal attention (bf16 I/O): per (b,p,head-group of 6). T=16.
// ---------------------------------------------------------------------------
__global__ __launch_bounds__(128) void temporal_attn_kernel(
    const unsigned short* __restrict__ Q, const unsigned short* __restrict__ Kb,
    const unsigned short* __restrict__ V, unsigned short* __restrict__ O)
{
    const int bid = blockIdx.x;          // (b*P + p)*2 + hg
    const int hg  = bid & 1;
    const int bp  = bid >> 1;
    const int p   = bp % cP;
    const int b   = bp / cP;

    __shared__ float Ks[cT][6][cD + 1];
    __shared__ float Vs[cT][6][cD + 1];

    const size_t framestride = (size_t)cP * cE;
    const size_t base0 = ((size_t)(b * cT) * cP + p) * cE + hg * 384;

    for (int li = threadIdx.x; li < cT * 384; li += 128) {
        const int s = li / 384;
        const int r = li % 384;
        const size_t src = base0 + (size_t)s * framestride + r;
        Ks[s][r / 64][r & 63] = b2f(Kb[src]);
        Vs[s][r / 64][r & 63] = b2f(V[src]);
    }
    __syncthreads();
    if (threadIdx.x >= 96) return;

    const int hh = threadIdx.x >> 4;
    const int t  = threadIdx.x & 15;
    const size_t qoff = ((size_t)(b * cT + t) * cP + p) * cE + hg * 384 + hh * cD;

    float q[cD];
    #pragma unroll
    for (int d = 0; d < cD; d += 8) {
        short8 f = *(const short8*)(Q + qoff + d);
        #pragma unroll
        for (int j = 0; j < 8; ++j) q[d + j] = b2f((unsigned short)f[j]);
    }

    float sc[cT];
    float mx = -INFINITY;
    #pragma unroll
    for (int s = 0; s < cT; ++s) {
        float acc = 0.f;
        #pragma unroll
        for (int d = 0; d < cD; ++d) acc = fmaf(q[d], Ks[s][hh][d], acc);
        sc[s] = (s <= t) ? acc * cSCALE : -INFINITY;
        mx = fmaxf(mx, sc[s]);
    }
    float l = 0.f;
    #pragma unroll
    for (int s = 0; s < cT; ++s) {
        const float e_ = __expf(sc[s] - mx);
        sc[s] = e_;
        l += e_;
    }
    float o[cD];
    #pragma unroll
    for (int d = 0; d < cD; ++d) o[d] = 0.f;
    #pragma unroll
    for (int s = 0; s < cT; ++s) {
        const float pj = sc[s];
        #pragma unroll
        for (int d = 0; d < cD; ++d) o[d] = fmaf(pj, Vs[s][hh][d], o[d]);
    }
    const float invl = 1.f / l;
    unsigned short* op = O + qoff;
    #pragma unroll
    for (int d = 0; d < cD; d += 8) {
        u16x8 f;
        #pragma unroll
        for (int j = 0; j < 8; ++j) f[j] = f2b(o[d + j] * invl);
        *(u16x8*)(op + d) = f;
    }
}

// ---------------------------------------------------------------------------
extern "C" void kernel_launch(void* const* d_in, const int* in_sizes, int n_in,
                              void* d_out, int out_size, void* d_ws, size_t ws_size,
                              hipStream_t stream)
{
    const float* x    = (const float*)d_in[0];
    const float* sq_w = (const float*)d_in[1];
    const float* sk_w = (const float*)d_in[2];
    const float* sv_w = (const float*)d_in[3];
    const float* so_w = (const float*)d_in[4];
    const float* sq_b = (const float*)d_in[5];
    const float* sk_b = (const float*)d_in[6];
    const float* sv_b = (const float*)d_in[7];
    const float* so_b = (const float*)d_in[8];
    const float* sg   = (const float*)d_in[9];
    const float* sb   = (const float*)d_in[10];
    const float* tq_w = (const float*)d_in[11];
    const float* tk_w = (const float*)d_in[12];
    const float* tv_w = (const float*)d_in[13];
    const float* to_w = (const float*)d_in[14];
    const float* tq_b = (const float*)d_in[15];
    const float* tk_b = (const float*)d_in[16];
    const float* tv_b = (const float*)d_in[17];
    const float* to_b = (const float*)d_in[18];
    const float* tg   = (const float*)d_in[19];
    const float* tb   = (const float*)d_in[20];
    const float* w1   = (const float*)d_in[21];
    const float* b1   = (const float*)d_in[22];
    const float* w2   = (const float*)d_in[23];
    const float* b2   = (const float*)d_in[24];
    const float* g    = (const float*)d_in[25];
    const float* bb   = (const float*)d_in[26];

    const size_t NE = (size_t)NTOK * cE;   // 12.58M elements
    const size_t EE = (size_t)cE * cE;     // 589824

    // workspace layout (~245 MB)
    float* W0 = (float*)d_ws;                    // fp32 residual stream [NE]
    float* Wp = W0 + NE;                         // fp32 proj / ffn out  [NE]
    unsigned short* Xb = (unsigned short*)(Wp + NE);  // bf16 x_cur [NE]
    unsigned short* Qb = Xb + NE;
    unsigned short* Kbuf = Qb + NE;
    unsigned short* Vb = Kbuf + NE;
    unsigned short* Ob = Vb + NE;
    unsigned short* Hb = Qb;                     // bf16 hidden [NTOK*DFF] overlays Qb..Ob
    unsigned short* WT = Ob + NE;                // bf16 transposed weights
    unsigned short* sqT = WT;                    // [sq;sk;sv] contiguous -> QKV fused B
    unsigned short* skT = sqT + EE;
    unsigned short* svT = skT + EE;
    unsigned short* soT = svT + EE;
    unsigned short* tqT = soT + EE;              // [tq;tk;tv] contiguous
    unsigned short* tkT = tqT + EE;
    unsigned short* tvT = tkT + EE;
    unsigned short* toT = tvT + EE;
    unsigned short* w1T = toT + EE;              // [DFF][E]
    unsigned short* w2T = w1T + (size_t)cDFF * cE;  // [E][DFF]

    const dim3 blk(256);
    const dim3 blk512(512);
    const dim3 gLN(NTOK);
    const dim3 gQKV(1152);       // 64 M-blocks * 18 N-blocks
    const dim3 gOUT(384);        // 64 * 6
    const dim3 gFF1(1536);       // 64 * 24

    // ---- prep: cast x, transpose+cast all weights to bf16 [N][K] ----
    cast_bf16_kernel<<<dim3(2048), blk, 0, stream>>>(x, Xb, (int)(NE / 4));
    {
        TP8 p;
        p.src[0] = sq_w; p.dst[0] = sqT;
        p.src[1] = sk_w; p.dst[1] = skT;
        p.src[2] = sv_w; p.dst[2] = svT;
        p.src[3] = so_w; p.dst[3] = soT;
        p.src[4] = tq_w; p.dst[4] = tqT;
        p.src[5] = tk_w; p.dst[5] = tkT;
        p.src[6] = tv_w; p.dst[6] = tvT;
        p.src[7] = to_w; p.dst[7] = toT;
        transpose_cast8_kernel<<<dim3(cE / 32, cE / 32, 8), blk, 0, stream>>>(p);
    }
    transpose_cast_kernel<<<dim3(cDFF / 32, cE / 32), blk, 0, stream>>>(w1, w1T, cE, cDFF);
    transpose_cast_kernel<<<dim3(cE / 32, cDFF / 32), blk, 0, stream>>>(w2, w2T, cDFF, cE);

    // ---- Spatial attention block ----
    gemm256_kernel<1,0,1><<<gQKV, blk512, 0, stream>>>(
        Xb, sqT, sq_b, sk_b, sv_b, Qb, Kbuf, Vb, NTOK, 2304, cE, 64);
    spatial_attn_mfma_kernel<<<dim3(cB * cT * cH), blk, 0, stream>>>(Qb, Kbuf, Vb, Ob);
    gemm256_kernel<0,0,0><<<gOUT, blk512, 0, stream>>>(
        Ob, soT, so_b, nullptr, nullptr, Wp, nullptr, nullptr, NTOK, cE, cE, 64);
    residual_ln_kernel<<<gLN, blk, 0, stream>>>(x, Wp, sg, sb, W0, Xb);

    // ---- Temporal attention block ----
    gemm256_kernel<1,0,1><<<gQKV, blk512, 0, stream>>>(
        Xb, tqT, tq_b, tk_b, tv_b, Qb, Kbuf, Vb, NTOK, 2304, cE, 64);
    temporal_attn_kernel<<<dim3(cB * cP * 2), dim3(128), 0, stream>>>(Qb, Kbuf, Vb, Ob);
    gemm256_kernel<0,0,0><<<gOUT, blk512, 0, stream>>>(
        Ob, toT, to_b, nullptr, nullptr, Wp, nullptr, nullptr, NTOK, cE, cE, 64);
    residual_ln_kernel<<<gLN, blk, 0, stream>>>(W0, Wp, tg, tb, W0, Xb);

    // ---- FFN ----
    gemm256_kernel<1,1,0><<<gFF1, blk512, 0, stream>>>(
        Xb, w1T, b1, nullptr, nullptr, Hb, nullptr, nullptr, NTOK, cDFF, cE, 64);
    gemm256_kernel<0,0,0><<<gOUT, blk512, 0, stream>>>(
        Hb, w2T, b2, nullptr, nullptr, Wp, nullptr, nullptr, NTOK, cE, cDFF, 64);
    residual_ln_kernel<<<gLN, blk, 0, stream>>>(W0, Wp, g, bb, (float*)d_out, nullptr);
}

// Round 9
// 753.473 us; speedup vs baseline: 1.0701x; 1.0701x over previous
//
#include <hip/hip_runtime.h>
#include <math.h>

// Problem constants
constexpr int cB   = 4;
constexpr int cT   = 16;
constexpr int cP   = 256;
constexpr int cE   = 768;
constexpr int cH   = 12;
constexpr int cD   = 64;
constexpr int cDFF = 3072;
constexpr int NTOK = cB * cT * cP;        // 16384
constexpr float cSCALE = 0.125f;          // 64^-0.5
constexpr float cEPS = 1e-5f;

typedef __attribute__((ext_vector_type(8))) short short8;
typedef __attribute__((ext_vector_type(4))) float f32x4;
typedef __attribute__((ext_vector_type(8))) unsigned short u16x8;
typedef __attribute__((ext_vector_type(4))) unsigned short u16x4;

#define AS1 __attribute__((address_space(1)))
#define AS3 __attribute__((address_space(3)))

__device__ inline float b2f(unsigned short u) {
    union { unsigned int i; float f; } c; c.i = ((unsigned int)u) << 16; return c.f;
}
__device__ inline unsigned short f2b(float f) {
    union { float f; unsigned int i; } c; c.f = f;
    unsigned int i = c.i;
    unsigned int r = i + 0x7FFFu + ((i >> 16) & 1u);   // RNE
    return (unsigned short)(r >> 16);
}

__device__ inline void gload16(const unsigned short* g, short* l) {
    __builtin_amdgcn_global_load_lds((AS1 const void*)g, (AS3 void*)l, 16, 0, 0);
}

// ---------------------------------------------------------------------------
// 256x128 MFMA GEMM, 3-deep pipeline + 2-phase interleave (m218b combo):
// BK=64, 512 threads (8 waves, 4M x 2N, 64x64 out/wave), 3 LDS buffers.
// Per K-tile: P0 {ds_read B(8)+A01(4), stage A(t+2), barrier, lgkm0, 16 MFMA,
// barrier}; P1 {ds_read A23(4), stage B(t+2), barrier, lgkm0, 16 MFMA,
// vmcnt(6) counted, barrier}. Ledger: end-of-tile in-flight = t+1(6)+t+2(6);
// vmcnt(6) retires t+1 in FIFO order -> every load covered by a full K-tile.
// T2 both-sides swizzle; T5 setprio; T1 XCD swizzle, bm-major (r7 ordering).
// SPLIT3: N=2304 QKV fusion. OUTB: bf16/fp32 out. ACT: exact GELU.
// ---------------------------------------------------------------------------
template<int OUTB, int ACT, int SPLIT3>
__global__ __launch_bounds__(512, 2) void gemm256_kernel(
    const unsigned short* __restrict__ A,   // [M][K] bf16
    const unsigned short* __restrict__ BT,  // [N][K] bf16
    const float* __restrict__ bias0, const float* __restrict__ bias1,
    const float* __restrict__ bias2,
    void* __restrict__ C0, void* __restrict__ C1, void* __restrict__ C2,
    int M, int N, int K, int nbn)
{
    __shared__ short LDS[3 * 24576];   // 144 KiB: 3 x (A[256][64] + B[128][64])

    const int tid = threadIdx.x;
    const int w = tid >> 6, l = tid & 63;
    const int l15 = l & 15, l16 = l >> 4;
    const int wm = w >> 1, wn = w & 1;      // 4 M-waves x 2 N-waves
    const int srow = l >> 3;                // staging: row-in-group 0..7
    const int sslot = l & 7;                // staging: 16B slot 0..7

    // bijective XCD swizzle (nwg % 8 == 0), bm-major (r7 ordering)
    const int nwg = gridDim.x;
    const int wg = (blockIdx.x & 7) * (nwg >> 3) + (blockIdx.x >> 3);
    const int bm = wg / nbn, bn = wg % nbn;
    const int m0 = bm * 256, n0 = bn * 128;

    const unsigned short* pA = A + (size_t)m0 * K;
    const unsigned short* pB = BT + (size_t)n0 * K;

    f32x4 acc[4][4];
    #pragma unroll
    for (int i = 0; i < 4; ++i)
        #pragma unroll
        for (int j = 0; j < 4; ++j)
            #pragma unroll
            for (int r = 0; r < 4; ++r) acc[i][j][r] = 0.f;

    const int nt = K >> 6;

    // ---- staging: linear LDS dest (lane*16B), inverse-swizzled global col ----
    #define STAGE_A(t_, buf_)                                                   \
        {                                                                       \
            const unsigned short* src_ = pA + (t_) * 64;                        \
            short* dst_ = LDS + (buf_) * 24576;                                 \
            _Pragma("unroll")                                                   \
            for (int j_ = 0; j_ < 4; ++j_) {                                    \
                const int r_ = w * 32 + j_ * 8 + srow;                          \
                gload16(src_ + (size_t)r_ * K + ((sslot ^ (r_ & 7)) << 3),      \
                        dst_ + r_ * 64 + (sslot << 3));                         \
            }                                                                   \
        }
    #define STAGE_B(t_, buf_)                                                   \
        {                                                                       \
            const unsigned short* src_ = pB + (t_) * 64;                        \
            short* dst_ = LDS + (buf_) * 24576 + 16384;                         \
            _Pragma("unroll")                                                   \
            for (int j_ = 0; j_ < 2; ++j_) {                                    \
                const int r_ = w * 8 + j_ * 64 + srow;                          \
                gload16(src_ + (size_t)r_ * K + ((sslot ^ (r_ & 7)) << 3),      \
                        dst_ + r_ * 64 + (sslot << 3));                         \
            }                                                                   \
        }

    // prologue: stage tiles 0 and 1; wait for tile 0 (6 newest stay in flight)
    STAGE_A(0, 0); STAGE_B(0, 0);
    STAGE_A(1, 1); STAGE_B(1, 1);
    asm volatile("s_waitcnt vmcnt(6)" ::: "memory");
    __builtin_amdgcn_s_barrier();

    int buf = 0;
    for (int t = 0; t < nt; ++t) {
        const short* bA = LDS + buf * 24576;
        const short* bB = bA + 16384;
        const int sbuf = (buf < 1) ? buf + 2 : buf - 1;   // (t+2)%3

        short8 aF[4][2], bF[4][2];
        // ================= PHASE 0 =================
        // ds_read: all B frags (8) + A frags mf0,mf1 (4)
        #pragma unroll
        for (int nf = 0; nf < 4; ++nf) {
            const int rb = wn * 64 + nf * 16 + l15;
            const char* pb = (const char*)bB + rb * 128;
            const int sw = (rb & 7) << 4;
            bF[nf][0] = *(const short8*)(pb + ((l16 * 16) ^ sw));
            bF[nf][1] = *(const short8*)(pb + ((64 + l16 * 16) ^ sw));
        }
        #pragma unroll
        for (int mm = 0; mm < 2; ++mm) {
            const int ra = wm * 64 + mm * 16 + l15;
            const char* pa = (const char*)bA + ra * 128;
            const int sw = (ra & 7) << 4;
            aF[mm][0] = *(const short8*)(pa + ((l16 * 16) ^ sw));
            aF[mm][1] = *(const short8*)(pa + ((64 + l16 * 16) ^ sw));
        }
        // stage A half-tiles of K-tile t+2
        if (t + 2 < nt) { STAGE_A(t + 2, sbuf); }

        __builtin_amdgcn_s_barrier();
        asm volatile("s_waitcnt lgkmcnt(0)" ::: "memory");
        __builtin_amdgcn_sched_barrier(0);
        __builtin_amdgcn_s_setprio(1);
        #pragma unroll
        for (int kk = 0; kk < 2; ++kk)
            #pragma unroll
            for (int nf = 0; nf < 4; ++nf)
                #pragma unroll
                for (int mm = 0; mm < 2; ++mm)
                    acc[mm][nf] = __builtin_amdgcn_mfma_f32_16x16x32_bf16(
                        aF[mm][kk], bF[nf][kk], acc[mm][nf], 0, 0, 0);
        __builtin_amdgcn_s_setprio(0);
        __builtin_amdgcn_sched_barrier(0);
        __builtin_amdgcn_s_barrier();

        // ================= PHASE 1 =================
        // ds_read: A frags mf2,mf3 (4)
        #pragma unroll
        for (int mm = 2; mm < 4; ++mm) {
            const int ra = wm * 64 + mm * 16 + l15;
            const char* pa = (const char*)bA + ra * 128;
            const int sw = (ra & 7) << 4;
            aF[mm][0] = *(const short8*)(pa + ((l16 * 16) ^ sw));
            aF[mm][1] = *(const short8*)(pa + ((64 + l16 * 16) ^ sw));
        }
        // stage B half-tile of K-tile t+2
        if (t + 2 < nt) { STAGE_B(t + 2, sbuf); }

        __builtin_amdgcn_s_barrier();
        asm volatile("s_waitcnt lgkmcnt(0)" ::: "memory");
        __builtin_amdgcn_sched_barrier(0);
        __builtin_amdgcn_s_setprio(1);
        #pragma unroll
        for (int kk = 0; kk < 2; ++kk)
            #pragma unroll
            for (int nf = 0; nf < 4; ++nf)
                #pragma unroll
                for (int mm = 2; mm < 4; ++mm)
                    acc[mm][nf] = __builtin_amdgcn_mfma_f32_16x16x32_bf16(
                        aF[mm][kk], bF[nf][kk], acc[mm][nf], 0, 0, 0);
        __builtin_amdgcn_s_setprio(0);
        __builtin_amdgcn_sched_barrier(0);

        if (t + 1 < nt) {
            // counted wait: retire t+1's 6 loads (FIFO-oldest), keep t+2's 6
            if (t + 2 < nt)
                asm volatile("s_waitcnt vmcnt(6)" ::: "memory");
            else
                asm volatile("s_waitcnt vmcnt(0)" ::: "memory");
            __builtin_amdgcn_s_barrier();
        }
        buf = (buf == 2) ? 0 : buf + 1;
    }
    #undef STAGE_A
    #undef STAGE_B

    // ---- epilogue: C/D layout col = lane&15, row = (lane>>4)*4 + reg ----
    #pragma unroll
    for (int mf = 0; mf < 4; ++mf) {
        #pragma unroll
        for (int nf = 0; nf < 4; ++nf) {
            const int ng = n0 + wn * 64 + nf * 16 + l15;
            int nl = ng;
            const float* bp = bias0;
            void* Cp = C0;
            int Nout = N;
            if (SPLIT3) {
                const int which = ng / 768;      // uniform per block (128 | 768)
                nl = ng - which * 768;
                bp = (which == 0) ? bias0 : (which == 1) ? bias1 : bias2;
                Cp = (which == 0) ? C0 : (which == 1) ? C1 : C2;
                Nout = 768;
            }
            const float bs = bp[nl];
            #pragma unroll
            for (int r = 0; r < 4; ++r) {
                const int row = m0 + wm * 64 + mf * 16 + l16 * 4 + r;
                float v = acc[mf][nf][r] + bs;
                if (ACT) v = 0.5f * v * (1.f + erff(v * 0.70710678118654752f));
                if (OUTB) ((unsigned short*)Cp)[(size_t)row * Nout + nl] = f2b(v);
                else      ((float*)Cp)[(size_t)row * Nout + nl] = v;
            }
        }
    }
}

// ---------------------------------------------------------------------------
// weight prep: W[K][N] fp32 -> WT[N][K] bf16  (32x32 LDS tile transpose)
// ---------------------------------------------------------------------------
__global__ __launch_bounds__(256) void transpose_cast_kernel(
    const float* __restrict__ W, unsigned short* __restrict__ WT,
    int K, int N)
{
    __shared__ float t[32][33];
    const int k0 = blockIdx.y * 32;
    const int n0 = blockIdx.x * 32;
    const int tx = threadIdx.x & 31;
    const int ty4 = (threadIdx.x >> 5) << 2;
    #pragma unroll
    for (int i = 0; i < 4; ++i)
        t[ty4 + i][tx] = W[(size_t)(k0 + ty4 + i) * N + n0 + tx];
    __syncthreads();
    #pragma unroll
    for (int i = 0; i < 4; ++i)
        WT[(size_t)(n0 + ty4 + i) * K + k0 + tx] = f2b(t[tx][ty4 + i]);
}

// fused prep for the 8 E x E attention weights (grid.z selects weight)
struct TP8 { const float* src[8]; unsigned short* dst[8]; };
__global__ __launch_bounds__(256) void transpose_cast8_kernel(TP8 p)
{
    __shared__ float t[32][33];
    const int z = blockIdx.z;
    const float* W = p.src[z];
    unsigned short* WT = p.dst[z];
    const int k0 = blockIdx.y * 32;
    const int n0 = blockIdx.x * 32;
    const int tx = threadIdx.x & 31;
    const int ty4 = (threadIdx.x >> 5) << 2;
    #pragma unroll
    for (int i = 0; i < 4; ++i)
        t[ty4 + i][tx] = W[(size_t)(k0 + ty4 + i) * cE + n0 + tx];
    __syncthreads();
    #pragma unroll
    for (int i = 0; i < 4; ++i)
        WT[(size_t)(n0 + ty4 + i) * cE + k0 + tx] = f2b(t[tx][ty4 + i]);
}

// fp32 -> bf16 elementwise (n multiple of 4)
__global__ __launch_bounds__(256) void cast_bf16_kernel(
    const float* __restrict__ in, unsigned short* __restrict__ out, int n4)
{
    for (int i = blockIdx.x * blockDim.x + threadIdx.x; i < n4;
         i += gridDim.x * blockDim.x) {
        float4 v = ((const float4*)in)[i];
        u16x4 o;
        o[0] = f2b(v.x); o[1] = f2b(v.y); o[2] = f2b(v.z); o[3] = f2b(v.w);
        *(u16x4*)(out + (size_t)i * 4) = o;
    }
}

// ---------------------------------------------------------------------------
// residual + layernorm: out = LN(X + R) * gamma + beta  (fp32), optional bf16 copy
// ---------------------------------------------------------------------------
__global__ __launch_bounds__(256) void residual_ln_kernel(
    const float* __restrict__ X, const float* __restrict__ R,
    const float* __restrict__ gamma, const float* __restrict__ beta,
    float* __restrict__ out, unsigned short* __restrict__ outb)
{
    const int row = blockIdx.x;
    const size_t off = (size_t)row * cE;
    const int tid = threadIdx.x;

    float v[3];
    float s = 0.f, ss = 0.f;
    #pragma unroll
    for (int i = 0; i < 3; ++i) {
        const int e = tid + i * 256;
        const float t = X[off + e] + R[off + e];
        v[i] = t; s += t; ss += t * t;
    }
    #pragma unroll
    for (int o = 32; o > 0; o >>= 1) {
        s  += __shfl_down(s, o);
        ss += __shfl_down(ss, o);
    }
    __shared__ float rs[4], rss[4];
    const int wid = tid >> 6;
    if ((tid & 63) == 0) { rs[wid] = s; rss[wid] = ss; }
    __syncthreads();
    s  = rs[0] + rs[1] + rs[2] + rs[3];
    ss = rss[0] + rss[1] + rss[2] + rss[3];

    const float mean = s * (1.f / cE);
    const float var  = ss * (1.f / cE) - mean * mean;
    const float inv  = rsqrtf(var + cEPS);
    #pragma unroll
    for (int i = 0; i < 3; ++i) {
        const int e = tid + i * 256;
        const float r = (v[i] - mean) * inv * gamma[e] + beta[e];
        out[off + e] = r;
        if (outb) outb[off + e] = f2b(r);
    }
}

// ---------------------------------------------------------------------------
// Spatial attention, MFMA flash version (verified round 4).
// ---------------------------------------------------------------------------
__global__ __launch_bounds__(256) void spatial_attn_mfma_kernel(
    const unsigned short* __restrict__ Q, const unsigned short* __restrict__ K,
    const unsigned short* __restrict__ V, unsigned short* __restrict__ O)
{
    __shared__ short Ks[64 * 64];      // [j][d] swizzled, row 128B
    __shared__ short Vt[64 * 64];      // [d][j] swizzled
    __shared__ short Ps[4][64 * 64];   // per-wave [q][j] swizzled

    const int bid = blockIdx.x;        // b*T*H + t*H + h
    const int h  = bid % cH;
    const int bt = bid / cH;
    const size_t base = (size_t)bt * cP * cE + h * cD;

    const int tid = threadIdx.x;
    const int w = tid >> 6, l = tid & 63;
    const int l15 = l & 15, l16 = l >> 4;

    short8 qf[4][2];
    #pragma unroll
    for (int mf = 0; mf < 4; ++mf)
        #pragma unroll
        for (int kf = 0; kf < 2; ++kf)
            qf[mf][kf] = *(const short8*)(
                Q + base + (size_t)(w * 64 + mf * 16 + l15) * cE + kf * 32 + l16 * 8);

    f32x4 o[4][4];
    float mrun[4][4], lrun[4][4];
    #pragma unroll
    for (int mf = 0; mf < 4; ++mf)
        #pragma unroll
        for (int j = 0; j < 4; ++j) {
            #pragma unroll
            for (int r = 0; r < 4; ++r) o[mf][j][r] = 0.f;
            mrun[mf][j] = -INFINITY; lrun[mf][j] = 0.f;
        }

    const int krow = w * 8 + (l >> 3);
    const int kc16 = l & 7;
    const int vj  = tid & 31;
    const int vd0 = (tid >> 5) * 8;

    for (int c0 = 0; c0 < cP; c0 += 64) {
        __syncthreads();
        #pragma unroll
        for (int p = 0; p < 2; ++p) {
            const int row = p * 32 + krow;
            gload16(K + base + (size_t)(c0 + row) * cE + ((kc16 ^ (row & 7)) << 3),
                    Ks + row * 64 + kc16 * 8);
        }
        #pragma unroll
        for (int p = 0; p < 2; ++p) {
            const int j = p * 32 + vj;
            short8 vv = *(const short8*)(V + base + (size_t)(c0 + j) * cE + vd0);
            char* vb = (char*)Vt;
            #pragma unroll
            for (int e = 0; e < 8; ++e) {
                const int row = vd0 + e;
                *(short*)(vb + row * 128 + ((2 * j) ^ ((row & 7) << 4))) = vv[e];
            }
        }
        __syncthreads();

        f32x4 s[4][4];
        #pragma unroll
        for (int mf = 0; mf < 4; ++mf)
            #pragma unroll
            for (int nf = 0; nf < 4; ++nf)
                #pragma unroll
                for (int r = 0; r < 4; ++r) s[mf][nf][r] = 0.f;

        #pragma unroll
        for (int nf = 0; nf < 4; ++nf) {
            const int row = nf * 16 + l15;
            const char* kb = (const char*)Ks + row * 128;
            const int sw = (row & 7) << 4;
            short8 k0 = *(const short8*)(kb + ((l16 * 16) ^ sw));
            short8 k1 = *(const short8*)(kb + ((64 + l16 * 16) ^ sw));
            #pragma unroll
            for (int mf = 0; mf < 4; ++mf) {
                s[mf][nf] = __builtin_amdgcn_mfma_f32_16x16x32_bf16(qf[mf][0], k0, s[mf][nf], 0, 0, 0);
                s[mf][nf] = __builtin_amdgcn_mfma_f32_16x16x32_bf16(qf[mf][1], k1, s[mf][nf], 0, 0, 0);
            }
        }

        #pragma unroll
        for (int mf = 0; mf < 4; ++mf)
            #pragma unroll
            for (int nf = 0; nf < 4; ++nf)
                #pragma unroll
                for (int r = 0; r < 4; ++r) s[mf][nf][r] *= cSCALE;

        #pragma unroll
        for (int mf = 0; mf < 4; ++mf) {
            #pragma unroll
            for (int r = 0; r < 4; ++r) {
                float rv = fmaxf(fmaxf(s[mf][0][r], s[mf][1][r]),
                                 fmaxf(s[mf][2][r], s[mf][3][r]));
                rv = fmaxf(rv, __shfl_xor(rv, 1));
                rv = fmaxf(rv, __shfl_xor(rv, 2));
                rv = fmaxf(rv, __shfl_xor(rv, 4));
                rv = fmaxf(rv, __shfl_xor(rv, 8));
                const float mn = fmaxf(mrun[mf][r], rv);
                const float al = __expf(mrun[mf][r] - mn);
                mrun[mf][r] = mn;
                float ps = 0.f;
                #pragma unroll
                for (int nf = 0; nf < 4; ++nf) {
                    const float pe = __expf(s[mf][nf][r] - mn);
                    s[mf][nf][r] = pe;
                    ps += pe;
                }
                ps += __shfl_xor(ps, 1);
                ps += __shfl_xor(ps, 2);
                ps += __shfl_xor(ps, 4);
                ps += __shfl_xor(ps, 8);
                lrun[mf][r] = lrun[mf][r] * al + ps;
                #pragma unroll
                for (int df = 0; df < 4; ++df) o[mf][df][r] *= al;
            }
        }

        char* pw = (char*)&Ps[w][0];
        #pragma unroll
        for (int mf = 0; mf < 4; ++mf)
            #pragma unroll
            for (int nf = 0; nf < 4; ++nf)
                #pragma unroll
                for (int r = 0; r < 4; ++r) {
                    const int row = mf * 16 + l16 * 4 + r;
                    *(short*)(pw + row * 128 + (((nf * 16 + l15) * 2) ^ ((row & 7) << 4))) =
                        (short)f2b(s[mf][nf][r]);
                }

        short8 pa[4][2];
        #pragma unroll
        for (int mf = 0; mf < 4; ++mf) {
            const int prow = mf * 16 + l15;
            const char* pb = (const char*)&Ps[w][0] + prow * 128;
            const int sw = (prow & 7) << 4;
            pa[mf][0] = *(const short8*)(pb + ((l16 * 16) ^ sw));
            pa[mf][1] = *(const short8*)(pb + ((64 + l16 * 16) ^ sw));
        }
        #pragma unroll
        for (int df = 0; df < 4; ++df) {
            const int vrow = df * 16 + l15;
            const char* vbb = (const char*)Vt + vrow * 128;
            const int sw = (vrow & 7) << 4;
            short8 v0 = *(const short8*)(vbb + ((l16 * 16) ^ sw));
            short8 v1 = *(const short8*)(vbb + ((64 + l16 * 16) ^ sw));
            #pragma unroll
            for (int mf = 0; mf < 4; ++mf) {
                o[mf][df] = __builtin_amdgcn_mfma_f32_16x16x32_bf16(pa[mf][0], v0, o[mf][df], 0, 0, 0);
                o[mf][df] = __builtin_amdgcn_mfma_f32_16x16x32_bf16(pa[mf][1], v1, o[mf][df], 0, 0, 0);
            }
        }
    }

    #pragma unroll
    for (int mf = 0; mf < 4; ++mf)
        #pragma unroll
        for (int r = 0; r < 4; ++r) {
            const float inv = 1.f / lrun[mf][r];
            const size_t rowoff = base + (size_t)(w * 64 + mf * 16 + l16 * 4 + r) * cE;
            #pragma unroll
            for (int df = 0; df < 4; ++df)
                O[rowoff + df * 16 + l15] = f2b(o[mf][df][r] * inv);
        }
}

// ---------------------------------------------------------------------------
// Temporal causal attention (bf16 I/O): per (b,p,head-group of 6). T=16.
// ---------------------------------------------------------------------------
__global__ __launch_bounds__(128) void temporal_attn_kernel(
    const unsigned short* __restrict__ Q, const unsigned short* __restrict__ Kb,
    const unsigned short* __restrict__ V, unsigned short* __restrict__ O)
{
    const int bid = blockIdx.x;          // (b*P + p)*2 + hg
    const int hg  = bid & 1;
    const int bp  = bid >> 1;
    const int p   = bp % cP;
    const int b   = bp / cP;

    __shared__ float Ks[cT][6][cD + 1];
    __shared__ float Vs[cT][6][cD + 1];

    const size_t framestride = (size_t)cP * cE;
    const size_t base0 = ((size_t)(b * cT) * cP + p) * cE + hg * 384;

    for (int li = threadIdx.x; li < cT * 384; li += 128) {
        const int s = li / 384;
        const int r = li % 384;
        const size_t src = base0 + (size_t)s * framestride + r;
        Ks[s][r / 64][r & 63] = b2f(Kb[src]);
        Vs[s][r / 64][r & 63] = b2f(V[src]);
    }
    __syncthreads();
    if (threadIdx.x >= 96) return;

    const int hh = threadIdx.x >> 4;
    const int t  = threadIdx.x & 15;
    const size_t qoff = ((size_t)(b * cT + t) * cP + p) * cE + hg * 384 + hh * cD;

    float q[cD];
    #pragma unroll
    for (int d = 0; d < cD; d += 8) {
        short8 f = *(const short8*)(Q + qoff + d);
        #pragma unroll
        for (int j = 0; j < 8; ++j) q[d + j] = b2f((unsigned short)f[j]);
    }

    float sc[cT];
    float mx = -INFINITY;
    #pragma unroll
    for (int s = 0; s < cT; ++s) {
        float acc = 0.f;
        #pragma unroll
        for (int d = 0; d < cD; ++d) acc = fmaf(q[d], Ks[s][hh][d], acc);
        sc[s] = (s <= t) ? acc * cSCALE : -INFINITY;
        mx = fmaxf(mx, sc[s]);
    }
    float l = 0.f;
    #pragma unroll
    for (int s = 0; s < cT; ++s) {
        const float e_ = __expf(sc[s] - mx);
        sc[s] = e_;
        l += e_;
    }
    float o[cD];
    #pragma unroll
    for (int d = 0; d < cD; ++d) o[d] = 0.f;
    #pragma unroll
    for (int s = 0; s < cT; ++s) {
        const float pj = sc[s];
        #pragma unroll
        for (int d = 0; d < cD; ++d) o[d] = fmaf(pj, Vs[s][hh][d], o[d]);
    }
    const float invl = 1.f / l;
    unsigned short* op = O + qoff;
    #pragma unroll
    for (int d = 0; d < cD; d += 8) {
        u16x8 f;
        #pragma unroll
        for (int j = 0; j < 8; ++j) f[j] = f2b(o[d + j] * invl);
        *(u16x8*)(op + d) = f;
    }
}

// ---------------------------------------------------------------------------
extern "C" void kernel_launch(void* const* d_in, const int* in_sizes, int n_in,
                              void* d_out, int out_size, void* d_ws, size_t ws_size,
                              hipStream_t stream)
{
    const float* x    = (const float*)d_in[0];
    const float* sq_w = (const float*)d_in[1];
    const float* sk_w = (const float*)d_in[2];
    const float* sv_w = (const float*)d_in[3];
    const float* so_w = (const float*)d_in[4];
    const float* sq_b = (const float*)d_in[5];
    const float* sk_b = (const float*)d_in[6];
    const float* sv_b = (const float*)d_in[7];
    const float* so_b = (const float*)d_in[8];
    const float* sg   = (const float*)d_in[9];
    const float* sb   = (const float*)d_in[10];
    const float* tq_w = (const float*)d_in[11];
    const float* tk_w = (const float*)d_in[12];
    const float* tv_w = (const float*)d_in[13];
    const float* to_w = (const float*)d_in[14];
    const float* tq_b = (const float*)d_in[15];
    const float* tk_b = (const float*)d_in[16];
    const float* tv_b = (const float*)d_in[17];
    const float* to_b = (const float*)d_in[18];
    const float* tg   = (const float*)d_in[19];
    const float* tb   = (const float*)d_in[20];
    const float* w1   = (const float*)d_in[21];
    const float* b1   = (const float*)d_in[22];
    const float* w2   = (const float*)d_in[23];
    const float* b2   = (const float*)d_in[24];
    const float* g    = (const float*)d_in[25];
    const float* bb   = (const float*)d_in[26];

    const size_t NE = (size_t)NTOK * cE;   // 12.58M elements
    const size_t EE = (size_t)cE * cE;     // 589824

    // workspace layout (~245 MB)
    float* W0 = (float*)d_ws;                    // fp32 residual stream [NE]
    float* Wp = W0 + NE;                         // fp32 proj / ffn out  [NE]
    unsigned short* Xb = (unsigned short*)(Wp + NE);  // bf16 x_cur [NE]
    unsigned short* Qb = Xb + NE;
    unsigned short* Kbuf = Qb + NE;
    unsigned short* Vb = Kbuf + NE;
    unsigned short* Ob = Vb + NE;
    unsigned short* Hb = Qb;                     // bf16 hidden [NTOK*DFF] overlays Qb..Ob
    unsigned short* WT = Ob + NE;                // bf16 transposed weights
    unsigned short* sqT = WT;                    // [sq;sk;sv] contiguous -> QKV fused B
    unsigned short* skT = sqT + EE;
    unsigned short* svT = skT + EE;
    unsigned short* soT = svT + EE;
    unsigned short* tqT = soT + EE;              // [tq;tk;tv] contiguous
    unsigned short* tkT = tqT + EE;
    unsigned short* tvT = tkT + EE;
    unsigned short* toT = tvT + EE;
    unsigned short* w1T = toT + EE;              // [DFF][E]
    unsigned short* w2T = w1T + (size_t)cDFF * cE;  // [E][DFF]

    const dim3 blk(256);
    const dim3 blk512(512);
    const dim3 gLN(NTOK);
    const dim3 gQKV(1152);       // 64 M-blocks * 18 N-blocks
    const dim3 gOUT(384);        // 64 * 6
    const dim3 gFF1(1536);       // 64 * 24

    // ---- prep: cast x, transpose+cast all weights to bf16 [N][K] ----
    cast_bf16_kernel<<<dim3(2048), blk, 0, stream>>>(x, Xb, (int)(NE / 4));
    {
        TP8 p;
        p.src[0] = sq_w; p.dst[0] = sqT;
        p.src[1] = sk_w; p.dst[1] = skT;
        p.src[2] = sv_w; p.dst[2] = svT;
        p.src[3] = so_w; p.dst[3] = soT;
        p.src[4] = tq_w; p.dst[4] = tqT;
        p.src[5] = tk_w; p.dst[5] = tkT;
        p.src[6] = tv_w; p.dst[6] = tvT;
        p.src[7] = to_w; p.dst[7] = toT;
        transpose_cast8_kernel<<<dim3(cE / 32, cE / 32, 8), blk, 0, stream>>>(p);
    }
    transpose_cast_kernel<<<dim3(cDFF / 32, cE / 32), blk, 0, stream>>>(w1, w1T, cE, cDFF);
    transpose_cast_kernel<<<dim3(cE / 32, cDFF / 32), blk, 0, stream>>>(w2, w2T, cDFF, cE);

    // ---- Spatial attention block ----
    gemm256_kernel<1,0,1><<<gQKV, blk512, 0, stream>>>(
        Xb, sqT, sq_b, sk_b, sv_b, Qb, Kbuf, Vb, NTOK, 2304, cE, 18);
    spatial_attn_mfma_kernel<<<dim3(cB * cT * cH), blk, 0, stream>>>(Qb, Kbuf, Vb, Ob);
    gemm256_kernel<0,0,0><<<gOUT, blk512, 0, stream>>>(
        Ob, soT, so_b, nullptr, nullptr, Wp, nullptr, nullptr, NTOK, cE, cE, 6);
    residual_ln_kernel<<<gLN, blk, 0, stream>>>(x, Wp, sg, sb, W0, Xb);

    // ---- Temporal attention block ----
    gemm256_kernel<1,0,1><<<gQKV, blk512, 0, stream>>>(
        Xb, tqT, tq_b, tk_b, tv_b, Qb, Kbuf, Vb, NTOK, 2304, cE, 18);
    temporal_attn_kernel<<<dim3(cB * cP * 2), dim3(128), 0, stream>>>(Qb, Kbuf, Vb, Ob);
    gemm256_kernel<0,0,0><<<gOUT, blk512, 0, stream>>>(
        Ob, toT, to_b, nullptr, nullptr, Wp, nullptr, nullptr, NTOK, cE, cE, 6);
    residual_ln_kernel<<<gLN, blk, 0, stream>>>(W0, Wp, tg, tb, W0, Xb);

    // ---- FFN ----
    gemm256_kernel<1,1,0><<<gFF1, blk512, 0, stream>>>(
        Xb, w1T, b1, nullptr, nullptr, Hb, nullptr, nullptr, NTOK, cDFF, cE, 24);
    gemm256_kernel<0,0,0><<<gOUT, blk512, 0, stream>>>(
        Hb, w2T, b2, nullptr, nullptr, Wp, nullptr, nullptr, NTOK, cE, cDFF, 6);
    residual_ln_kernel<<<gLN, blk, 0, stream>>>(W0, Wp, g, bb, (float*)d_out, nullptr);
}

// Round 10
// 715.633 us; speedup vs baseline: 1.1267x; 1.0529x over previous
//
#include <hip/hip_runtime.h>
#include <math.h>

// Problem constants
constexpr int cB   = 4;
constexpr int cT   = 16;
constexpr int cP   = 256;
constexpr int cE   = 768;
constexpr int cH   = 12;
constexpr int cD   = 64;
constexpr int cDFF = 3072;
constexpr int NTOK = cB * cT * cP;        // 16384
constexpr float cSCALE = 0.125f;          // 64^-0.5
constexpr float cEPS = 1e-5f;

typedef __attribute__((ext_vector_type(8))) short short8;
typedef __attribute__((ext_vector_type(4))) float f32x4;
typedef __attribute__((ext_vector_type(8))) unsigned short u16x8;
typedef __attribute__((ext_vector_type(4))) unsigned short u16x4;

#define AS1 __attribute__((address_space(1)))
#define AS3 __attribute__((address_space(3)))

__device__ inline float b2f(unsigned short u) {
    union { unsigned int i; float f; } c; c.i = ((unsigned int)u) << 16; return c.f;
}
__device__ inline unsigned short f2b(float f) {
    union { float f; unsigned int i; } c; c.f = f;
    unsigned int i = c.i;
    unsigned int r = i + 0x7FFFu + ((i >> 16) & 1u);   // RNE
    return (unsigned short)(r >> 16);
}

__device__ inline void gload16(const unsigned short* g, short* l) {
    __builtin_amdgcn_global_load_lds((AS1 const void*)g, (AS3 void*)l, 16, 0, 0);
}

// ---------------------------------------------------------------------------
// 256x128 MFMA GEMM (r7 structure, best measured): BK=64, 512 threads
// (8 waves, 4M x 2N, 64x64 out/wave), 3 LDS buffers, 16 ds_read then 32 MFMA,
// counted vmcnt(6), ONE s_barrier per K-tile. T2 both-sides swizzle,
// T5 setprio, T1 bijective XCD swizzle, bm-major. Used for QKV + FFN1
// (grids 1152 / 1536 blocks — good CU fill).
// SPLIT3: N=2304 QKV fusion. OUTB: bf16/fp32 out. ACT: exact GELU.
// ---------------------------------------------------------------------------
template<int OUTB, int ACT, int SPLIT3>
__global__ __launch_bounds__(512, 2) void gemm256_kernel(
    const unsigned short* __restrict__ A,   // [M][K] bf16
    const unsigned short* __restrict__ BT,  // [N][K] bf16
    const float* __restrict__ bias0, const float* __restrict__ bias1,
    const float* __restrict__ bias2,
    void* __restrict__ C0, void* __restrict__ C1, void* __restrict__ C2,
    int M, int N, int K, int nbn)
{
    __shared__ short LDS[3 * 24576];   // 144 KiB: 3 x (A[256][64] + B[128][64])

    const int tid = threadIdx.x;
    const int w = tid >> 6, l = tid & 63;
    const int l15 = l & 15, l16 = l >> 4;
    const int wm = w >> 1, wn = w & 1;      // 4 M-waves x 2 N-waves
    const int srow = l >> 3;                // staging: row-in-group 0..7
    const int sslot = l & 7;                // staging: 16B slot 0..7

    // bijective XCD swizzle (nwg % 8 == 0), bm-major
    const int nwg = gridDim.x;
    const int wg = (blockIdx.x & 7) * (nwg >> 3) + (blockIdx.x >> 3);
    const int bm = wg / nbn, bn = wg % nbn;
    const int m0 = bm * 256, n0 = bn * 128;

    const unsigned short* pA = A + (size_t)m0 * K;
    const unsigned short* pB = BT + (size_t)n0 * K;

    f32x4 acc[4][4];
    #pragma unroll
    for (int i = 0; i < 4; ++i)
        #pragma unroll
        for (int j = 0; j < 4; ++j)
            #pragma unroll
            for (int r = 0; r < 4; ++r) acc[i][j][r] = 0.f;

    const int nt = K >> 6;

    #define STAGE_A(t_, buf_)                                                   \
        {                                                                       \
            const unsigned short* src_ = pA + (t_) * 64;                        \
            short* dst_ = LDS + (buf_) * 24576;                                 \
            _Pragma("unroll")                                                   \
            for (int j_ = 0; j_ < 4; ++j_) {                                    \
                const int r_ = w * 32 + j_ * 8 + srow;                          \
                gload16(src_ + (size_t)r_ * K + ((sslot ^ (r_ & 7)) << 3),      \
                        dst_ + r_ * 64 + (sslot << 3));                         \
            }                                                                   \
        }
    #define STAGE_B(t_, buf_)                                                   \
        {                                                                       \
            const unsigned short* src_ = pB + (t_) * 64;                        \
            short* dst_ = LDS + (buf_) * 24576 + 16384;                         \
            _Pragma("unroll")                                                   \
            for (int j_ = 0; j_ < 2; ++j_) {                                    \
                const int r_ = w * 8 + j_ * 64 + srow;                          \
                gload16(src_ + (size_t)r_ * K + ((sslot ^ (r_ & 7)) << 3),      \
                        dst_ + r_ * 64 + (sslot << 3));                         \
            }                                                                   \
        }

    // prologue: stage tiles 0 and 1; wait for tile 0 (6 newest stay in flight)
    STAGE_A(0, 0); STAGE_B(0, 0);
    STAGE_A(1, 1); STAGE_B(1, 1);
    asm volatile("s_waitcnt vmcnt(6)" ::: "memory");
    __builtin_amdgcn_s_barrier();

    int buf = 0;
    for (int t = 0; t < nt; ++t) {
        const short* bA = LDS + buf * 24576;
        const short* bB = bA + 16384;

        short8 aF[4][2], bF[4][2];
        // kk0 fragment reads (8 ds_read_b128)
        #pragma unroll
        for (int mm = 0; mm < 4; ++mm) {
            const int ra = wm * 64 + mm * 16 + l15;
            const char* pa = (const char*)bA + ra * 128;
            aF[mm][0] = *(const short8*)(pa + ((l16 * 16) ^ ((ra & 7) << 4)));
        }
        #pragma unroll
        for (int nf = 0; nf < 4; ++nf) {
            const int rb = wn * 64 + nf * 16 + l15;
            const char* pb = (const char*)bB + rb * 128;
            bF[nf][0] = *(const short8*)(pb + ((l16 * 16) ^ ((rb & 7) << 4)));
        }
        __builtin_amdgcn_sched_barrier(0);   // pin kk0-group issue order
        // kk1 fragment reads (8 ds_read_b128)
        #pragma unroll
        for (int mm = 0; mm < 4; ++mm) {
            const int ra = wm * 64 + mm * 16 + l15;
            const char* pa = (const char*)bA + ra * 128;
            aF[mm][1] = *(const short8*)(pa + ((64 + l16 * 16) ^ ((ra & 7) << 4)));
        }
        #pragma unroll
        for (int nf = 0; nf < 4; ++nf) {
            const int rb = wn * 64 + nf * 16 + l15;
            const char* pb = (const char*)bB + rb * 128;
            bF[nf][1] = *(const short8*)(pb + ((64 + l16 * 16) ^ ((rb & 7) << 4)));
        }

        // stage tile t+2 into the buffer freed at the end of tile t-1
        if (t + 2 < nt) {
            const int b2 = (buf == 0) ? 2 : buf - 1;
            STAGE_A(t + 2, b2); STAGE_B(t + 2, b2);
        }

        asm volatile("s_waitcnt lgkmcnt(8)" ::: "memory");   // kk0 frags ready
        __builtin_amdgcn_sched_barrier(0);
        __builtin_amdgcn_s_setprio(1);
        #pragma unroll
        for (int nf = 0; nf < 4; ++nf)
            #pragma unroll
            for (int mm = 0; mm < 4; ++mm)
                acc[mm][nf] = __builtin_amdgcn_mfma_f32_16x16x32_bf16(
                    aF[mm][0], bF[nf][0], acc[mm][nf], 0, 0, 0);
        __builtin_amdgcn_s_setprio(0);
        asm volatile("s_waitcnt lgkmcnt(0)" ::: "memory");   // kk1 frags ready
        __builtin_amdgcn_sched_barrier(0);
        __builtin_amdgcn_s_setprio(1);
        #pragma unroll
        for (int nf = 0; nf < 4; ++nf)
            #pragma unroll
            for (int mm = 0; mm < 4; ++mm)
                acc[mm][nf] = __builtin_amdgcn_mfma_f32_16x16x32_bf16(
                    aF[mm][1], bF[nf][1], acc[mm][nf], 0, 0, 0);
        __builtin_amdgcn_s_setprio(0);

        if (t + 1 < nt) {
            // retire tile t+1's loads; keep tile t+2's 6 in flight (counted!)
            if (t + 2 < nt)
                asm volatile("s_waitcnt vmcnt(6)" ::: "memory");
            else
                asm volatile("s_waitcnt vmcnt(0)" ::: "memory");
            __builtin_amdgcn_s_barrier();
        }
        buf = (buf == 2) ? 0 : buf + 1;
    }
    #undef STAGE_A
    #undef STAGE_B

    // ---- epilogue: C/D layout col = lane&15, row = (lane>>4)*4 + reg ----
    #pragma unroll
    for (int mf = 0; mf < 4; ++mf) {
        #pragma unroll
        for (int nf = 0; nf < 4; ++nf) {
            const int ng = n0 + wn * 64 + nf * 16 + l15;
            int nl = ng;
            const float* bp = bias0;
            void* Cp = C0;
            int Nout = N;
            if (SPLIT3) {
                const int which = ng / 768;      // uniform per block (128 | 768)
                nl = ng - which * 768;
                bp = (which == 0) ? bias0 : (which == 1) ? bias1 : bias2;
                Cp = (which == 0) ? C0 : (which == 1) ? C1 : C2;
                Nout = 768;
            }
            const float bs = bp[nl];
            #pragma unroll
            for (int r = 0; r < 4; ++r) {
                const int row = m0 + wm * 64 + mf * 16 + l16 * 4 + r;
                float v = acc[mf][nf][r] + bs;
                if (ACT) v = 0.5f * v * (1.f + erff(v * 0.70710678118654752f));
                if (OUTB) ((unsigned short*)Cp)[(size_t)row * Nout + nl] = f2b(v);
                else      ((float*)Cp)[(size_t)row * Nout + nl] = v;
            }
        }
    }
}

// ---------------------------------------------------------------------------
// 128x128 MFMA GEMM (r5 structure, proven): BK=32, 256 threads (4 waves 2x2),
// double-buffered LDS (32 KiB), prefetch-next-before-compute, __syncthreads.
// 72 VGPR -> ~3 blocks/CU. Used for OUT-proj x2 and FFN2 (grid 768 blocks
// = 3 blocks/CU full fill; the 256x128 kernel only fills 1.5/CU there).
// OUTB: 1 -> bf16 out, 0 -> fp32 out.  ACT: 1 -> exact GELU.
// ---------------------------------------------------------------------------
template<int OUTB, int ACT>
__global__ __launch_bounds__(256) void gemm128_kernel(
    const unsigned short* __restrict__ A,   // [M][K] bf16
    const unsigned short* __restrict__ BT,  // [N][K] bf16
    const float* __restrict__ bias,         // [N]
    void* __restrict__ Cout,
    int M, int N, int K)
{
    __shared__ short As[8192];   // 2 x [128][32] bf16, linear (gload_lds order)
    __shared__ short Bs[8192];   // 2 x [128][32] bf16 (rows = n)

    const int tid = threadIdx.x;
    const int m0 = blockIdx.y * 128;
    const int n0 = blockIdx.x * 128;
    const int w  = tid >> 6;
    const int l  = tid & 63;
    const int wr = w >> 1, wc = w & 1;
    const int l15 = l & 15, l16 = l >> 4;

    f32x4 acc[4][4];
    #pragma unroll
    for (int i = 0; i < 4; ++i)
        #pragma unroll
        for (int j = 0; j < 4; ++j)
            #pragma unroll
            for (int r = 0; r < 4; ++r) acc[i][j][r] = 0.f;

    // staging: thread t loads 8 bf16 (16B): row t/4, k-chunk (t%4)*8
    const int sr = tid >> 2;
    const int sc = (tid & 3) << 3;
    const unsigned short* ga0 = A  + (size_t)(m0 + sr) * K + sc;
    const unsigned short* ga1 = A  + (size_t)(m0 + 64 + sr) * K + sc;
    const unsigned short* gb0 = BT + (size_t)(n0 + sr) * K + sc;
    const unsigned short* gb1 = BT + (size_t)(n0 + 64 + sr) * K + sc;
    short* lA = As + tid * 8;
    short* lB = Bs + tid * 8;

    const int aoff = (wr * 64 + l15) * 32 + l16 * 8;   // + mf*16*32
    const int boff = (wc * 64 + l15) * 32 + l16 * 8;   // + nf*16*32

    // prologue: stage tile 0 into buffer 0
    gload16(ga0, lA);
    gload16(ga1, lA + 2048);
    gload16(gb0, lB);
    gload16(gb1, lB + 2048);
    __syncthreads();          // vmcnt(0) drain + barrier

    int cur = 0;
    for (int k0 = 0; k0 < K; k0 += 32) {
        // issue next-tile prefetch into the other buffer (async)
        if (k0 + 32 < K) {
            const int nb = (cur ^ 1) << 12;
            gload16(ga0 + k0 + 32, lA + nb);
            gload16(ga1 + k0 + 32, lA + nb + 2048);
            gload16(gb0 + k0 + 32, lB + nb);
            gload16(gb1 + k0 + 32, lB + nb + 2048);
        }
        const int cb = cur << 12;
        short8 aF[4], bF[4];
        #pragma unroll
        for (int mf = 0; mf < 4; ++mf)
            aF[mf] = *(const short8*)(As + cb + aoff + mf * 512);
        #pragma unroll
        for (int nf = 0; nf < 4; ++nf)
            bF[nf] = *(const short8*)(Bs + cb + boff + nf * 512);
        #pragma unroll
        for (int mf = 0; mf < 4; ++mf)
            #pragma unroll
            for (int nf = 0; nf < 4; ++nf)
                acc[mf][nf] = __builtin_amdgcn_mfma_f32_16x16x32_bf16(
                    aF[mf], bF[nf], acc[mf][nf], 0, 0, 0);
        __syncthreads();      // drains this iter's prefetch (vmcnt0) + barrier
        cur ^= 1;
    }

    // epilogue: C/D layout col = lane&15, row = (lane>>4)*4 + reg
    #pragma unroll
    for (int mf = 0; mf < 4; ++mf) {
        #pragma unroll
        for (int nf = 0; nf < 4; ++nf) {
            const int col = n0 + wc * 64 + nf * 16 + l15;
            const float bs = bias[col];
            #pragma unroll
            for (int r = 0; r < 4; ++r) {
                const int row = m0 + wr * 64 + mf * 16 + l16 * 4 + r;
                float v = acc[mf][nf][r] + bs;
                if (ACT) v = 0.5f * v * (1.f + erff(v * 0.70710678118654752f));
                if (OUTB) ((unsigned short*)Cout)[(size_t)row * N + col] = f2b(v);
                else      ((float*)Cout)[(size_t)row * N + col] = v;
            }
        }
    }
}

// ---------------------------------------------------------------------------
// weight prep: W[K][N] fp32 -> WT[N][K] bf16  (32x32 LDS tile transpose)
// ---------------------------------------------------------------------------
__global__ __launch_bounds__(256) void transpose_cast_kernel(
    const float* __restrict__ W, unsigned short* __restrict__ WT,
    int K, int N)
{
    __shared__ float t[32][33];
    const int k0 = blockIdx.y * 32;
    const int n0 = blockIdx.x * 32;
    const int tx = threadIdx.x & 31;
    const int ty4 = (threadIdx.x >> 5) << 2;
    #pragma unroll
    for (int i = 0; i < 4; ++i)
        t[ty4 + i][tx] = W[(size_t)(k0 + ty4 + i) * N + n0 + tx];
    __syncthreads();
    #pragma unroll
    for (int i = 0; i < 4; ++i)
        WT[(size_t)(n0 + ty4 + i) * K + k0 + tx] = f2b(t[tx][ty4 + i]);
}

// fused prep for the 8 E x E attention weights (grid.z selects weight)
struct TP8 { const float* src[8]; unsigned short* dst[8]; };
__global__ __launch_bounds__(256) void transpose_cast8_kernel(TP8 p)
{
    __shared__ float t[32][33];
    const int z = blockIdx.z;
    const float* W = p.src[z];
    unsigned short* WT = p.dst[z];
    const int k0 = blockIdx.y * 32;
    const int n0 = blockIdx.x * 32;
    const int tx = threadIdx.x & 31;
    const int ty4 = (threadIdx.x >> 5) << 2;
    #pragma unroll
    for (int i = 0; i < 4; ++i)
        t[ty4 + i][tx] = W[(size_t)(k0 + ty4 + i) * cE + n0 + tx];
    __syncthreads();
    #pragma unroll
    for (int i = 0; i < 4; ++i)
        WT[(size_t)(n0 + ty4 + i) * cE + k0 + tx] = f2b(t[tx][ty4 + i]);
}

// fp32 -> bf16 elementwise (n multiple of 4)
__global__ __launch_bounds__(256) void cast_bf16_kernel(
    const float* __restrict__ in, unsigned short* __restrict__ out, int n4)
{
    for (int i = blockIdx.x * blockDim.x + threadIdx.x; i < n4;
         i += gridDim.x * blockDim.x) {
        float4 v = ((const float4*)in)[i];
        u16x4 o;
        o[0] = f2b(v.x); o[1] = f2b(v.y); o[2] = f2b(v.z); o[3] = f2b(v.w);
        *(u16x4*)(out + (size_t)i * 4) = o;
    }
}

// ---------------------------------------------------------------------------
// residual + layernorm: out = LN(X + R) * gamma + beta; X fp32, R bf16.
// Optional bf16 copy of the result.
// ---------------------------------------------------------------------------
__global__ __launch_bounds__(256) void residual_ln_kernel(
    const float* __restrict__ X, const unsigned short* __restrict__ R,
    const float* __restrict__ gamma, const float* __restrict__ beta,
    float* __restrict__ out, unsigned short* __restrict__ outb)
{
    const int row = blockIdx.x;
    const size_t off = (size_t)row * cE;
    const int tid = threadIdx.x;

    float v[3];
    float s = 0.f, ss = 0.f;
    #pragma unroll
    for (int i = 0; i < 3; ++i) {
        const int e = tid + i * 256;
        const float t = X[off + e] + b2f(R[off + e]);
        v[i] = t; s += t; ss += t * t;
    }
    #pragma unroll
    for (int o = 32; o > 0; o >>= 1) {
        s  += __shfl_down(s, o);
        ss += __shfl_down(ss, o);
    }
    __shared__ float rs[4], rss[4];
    const int wid = tid >> 6;
    if ((tid & 63) == 0) { rs[wid] = s; rss[wid] = ss; }
    __syncthreads();
    s  = rs[0] + rs[1] + rs[2] + rs[3];
    ss = rss[0] + rss[1] + rss[2] + rss[3];

    const float mean = s * (1.f / cE);
    const float var  = ss * (1.f / cE) - mean * mean;
    const float inv  = rsqrtf(var + cEPS);
    #pragma unroll
    for (int i = 0; i < 3; ++i) {
        const int e = tid + i * 256;
        const float r = (v[i] - mean) * inv * gamma[e] + beta[e];
        out[off + e] = r;
        if (outb) outb[off + e] = f2b(r);
    }
}

// ---------------------------------------------------------------------------
// Spatial attention, MFMA flash version (verified round 4).
// ---------------------------------------------------------------------------
__global__ __launch_bounds__(256) void spatial_attn_mfma_kernel(
    const unsigned short* __restrict__ Q, const unsigned short* __restrict__ K,
    const unsigned short* __restrict__ V, unsigned short* __restrict__ O)
{
    __shared__ short Ks[64 * 64];      // [j][d] swizzled, row 128B
    __shared__ short Vt[64 * 64];      // [d][j] swizzled
    __shared__ short Ps[4][64 * 64];   // per-wave [q][j] swizzled

    const int bid = blockIdx.x;        // b*T*H + t*H + h
    const int h  = bid % cH;
    const int bt = bid / cH;
    const size_t base = (size_t)bt * cP * cE + h * cD;

    const int tid = threadIdx.x;
    const int w = tid >> 6, l = tid & 63;
    const int l15 = l & 15, l16 = l >> 4;

    short8 qf[4][2];
    #pragma unroll
    for (int mf = 0; mf < 4; ++mf)
        #pragma unroll
        for (int kf = 0; kf < 2; ++kf)
            qf[mf][kf] = *(const short8*)(
                Q + base + (size_t)(w * 64 + mf * 16 + l15) * cE + kf * 32 + l16 * 8);

    f32x4 o[4][4];
    float mrun[4][4], lrun[4][4];
    #pragma unroll
    for (int mf = 0; mf < 4; ++mf)
        #pragma unroll
        for (int j = 0; j < 4; ++j) {
            #pragma unroll
            for (int r = 0; r < 4; ++r) o[mf][j][r] = 0.f;
            mrun[mf][j] = -INFINITY; lrun[mf][j] = 0.f;
        }

    const int krow = w * 8 + (l >> 3);
    const int kc16 = l & 7;
    const int vj  = tid & 31;
    const int vd0 = (tid >> 5) * 8;

    for (int c0 = 0; c0 < cP; c0 += 64) {
        __syncthreads();
        #pragma unroll
        for (int p = 0; p < 2; ++p) {
            const int row = p * 32 + krow;
            gload16(K + base + (size_t)(c0 + row) * cE + ((kc16 ^ (row & 7)) << 3),
                    Ks + row * 64 + kc16 * 8);
        }
        #pragma unroll
        for (int p = 0; p < 2; ++p) {
            const int j = p * 32 + vj;
            short8 vv = *(const short8*)(V + base + (size_t)(c0 + j) * cE + vd0);
            char* vb = (char*)Vt;
            #pragma unroll
            for (int e = 0; e < 8; ++e) {
                const int row = vd0 + e;
                *(short*)(vb + row * 128 + ((2 * j) ^ ((row & 7) << 4))) = vv[e];
            }
        }
        __syncthreads();

        f32x4 s[4][4];
        #pragma unroll
        for (int mf = 0; mf < 4; ++mf)
            #pragma unroll
            for (int nf = 0; nf < 4; ++nf)
                #pragma unroll
                for (int r = 0; r < 4; ++r) s[mf][nf][r] = 0.f;

        #pragma unroll
        for (int nf = 0; nf < 4; ++nf) {
            const int row = nf * 16 + l15;
            const char* kb = (const char*)Ks + row * 128;
            const int sw = (row & 7) << 4;
            short8 k0 = *(const short8*)(kb + ((l16 * 16) ^ sw));
            short8 k1 = *(const short8*)(kb + ((64 + l16 * 16) ^ sw));
            #pragma unroll
            for (int mf = 0; mf < 4; ++mf) {
                s[mf][nf] = __builtin_amdgcn_mfma_f32_16x16x32_bf16(qf[mf][0], k0, s[mf][nf], 0, 0, 0);
                s[mf][nf] = __builtin_amdgcn_mfma_f32_16x16x32_bf16(qf[mf][1], k1, s[mf][nf], 0, 0, 0);
            }
        }

        #pragma unroll
        for (int mf = 0; mf < 4; ++mf)
            #pragma unroll
            for (int nf = 0; nf < 4; ++nf)
                #pragma unroll
                for (int r = 0; r < 4; ++r) s[mf][nf][r] *= cSCALE;

        #pragma unroll
        for (int mf = 0; mf < 4; ++mf) {
            #pragma unroll
            for (int r = 0; r < 4; ++r) {
                float rv = fmaxf(fmaxf(s[mf][0][r], s[mf][1][r]),
                                 fmaxf(s[mf][2][r], s[mf][3][r]));
                rv = fmaxf(rv, __shfl_xor(rv, 1));
                rv = fmaxf(rv, __shfl_xor(rv, 2));
                rv = fmaxf(rv, __shfl_xor(rv, 4));
                rv = fmaxf(rv, __shfl_xor(rv, 8));
                const float mn = fmaxf(mrun[mf][r], rv);
                const float al = __expf(mrun[mf][r] - mn);
                mrun[mf][r] = mn;
                float ps = 0.f;
                #pragma unroll
                for (int nf = 0; nf < 4; ++nf) {
                    const float pe = __expf(s[mf][nf][r] - mn);
                    s[mf][nf][r] = pe;
                    ps += pe;
                }
                ps += __shfl_xor(ps, 1);
                ps += __shfl_xor(ps, 2);
                ps += __shfl_xor(ps, 4);
                ps += __shfl_xor(ps, 8);
                lrun[mf][r] = lrun[mf][r] * al + ps;
                #pragma unroll
                for (int df = 0; df < 4; ++df) o[mf][df][r] *= al;
            }
        }

        char* pw = (char*)&Ps[w][0];
        #pragma unroll
        for (int mf = 0; mf < 4; ++mf)
            #pragma unroll
            for (int nf = 0; nf < 4; ++nf)
                #pragma unroll
                for (int r = 0; r < 4; ++r) {
                    const int row = mf * 16 + l16 * 4 + r;
                    *(short*)(pw + row * 128 + (((nf * 16 + l15) * 2) ^ ((row & 7) << 4))) =
                        (short)f2b(s[mf][nf][r]);
                }

        short8 pa[4][2];
        #pragma unroll
        for (int mf = 0; mf < 4; ++mf) {
            const int prow = mf * 16 + l15;
            const char* pb = (const char*)&Ps[w][0] + prow * 128;
            const int sw = (prow & 7) << 4;
            pa[mf][0] = *(const short8*)(pb + ((l16 * 16) ^ sw));
            pa[mf][1] = *(const short8*)(pb + ((64 + l16 * 16) ^ sw));
        }
        #pragma unroll
        for (int df = 0; df < 4; ++df) {
            const int vrow = df * 16 + l15;
            const char* vbb = (const char*)Vt + vrow * 128;
            const int sw = (vrow & 7) << 4;
            short8 v0 = *(const short8*)(vbb + ((l16 * 16) ^ sw));
            short8 v1 = *(const short8*)(vbb + ((64 + l16 * 16) ^ sw));
            #pragma unroll
            for (int mf = 0; mf < 4; ++mf) {
                o[mf][df] = __builtin_amdgcn_mfma_f32_16x16x32_bf16(pa[mf][0], v0, o[mf][df], 0, 0, 0);
                o[mf][df] = __builtin_amdgcn_mfma_f32_16x16x32_bf16(pa[mf][1], v1, o[mf][df], 0, 0, 0);
            }
        }
    }

    #pragma unroll
    for (int mf = 0; mf < 4; ++mf)
        #pragma unroll
        for (int r = 0; r < 4; ++r) {
            const float inv = 1.f / lrun[mf][r];
            const size_t rowoff = base + (size_t)(w * 64 + mf * 16 + l16 * 4 + r) * cE;
            #pragma unroll
            for (int df = 0; df < 4; ++df)
                O[rowoff + df * 16 + l15] = f2b(o[mf][df][r] * inv);
        }
}

// ---------------------------------------------------------------------------
// Temporal causal attention (bf16 I/O): per (b,p,head-group of 6). T=16.
// ---------------------------------------------------------------------------
__global__ __launch_bounds__(128) void temporal_attn_kernel(
    const unsigned short* __restrict__ Q, const unsigned short* __restrict__ Kb,
    const unsigned short* __restrict__ V, unsigned short* __restrict__ O)
{
    const int bid = blockIdx.x;          // (b*P + p)*2 + hg
    const int hg  = bid & 1;
    const int bp  = bid >> 1;
    const int p   = bp % cP;
    const int b   = bp / cP;

    __shared__ float Ks[cT][6][cD + 1];
    __shared__ float Vs[cT][6][cD + 1];

    const size_t framestride = (size_t)cP * cE;
    const size_t base0 = ((size_t)(b * cT) * cP + p) * cE + hg * 384;

    for (int li = threadIdx.x; li < cT * 384; li += 128) {
        const int s = li / 384;
        const int r = li % 384;
        const size_t src = base0 + (size_t)s * framestride + r;
        Ks[s][r / 64][r & 63] = b2f(Kb[src]);
        Vs[s][r / 64][r & 63] = b2f(V[src]);
    }
    __syncthreads();
    if (threadIdx.x >= 96) return;

    const int hh = threadIdx.x >> 4;
    const int t  = threadIdx.x & 15;
    const size_t qoff = ((size_t)(b * cT + t) * cP + p) * cE + hg * 384 + hh * cD;

    float q[cD];
    #pragma unroll
    for (int d = 0; d < cD; d += 8) {
        short8 f = *(const short8*)(Q + qoff + d);
        #pragma unroll
        for (int j = 0; j < 8; ++j) q[d + j] = b2f((unsigned short)f[j]);
    }

    float sc[cT];
    float mx = -INFINITY;
    #pragma unroll
    for (int s = 0; s < cT; ++s) {
        float acc = 0.f;
        #pragma unroll
        for (int d = 0; d < cD; ++d) acc = fmaf(q[d], Ks[s][hh][d], acc);
        sc[s] = (s <= t) ? acc * cSCALE : -INFINITY;
        mx = fmaxf(mx, sc[s]);
    }
    float l = 0.f;
    #pragma unroll
    for (int s = 0; s < cT; ++s) {
        const float e_ = __expf(sc[s] - mx);
        sc[s] = e_;
        l += e_;
    }
    float o[cD];
    #pragma unroll
    for (int d = 0; d < cD; ++d) o[d] = 0.f;
    #pragma unroll
    for (int s = 0; s < cT; ++s) {
        const float pj = sc[s];
        #pragma unroll
        for (int d = 0; d < cD; ++d) o[d] = fmaf(pj, Vs[s][hh][d], o[d]);
    }
    const float invl = 1.f / l;
    unsigned short* op = O + qoff;
    #pragma unroll
    for (int d = 0; d < cD; d += 8) {
        u16x8 f;
        #pragma unroll
        for (int j = 0; j < 8; ++j) f[j] = f2b(o[d + j] * invl);
        *(u16x8*)(op + d) = f;
    }
}

// ---------------------------------------------------------------------------
extern "C" void kernel_launch(void* const* d_in, const int* in_sizes, int n_in,
                              void* d_out, int out_size, void* d_ws, size_t ws_size,
                              hipStream_t stream)
{
    const float* x    = (const float*)d_in[0];
    const float* sq_w = (const float*)d_in[1];
    const float* sk_w = (const float*)d_in[2];
    const float* sv_w = (const float*)d_in[3];
    const float* so_w = (const float*)d_in[4];
    const float* sq_b = (const float*)d_in[5];
    const float* sk_b = (const float*)d_in[6];
    const float* sv_b = (const float*)d_in[7];
    const float* so_b = (const float*)d_in[8];
    const float* sg   = (const float*)d_in[9];
    const float* sb   = (const float*)d_in[10];
    const float* tq_w = (const float*)d_in[11];
    const float* tk_w = (const float*)d_in[12];
    const float* tv_w = (const float*)d_in[13];
    const float* to_w = (const float*)d_in[14];
    const float* tq_b = (const float*)d_in[15];
    const float* tk_b = (const float*)d_in[16];
    const float* tv_b = (const float*)d_in[17];
    const float* to_b = (const float*)d_in[18];
    const float* tg   = (const float*)d_in[19];
    const float* tb   = (const float*)d_in[20];
    const float* w1   = (const float*)d_in[21];
    const float* b1   = (const float*)d_in[22];
    const float* w2   = (const float*)d_in[23];
    const float* b2   = (const float*)d_in[24];
    const float* g    = (const float*)d_in[25];
    const float* bb   = (const float*)d_in[26];

    const size_t NE = (size_t)NTOK * cE;   // 12.58M elements
    const size_t EE = (size_t)cE * cE;     // 589824

    // workspace layout (~245 MB)
    float* W0 = (float*)d_ws;                    // fp32 residual stream [NE]
    float* Wp = W0 + NE;                         // region reused as bf16 R [NE]
    unsigned short* Rb = (unsigned short*)Wp;    // bf16 projection/FFN output
    unsigned short* Xb = (unsigned short*)(Wp + NE);  // bf16 x_cur [NE]
    unsigned short* Qb = Xb + NE;
    unsigned short* Kbuf = Qb + NE;
    unsigned short* Vb = Kbuf + NE;
    unsigned short* Ob = Vb + NE;
    unsigned short* Hb = Qb;                     // bf16 hidden [NTOK*DFF] overlays Qb..Ob
    unsigned short* WT = Ob + NE;                // bf16 transposed weights
    unsigned short* sqT = WT;                    // [sq;sk;sv] contiguous -> QKV fused B
    unsigned short* skT = sqT + EE;
    unsigned short* svT = skT + EE;
    unsigned short* soT = svT + EE;
    unsigned short* tqT = soT + EE;              // [tq;tk;tv] contiguous
    unsigned short* tkT = tqT + EE;
    unsigned short* tvT = tkT + EE;
    unsigned short* toT = tvT + EE;
    unsigned short* w1T = toT + EE;              // [DFF][E]
    unsigned short* w2T = w1T + (size_t)cDFF * cE;  // [E][DFF]

    const dim3 blk(256);
    const dim3 blk512(512);
    const dim3 gLN(NTOK);
    const dim3 gQKV(1152);               // 64 M-blocks * 18 N-blocks (256x128)
    const dim3 gFF1(1536);               // 64 * 24 (256x128)
    const dim3 g128(cE / 128, NTOK / 128);   // (6, 128) = 768 blocks (128x128)

    // ---- prep: cast x, transpose+cast all weights to bf16 [N][K] ----
    cast_bf16_kernel<<<dim3(2048), blk, 0, stream>>>(x, Xb, (int)(NE / 4));
    {
        TP8 p;
        p.src[0] = sq_w; p.dst[0] = sqT;
        p.src[1] = sk_w; p.dst[1] = skT;
        p.src[2] = sv_w; p.dst[2] = svT;
        p.src[3] = so_w; p.dst[3] = soT;
        p.src[4] = tq_w; p.dst[4] = tqT;
        p.src[5] = tk_w; p.dst[5] = tkT;
        p.src[6] = tv_w; p.dst[6] = tvT;
        p.src[7] = to_w; p.dst[7] = toT;
        transpose_cast8_kernel<<<dim3(cE / 32, cE / 32, 8), blk, 0, stream>>>(p);
    }
    transpose_cast_kernel<<<dim3(cDFF / 32, cE / 32), blk, 0, stream>>>(w1, w1T, cE, cDFF);
    transpose_cast_kernel<<<dim3(cE / 32, cDFF / 32), blk, 0, stream>>>(w2, w2T, cDFF, cE);

    // ---- Spatial attention block ----
    gemm256_kernel<1,0,1><<<gQKV, blk512, 0, stream>>>(
        Xb, sqT, sq_b, sk_b, sv_b, Qb, Kbuf, Vb, NTOK, 2304, cE, 18);
    spatial_attn_mfma_kernel<<<dim3(cB * cT * cH), blk, 0, stream>>>(Qb, Kbuf, Vb, Ob);
    gemm128_kernel<1,0><<<g128, blk, 0, stream>>>(Ob, soT, so_b, Rb, NTOK, cE, cE);
    residual_ln_kernel<<<gLN, blk, 0, stream>>>(x, Rb, sg, sb, W0, Xb);

    // ---- Temporal attention block ----
    gemm256_kernel<1,0,1><<<gQKV, blk512, 0, stream>>>(
        Xb, tqT, tq_b, tk_b, tv_b, Qb, Kbuf, Vb, NTOK, 2304, cE, 18);
    temporal_attn_kernel<<<dim3(cB * cP * 2), dim3(128), 0, stream>>>(Qb, Kbuf, Vb, Ob);
    gemm128_kernel<1,0><<<g128, blk, 0, stream>>>(Ob, toT, to_b, Rb, NTOK, cE, cE);
    residual_ln_kernel<<<gLN, blk, 0, stream>>>(W0, Rb, tg, tb, W0, Xb);

    // ---- FFN ----
    gemm256_kernel<1,1,0><<<gFF1, blk512, 0, stream>>>(
        Xb, w1T, b1, nullptr, nullptr, Hb, nullptr, nullptr, NTOK, cDFF, cE, 24);
    gemm128_kernel<1,0><<<g128, blk, 0, stream>>>(Hb, w2T, b2, Rb, NTOK, cE, cDFF);
    residual_ln_kernel<<<gLN, blk, 0, stream>>>(W0, Rb, g, bb, (float*)d_out, nullptr);
}

// Round 11
// 711.201 us; speedup vs baseline: 1.1337x; 1.0062x over previous
//
#include <hip/hip_runtime.h>
#include <math.h>

// Problem constants
constexpr int cB   = 4;
constexpr int cT   = 16;
constexpr int cP   = 256;
constexpr int cE   = 768;
constexpr int cH   = 12;
constexpr int cD   = 64;
constexpr int cDFF = 3072;
constexpr int NTOK = cB * cT * cP;        // 16384
constexpr float cSCALE = 0.125f;          // 64^-0.5
constexpr float cEPS = 1e-5f;

typedef __attribute__((ext_vector_type(8))) short short8;
typedef __attribute__((ext_vector_type(4))) float f32x4;
typedef __attribute__((ext_vector_type(8))) unsigned short u16x8;
typedef __attribute__((ext_vector_type(4))) unsigned short u16x4;

#define AS1 __attribute__((address_space(1)))
#define AS3 __attribute__((address_space(3)))

__device__ inline float b2f(unsigned short u) {
    union { unsigned int i; float f; } c; c.i = ((unsigned int)u) << 16; return c.f;
}
__device__ inline unsigned short f2b(float f) {
    union { float f; unsigned int i; } c; c.f = f;
    unsigned int i = c.i;
    unsigned int r = i + 0x7FFFu + ((i >> 16) & 1u);   // RNE
    return (unsigned short)(r >> 16);
}

__device__ inline void gload16(const unsigned short* g, short* l) {
    __builtin_amdgcn_global_load_lds((AS1 const void*)g, (AS3 void*)l, 16, 0, 0);
}

// ---------------------------------------------------------------------------
// 256x128 MFMA GEMM (r7 schedule + r11 strength reduction):
// BK=64, 512 threads (8 waves, 4M x 2N), 3 LDS buffers, counted vmcnt(6),
// ONE s_barrier per K-tile, T2 both-sides swizzle, T5 setprio, T1 XCD swizzle.
// r11 change: ALL loop-variant address math hoisted — 6 global staging
// pointers advanced by +=64/tile (no in-loop size_t multiplies), 16 ds_read
// byte offsets + 6 LDS dest offsets precomputed in VGPRs, launch_bounds(512,1)
// so the VGPR cap doesn't force recomputation (VALUBusy was 2x MfmaUtil).
// SPLIT3: N=2304 QKV fusion. OUTB: bf16/fp32 out. ACT: exact GELU.
// ---------------------------------------------------------------------------
template<int OUTB, int ACT, int SPLIT3>
__global__ __launch_bounds__(512, 1) void gemm256_kernel(
    const unsigned short* __restrict__ A,   // [M][K] bf16
    const unsigned short* __restrict__ BT,  // [N][K] bf16
    const float* __restrict__ bias0, const float* __restrict__ bias1,
    const float* __restrict__ bias2,
    void* __restrict__ C0, void* __restrict__ C1, void* __restrict__ C2,
    int M, int N, int K, int nbn)
{
    __shared__ short LDS[3 * 24576];   // 144 KiB: 3 x (A[256][64] + B[128][64])

    const int tid = threadIdx.x;
    const int w = tid >> 6, l = tid & 63;
    const int l15 = l & 15, l16 = l >> 4;
    const int wm = w >> 1, wn = w & 1;      // 4 M-waves x 2 N-waves
    const int srow = l >> 3;                // staging: row-in-group 0..7
    const int sslot = l & 7;                // staging: 16B slot 0..7

    // bijective XCD swizzle (nwg % 8 == 0), bm-major
    const int nwg = gridDim.x;
    const int wg = (blockIdx.x & 7) * (nwg >> 3) + (blockIdx.x >> 3);
    const int bm = wg / nbn, bn = wg % nbn;
    const int m0 = bm * 256, n0 = bn * 128;

    f32x4 acc[4][4];
    #pragma unroll
    for (int i = 0; i < 4; ++i)
        #pragma unroll
        for (int j = 0; j < 4; ++j)
            #pragma unroll
            for (int r = 0; r < 4; ++r) acc[i][j][r] = 0.f;

    const int nt = K >> 6;

    // ---- hoisted staging pointers (advance += 64/tile) + LDS dest offsets ----
    const unsigned short* gA[4];
    const unsigned short* gB[2];
    int dA[4], dB[2];                       // LDS dest offsets (elements, buf0)
    #pragma unroll
    for (int j = 0; j < 4; ++j) {
        const int r = w * 32 + j * 8 + srow;
        gA[j] = A + (size_t)(m0 + r) * K + ((sslot ^ (r & 7)) << 3);
        dA[j] = r * 64 + (sslot << 3);
    }
    #pragma unroll
    for (int j = 0; j < 2; ++j) {
        const int r = w * 8 + j * 64 + srow;
        gB[j] = BT + (size_t)(n0 + r) * K + ((sslot ^ (r & 7)) << 3);
        dB[j] = 16384 + r * 64 + (sslot << 3);
    }

    // ---- hoisted ds_read byte offsets (relative to buffer base) ----
    int offA[4][2], offB[4][2];
    #pragma unroll
    for (int mm = 0; mm < 4; ++mm) {
        const int ra = wm * 64 + mm * 16 + l15;
        const int sw = (ra & 7) << 4;
        offA[mm][0] = ra * 128 + ((l16 * 16) ^ sw);
        offA[mm][1] = ra * 128 + ((64 + l16 * 16) ^ sw);
    }
    #pragma unroll
    for (int nf = 0; nf < 4; ++nf) {
        const int rb = wn * 64 + nf * 16 + l15;
        const int sw = (rb & 7) << 4;
        offB[nf][0] = 32768 + rb * 128 + ((l16 * 16) ^ sw);
        offB[nf][1] = 32768 + rb * 128 + ((64 + l16 * 16) ^ sw);
    }

    // prologue: stage tiles 0 (buf0) and 1 (buf1); advance pointers to tile 2
    #pragma unroll
    for (int j = 0; j < 4; ++j) { gload16(gA[j], LDS + dA[j]); }
    #pragma unroll
    for (int j = 0; j < 2; ++j) { gload16(gB[j], LDS + dB[j]); }
    #pragma unroll
    for (int j = 0; j < 4; ++j) { gload16(gA[j] + 64, LDS + 24576 + dA[j]); }
    #pragma unroll
    for (int j = 0; j < 2; ++j) { gload16(gB[j] + 64, LDS + 24576 + dB[j]); }
    #pragma unroll
    for (int j = 0; j < 4; ++j) gA[j] += 128;
    #pragma unroll
    for (int j = 0; j < 2; ++j) gB[j] += 128;

    asm volatile("s_waitcnt vmcnt(6)" ::: "memory");
    __builtin_amdgcn_s_barrier();

    int buf = 0;
    for (int t = 0; t < nt; ++t) {
        const char* Lb = (const char*)LDS + buf * 49152;

        short8 aF[4][2], bF[4][2];
        // kk0 fragment reads (8 ds_read_b128)
        #pragma unroll
        for (int mm = 0; mm < 4; ++mm)
            aF[mm][0] = *(const short8*)(Lb + offA[mm][0]);
        #pragma unroll
        for (int nf = 0; nf < 4; ++nf)
            bF[nf][0] = *(const short8*)(Lb + offB[nf][0]);
        __builtin_amdgcn_sched_barrier(0);   // pin kk0-group issue order
        // kk1 fragment reads (8 ds_read_b128)
        #pragma unroll
        for (int mm = 0; mm < 4; ++mm)
            aF[mm][1] = *(const short8*)(Lb + offA[mm][1]);
        #pragma unroll
        for (int nf = 0; nf < 4; ++nf)
            bF[nf][1] = *(const short8*)(Lb + offB[nf][1]);

        // stage tile t+2 into the buffer freed at the end of tile t-1
        if (t + 2 < nt) {
            const int b2 = (buf == 0) ? 2 : buf - 1;
            short* dst = LDS + b2 * 24576;
            #pragma unroll
            for (int j = 0; j < 4; ++j) { gload16(gA[j], dst + dA[j]); gA[j] += 64; }
            #pragma unroll
            for (int j = 0; j < 2; ++j) { gload16(gB[j], dst + dB[j]); gB[j] += 64; }
        }

        asm volatile("s_waitcnt lgkmcnt(8)" ::: "memory");   // kk0 frags ready
        __builtin_amdgcn_sched_barrier(0);
        __builtin_amdgcn_s_setprio(1);
        #pragma unroll
        for (int nf = 0; nf < 4; ++nf)
            #pragma unroll
            for (int mm = 0; mm < 4; ++mm)
                acc[mm][nf] = __builtin_amdgcn_mfma_f32_16x16x32_bf16(
                    aF[mm][0], bF[nf][0], acc[mm][nf], 0, 0, 0);
        __builtin_amdgcn_s_setprio(0);
        asm volatile("s_waitcnt lgkmcnt(0)" ::: "memory");   // kk1 frags ready
        __builtin_amdgcn_sched_barrier(0);
        __builtin_amdgcn_s_setprio(1);
        #pragma unroll
        for (int nf = 0; nf < 4; ++nf)
            #pragma unroll
            for (int mm = 0; mm < 4; ++mm)
                acc[mm][nf] = __builtin_amdgcn_mfma_f32_16x16x32_bf16(
                    aF[mm][1], bF[nf][1], acc[mm][nf], 0, 0, 0);
        __builtin_amdgcn_s_setprio(0);

        if (t + 1 < nt) {
            // retire tile t+1's loads; keep tile t+2's 6 in flight (counted!)
            if (t + 2 < nt)
                asm volatile("s_waitcnt vmcnt(6)" ::: "memory");
            else
                asm volatile("s_waitcnt vmcnt(0)" ::: "memory");
            __builtin_amdgcn_s_barrier();
        }
        buf = (buf == 2) ? 0 : buf + 1;
    }

    // ---- epilogue: C/D layout col = lane&15, row = (lane>>4)*4 + reg ----
    #pragma unroll
    for (int mf = 0; mf < 4; ++mf) {
        #pragma unroll
        for (int nf = 0; nf < 4; ++nf) {
            const int ng = n0 + wn * 64 + nf * 16 + l15;
            int nl = ng;
            const float* bp = bias0;
            void* Cp = C0;
            int Nout = N;
            if (SPLIT3) {
                const int which = ng / 768;      // uniform per block (128 | 768)
                nl = ng - which * 768;
                bp = (which == 0) ? bias0 : (which == 1) ? bias1 : bias2;
                Cp = (which == 0) ? C0 : (which == 1) ? C1 : C2;
                Nout = 768;
            }
            const float bs = bp[nl];
            #pragma unroll
            for (int r = 0; r < 4; ++r) {
                const int row = m0 + wm * 64 + mf * 16 + l16 * 4 + r;
                float v = acc[mf][nf][r] + bs;
                if (ACT) v = 0.5f * v * (1.f + erff(v * 0.70710678118654752f));
                if (OUTB) ((unsigned short*)Cp)[(size_t)row * Nout + nl] = f2b(v);
                else      ((float*)Cp)[(size_t)row * Nout + nl] = v;
            }
        }
    }
}

// ---------------------------------------------------------------------------
// 128x128 MFMA GEMM (r5 structure, proven): BK=32, 256 threads (4 waves 2x2),
// double-buffered LDS (32 KiB), prefetch-next-before-compute, __syncthreads.
// Used for OUT-proj x2 and FFN2 (grid 768 blocks = good CU fill).
// OUTB: 1 -> bf16 out, 0 -> fp32 out.  ACT: 1 -> exact GELU.
// ---------------------------------------------------------------------------
template<int OUTB, int ACT>
__global__ __launch_bounds__(256) void gemm128_kernel(
    const unsigned short* __restrict__ A,   // [M][K] bf16
    const unsigned short* __restrict__ BT,  // [N][K] bf16
    const float* __restrict__ bias,         // [N]
    void* __restrict__ Cout,
    int M, int N, int K)
{
    __shared__ short As[8192];   // 2 x [128][32] bf16, linear (gload_lds order)
    __shared__ short Bs[8192];   // 2 x [128][32] bf16 (rows = n)

    const int tid = threadIdx.x;
    const int m0 = blockIdx.y * 128;
    const int n0 = blockIdx.x * 128;
    const int w  = tid >> 6;
    const int l  = tid & 63;
    const int wr = w >> 1, wc = w & 1;
    const int l15 = l & 15, l16 = l >> 4;

    f32x4 acc[4][4];
    #pragma unroll
    for (int i = 0; i < 4; ++i)
        #pragma unroll
        for (int j = 0; j < 4; ++j)
            #pragma unroll
            for (int r = 0; r < 4; ++r) acc[i][j][r] = 0.f;

    // staging: thread t loads 8 bf16 (16B): row t/4, k-chunk (t%4)*8
    const int sr = tid >> 2;
    const int sc = (tid & 3) << 3;
    const unsigned short* ga0 = A  + (size_t)(m0 + sr) * K + sc;
    const unsigned short* ga1 = A  + (size_t)(m0 + 64 + sr) * K + sc;
    const unsigned short* gb0 = BT + (size_t)(n0 + sr) * K + sc;
    const unsigned short* gb1 = BT + (size_t)(n0 + 64 + sr) * K + sc;
    short* lA = As + tid * 8;
    short* lB = Bs + tid * 8;

    const int aoff = (wr * 64 + l15) * 32 + l16 * 8;   // + mf*16*32
    const int boff = (wc * 64 + l15) * 32 + l16 * 8;   // + nf*16*32

    // prologue: stage tile 0 into buffer 0
    gload16(ga0, lA);
    gload16(ga1, lA + 2048);
    gload16(gb0, lB);
    gload16(gb1, lB + 2048);
    __syncthreads();          // vmcnt(0) drain + barrier

    int cur = 0;
    for (int k0 = 0; k0 < K; k0 += 32) {
        // issue next-tile prefetch into the other buffer (async)
        if (k0 + 32 < K) {
            const int nb = (cur ^ 1) << 12;
            gload16(ga0 + k0 + 32, lA + nb);
            gload16(ga1 + k0 + 32, lA + nb + 2048);
            gload16(gb0 + k0 + 32, lB + nb);
            gload16(gb1 + k0 + 32, lB + nb + 2048);
        }
        const int cb = cur << 12;
        short8 aF[4], bF[4];
        #pragma unroll
        for (int mf = 0; mf < 4; ++mf)
            aF[mf] = *(const short8*)(As + cb + aoff + mf * 512);
        #pragma unroll
        for (int nf = 0; nf < 4; ++nf)
            bF[nf] = *(const short8*)(Bs + cb + boff + nf * 512);
        #pragma unroll
        for (int mf = 0; mf < 4; ++mf)
            #pragma unroll
            for (int nf = 0; nf < 4; ++nf)
                acc[mf][nf] = __builtin_amdgcn_mfma_f32_16x16x32_bf16(
                    aF[mf], bF[nf], acc[mf][nf], 0, 0, 0);
        __syncthreads();      // drains this iter's prefetch (vmcnt0) + barrier
        cur ^= 1;
    }

    // epilogue: C/D layout col = lane&15, row = (lane>>4)*4 + reg
    #pragma unroll
    for (int mf = 0; mf < 4; ++mf) {
        #pragma unroll
        for (int nf = 0; nf < 4; ++nf) {
            const int col = n0 + wc * 64 + nf * 16 + l15;
            const float bs = bias[col];
            #pragma unroll
            for (int r = 0; r < 4; ++r) {
                const int row = m0 + wr * 64 + mf * 16 + l16 * 4 + r;
                float v = acc[mf][nf][r] + bs;
                if (ACT) v = 0.5f * v * (1.f + erff(v * 0.70710678118654752f));
                if (OUTB) ((unsigned short*)Cout)[(size_t)row * N + col] = f2b(v);
                else      ((float*)Cout)[(size_t)row * N + col] = v;
            }
        }
    }
}

// ---------------------------------------------------------------------------
// weight prep: W[K][N] fp32 -> WT[N][K] bf16  (32x32 LDS tile transpose)
// ---------------------------------------------------------------------------
__global__ __launch_bounds__(256) void transpose_cast_kernel(
    const float* __restrict__ W, unsigned short* __restrict__ WT,
    int K, int N)
{
    __shared__ float t[32][33];
    const int k0 = blockIdx.y * 32;
    const int n0 = blockIdx.x * 32;
    const int tx = threadIdx.x & 31;
    const int ty4 = (threadIdx.x >> 5) << 2;
    #pragma unroll
    for (int i = 0; i < 4; ++i)
        t[ty4 + i][tx] = W[(size_t)(k0 + ty4 + i) * N + n0 + tx];
    __syncthreads();
    #pragma unroll
    for (int i = 0; i < 4; ++i)
        WT[(size_t)(n0 + ty4 + i) * K + k0 + tx] = f2b(t[tx][ty4 + i]);
}

// fused prep for the 8 E x E attention weights (grid.z selects weight)
struct TP8 { const float* src[8]; unsigned short* dst[8]; };
__global__ __launch_bounds__(256) void transpose_cast8_kernel(TP8 p)
{
    __shared__ float t[32][33];
    const int z = blockIdx.z;
    const float* W = p.src[z];
    unsigned short* WT = p.dst[z];
    const int k0 = blockIdx.y * 32;
    const int n0 = blockIdx.x * 32;
    const int tx = threadIdx.x & 31;
    const int ty4 = (threadIdx.x >> 5) << 2;
    #pragma unroll
    for (int i = 0; i < 4; ++i)
        t[ty4 + i][tx] = W[(size_t)(k0 + ty4 + i) * cE + n0 + tx];
    __syncthreads();
    #pragma unroll
    for (int i = 0; i < 4; ++i)
        WT[(size_t)(n0 + ty4 + i) * cE + k0 + tx] = f2b(t[tx][ty4 + i]);
}

// fp32 -> bf16 elementwise (n multiple of 4)
__global__ __launch_bounds__(256) void cast_bf16_kernel(
    const float* __restrict__ in, unsigned short* __restrict__ out, int n4)
{
    for (int i = blockIdx.x * blockDim.x + threadIdx.x; i < n4;
         i += gridDim.x * blockDim.x) {
        float4 v = ((const float4*)in)[i];
        u16x4 o;
        o[0] = f2b(v.x); o[1] = f2b(v.y); o[2] = f2b(v.z); o[3] = f2b(v.w);
        *(u16x4*)(out + (size_t)i * 4) = o;
    }
}

// ---------------------------------------------------------------------------
// residual + layernorm: out = LN(X + R) * gamma + beta; X fp32, R bf16.
// Optional bf16 copy of the result.
// ---------------------------------------------------------------------------
__global__ __launch_bounds__(256) void residual_ln_kernel(
    const float* __restrict__ X, const unsigned short* __restrict__ R,
    const float* __restrict__ gamma, const float* __restrict__ beta,
    float* __restrict__ out, unsigned short* __restrict__ outb)
{
    const int row = blockIdx.x;
    const size_t off = (size_t)row * cE;
    const int tid = threadIdx.x;

    float v[3];
    float s = 0.f, ss = 0.f;
    #pragma unroll
    for (int i = 0; i < 3; ++i) {
        const int e = tid + i * 256;
        const float t = X[off + e] + b2f(R[off + e]);
        v[i] = t; s += t; ss += t * t;
    }
    #pragma unroll
    for (int o = 32; o > 0; o >>= 1) {
        s  += __shfl_down(s, o);
        ss += __shfl_down(ss, o);
    }
    __shared__ float rs[4], rss[4];
    const int wid = tid >> 6;
    if ((tid & 63) == 0) { rs[wid] = s; rss[wid] = ss; }
    __syncthreads();
    s  = rs[0] + rs[1] + rs[2] + rs[3];
    ss = rss[0] + rss[1] + rss[2] + rss[3];

    const float mean = s * (1.f / cE);
    const float var  = ss * (1.f / cE) - mean * mean;
    const float inv  = rsqrtf(var + cEPS);
    #pragma unroll
    for (int i = 0; i < 3; ++i) {
        const int e = tid + i * 256;
        const float r = (v[i] - mean) * inv * gamma[e] + beta[e];
        out[off + e] = r;
        if (outb) outb[off + e] = f2b(r);
    }
}

// ---------------------------------------------------------------------------
// Spatial attention, MFMA flash version (verified round 4).
// ---------------------------------------------------------------------------
__global__ __launch_bounds__(256) void spatial_attn_mfma_kernel(
    const unsigned short* __restrict__ Q, const unsigned short* __restrict__ K,
    const unsigned short* __restrict__ V, unsigned short* __restrict__ O)
{
    __shared__ short Ks[64 * 64];      // [j][d] swizzled, row 128B
    __shared__ short Vt[64 * 64];      // [d][j] swizzled
    __shared__ short Ps[4][64 * 64];   // per-wave [q][j] swizzled

    const int bid = blockIdx.x;        // b*T*H + t*H + h
    const int h  = bid % cH;
    const int bt = bid / cH;
    const size_t base = (size_t)bt * cP * cE + h * cD;

    const int tid = threadIdx.x;
    const int w = tid >> 6, l = tid & 63;
    const int l15 = l & 15, l16 = l >> 4;

    short8 qf[4][2];
    #pragma unroll
    for (int mf = 0; mf < 4; ++mf)
        #pragma unroll
        for (int kf = 0; kf < 2; ++kf)
            qf[mf][kf] = *(const short8*)(
                Q + base + (size_t)(w * 64 + mf * 16 + l15) * cE + kf * 32 + l16 * 8);

    f32x4 o[4][4];
    float mrun[4][4], lrun[4][4];
    #pragma unroll
    for (int mf = 0; mf < 4; ++mf)
        #pragma unroll
        for (int j = 0; j < 4; ++j) {
            #pragma unroll
            for (int r = 0; r < 4; ++r) o[mf][j][r] = 0.f;
            mrun[mf][j] = -INFINITY; lrun[mf][j] = 0.f;
        }

    const int krow = w * 8 + (l >> 3);
    const int kc16 = l & 7;
    const int vj  = tid & 31;
    const int vd0 = (tid >> 5) * 8;

    for (int c0 = 0; c0 < cP; c0 += 64) {
        __syncthreads();
        #pragma unroll
        for (int p = 0; p < 2; ++p) {
            const int row = p * 32 + krow;
            gload16(K + base + (size_t)(c0 + row) * cE + ((kc16 ^ (row & 7)) << 3),
                    Ks + row * 64 + kc16 * 8);
        }
        #pragma unroll
        for (int p = 0; p < 2; ++p) {
            const int j = p * 32 + vj;
            short8 vv = *(const short8*)(V + base + (size_t)(c0 + j) * cE + vd0);
            char* vb = (char*)Vt;
            #pragma unroll
            for (int e = 0; e < 8; ++e) {
                const int row = vd0 + e;
                *(short*)(vb + row * 128 + ((2 * j) ^ ((row & 7) << 4))) = vv[e];
            }
        }
        __syncthreads();

        f32x4 s[4][4];
        #pragma unroll
        for (int mf = 0; mf < 4; ++mf)
            #pragma unroll
            for (int nf = 0; nf < 4; ++nf)
                #pragma unroll
                for (int r = 0; r < 4; ++r) s[mf][nf][r] = 0.f;

        #pragma unroll
        for (int nf = 0; nf < 4; ++nf) {
            const int row = nf * 16 + l15;
            const char* kb = (const char*)Ks + row * 128;
            const int sw = (row & 7) << 4;
            short8 k0 = *(const short8*)(kb + ((l16 * 16) ^ sw));
            short8 k1 = *(const short8*)(kb + ((64 + l16 * 16) ^ sw));
            #pragma unroll
            for (int mf = 0; mf < 4; ++mf) {
                s[mf][nf] = __builtin_amdgcn_mfma_f32_16x16x32_bf16(qf[mf][0], k0, s[mf][nf], 0, 0, 0);
                s[mf][nf] = __builtin_amdgcn_mfma_f32_16x16x32_bf16(qf[mf][1], k1, s[mf][nf], 0, 0, 0);
            }
        }

        #pragma unroll
        for (int mf = 0; mf < 4; ++mf)
            #pragma unroll
            for (int nf = 0; nf < 4; ++nf)
                #pragma unroll
                for (int r = 0; r < 4; ++r) s[mf][nf][r] *= cSCALE;

        #pragma unroll
        for (int mf = 0; mf < 4; ++mf) {
            #pragma unroll
            for (int r = 0; r < 4; ++r) {
                float rv = fmaxf(fmaxf(s[mf][0][r], s[mf][1][r]),
                                 fmaxf(s[mf][2][r], s[mf][3][r]));
                rv = fmaxf(rv, __shfl_xor(rv, 1));
                rv = fmaxf(rv, __shfl_xor(rv, 2));
                rv = fmaxf(rv, __shfl_xor(rv, 4));
                rv = fmaxf(rv, __shfl_xor(rv, 8));
                const float mn = fmaxf(mrun[mf][r], rv);
                const float al = __expf(mrun[mf][r] - mn);
                mrun[mf][r] = mn;
                float ps = 0.f;
                #pragma unroll
                for (int nf = 0; nf < 4; ++nf) {
                    const float pe = __expf(s[mf][nf][r] - mn);
                    s[mf][nf][r] = pe;
                    ps += pe;
                }
                ps += __shfl_xor(ps, 1);
                ps += __shfl_xor(ps, 2);
                ps += __shfl_xor(ps, 4);
                ps += __shfl_xor(ps, 8);
                lrun[mf][r] = lrun[mf][r] * al + ps;
                #pragma unroll
                for (int df = 0; df < 4; ++df) o[mf][df][r] *= al;
            }
        }

        char* pw = (char*)&Ps[w][0];
        #pragma unroll
        for (int mf = 0; mf < 4; ++mf)
            #pragma unroll
            for (int nf = 0; nf < 4; ++nf)
                #pragma unroll
                for (int r = 0; r < 4; ++r) {
                    const int row = mf * 16 + l16 * 4 + r;
                    *(short*)(pw + row * 128 + (((nf * 16 + l15) * 2) ^ ((row & 7) << 4))) =
                        (short)f2b(s[mf][nf][r]);
                }

        short8 pa[4][2];
        #pragma unroll
        for (int mf = 0; mf < 4; ++mf) {
            const int prow = mf * 16 + l15;
            const char* pb = (const char*)&Ps[w][0] + prow * 128;
            const int sw = (prow & 7) << 4;
            pa[mf][0] = *(const short8*)(pb + ((l16 * 16) ^ sw));
            pa[mf][1] = *(const short8*)(pb + ((64 + l16 * 16) ^ sw));
        }
        #pragma unroll
        for (int df = 0; df < 4; ++df) {
            const int vrow = df * 16 + l15;
            const char* vbb = (const char*)Vt + vrow * 128;
            const int sw = (vrow & 7) << 4;
            short8 v0 = *(const short8*)(vbb + ((l16 * 16) ^ sw));
            short8 v1 = *(const short8*)(vbb + ((64 + l16 * 16) ^ sw));
            #pragma unroll
            for (int mf = 0; mf < 4; ++mf) {
                o[mf][df] = __builtin_amdgcn_mfma_f32_16x16x32_bf16(pa[mf][0], v0, o[mf][df], 0, 0, 0);
                o[mf][df] = __builtin_amdgcn_mfma_f32_16x16x32_bf16(pa[mf][1], v1, o[mf][df], 0, 0, 0);
            }
        }
    }

    #pragma unroll
    for (int mf = 0; mf < 4; ++mf)
        #pragma unroll
        for (int r = 0; r < 4; ++r) {
            const float inv = 1.f / lrun[mf][r];
            const size_t rowoff = base + (size_t)(w * 64 + mf * 16 + l16 * 4 + r) * cE;
            #pragma unroll
            for (int df = 0; df < 4; ++df)
                O[rowoff + df * 16 + l15] = f2b(o[mf][df][r] * inv);
        }
}

// ---------------------------------------------------------------------------
// Temporal causal attention (bf16 I/O): per (b,p,head-group of 6). T=16.
// ---------------------------------------------------------------------------
__global__ __launch_bounds__(128) void temporal_attn_kernel(
    const unsigned short* __restrict__ Q, const unsigned short* __restrict__ Kb,
    const unsigned short* __restrict__ V, unsigned short* __restrict__ O)
{
    const int bid = blockIdx.x;          // (b*P + p)*2 + hg
    const int hg  = bid & 1;
    const int bp  = bid >> 1;
    const int p   = bp % cP;
    const int b   = bp / cP;

    __shared__ float Ks[cT][6][cD + 1];
    __shared__ float Vs[cT][6][cD + 1];

    const size_t framestride = (size_t)cP * cE;
    const size_t base0 = ((size_t)(b * cT) * cP + p) * cE + hg * 384;

    for (int li = threadIdx.x; li < cT * 384; li += 128) {
        const int s = li / 384;
        const int r = li % 384;
        const size_t src = base0 + (size_t)s * framestride + r;
        Ks[s][r / 64][r & 63] = b2f(Kb[src]);
        Vs[s][r / 64][r & 63] = b2f(V[src]);
    }
    __syncthreads();
    if (threadIdx.x >= 96) return;

    const int hh = threadIdx.x >> 4;
    const int t  = threadIdx.x & 15;
    const size_t qoff = ((size_t)(b * cT + t) * cP + p) * cE + hg * 384 + hh * cD;

    float q[cD];
    #pragma unroll
    for (int d = 0; d < cD; d += 8) {
        short8 f = *(const short8*)(Q + qoff + d);
        #pragma unroll
        for (int j = 0; j < 8; ++j) q[d + j] = b2f((unsigned short)f[j]);
    }

    float sc[cT];
    float mx = -INFINITY;
    #pragma unroll
    for (int s = 0; s < cT; ++s) {
        float acc = 0.f;
        #pragma unroll
        for (int d = 0; d < cD; ++d) acc = fmaf(q[d], Ks[s][hh][d], acc);
        sc[s] = (s <= t) ? acc * cSCALE : -INFINITY;
        mx = fmaxf(mx, sc[s]);
    }
    float l = 0.f;
    #pragma unroll
    for (int s = 0; s < cT; ++s) {
        const float e_ = __expf(sc[s] - mx);
        sc[s] = e_;
        l += e_;
    }
    float o[cD];
    #pragma unroll
    for (int d = 0; d < cD; ++d) o[d] = 0.f;
    #pragma unroll
    for (int s = 0; s < cT; ++s) {
        const float pj = sc[s];
        #pragma unroll
        for (int d = 0; d < cD; ++d) o[d] = fmaf(pj, Vs[s][hh][d], o[d]);
    }
    const float invl = 1.f / l;
    unsigned short* op = O + qoff;
    #pragma unroll
    for (int d = 0; d < cD; d += 8) {
        u16x8 f;
        #pragma unroll
        for (int j = 0; j < 8; ++j) f[j] = f2b(o[d + j] * invl);
        *(u16x8*)(op + d) = f;
    }
}

// ---------------------------------------------------------------------------
extern "C" void kernel_launch(void* const* d_in, const int* in_sizes, int n_in,
                              void* d_out, int out_size, void* d_ws, size_t ws_size,
                              hipStream_t stream)
{
    const float* x    = (const float*)d_in[0];
    const float* sq_w = (const float*)d_in[1];
    const float* sk_w = (const float*)d_in[2];
    const float* sv_w = (const float*)d_in[3];
    const float* so_w = (const float*)d_in[4];
    const float* sq_b = (const float*)d_in[5];
    const float* sk_b = (const float*)d_in[6];
    const float* sv_b = (const float*)d_in[7];
    const float* so_b = (const float*)d_in[8];
    const float* sg   = (const float*)d_in[9];
    const float* sb   = (const float*)d_in[10];
    const float* tq_w = (const float*)d_in[11];
    const float* tk_w = (const float*)d_in[12];
    const float* tv_w = (const float*)d_in[13];
    const float* to_w = (const float*)d_in[14];
    const float* tq_b = (const float*)d_in[15];
    const float* tk_b = (const float*)d_in[16];
    const float* tv_b = (const float*)d_in[17];
    const float* to_b = (const float*)d_in[18];
    const float* tg   = (const float*)d_in[19];
    const float* tb   = (const float*)d_in[20];
    const float* w1   = (const float*)d_in[21];
    const float* b1   = (const float*)d_in[22];
    const float* w2   = (const float*)d_in[23];
    const float* b2   = (const float*)d_in[24];
    const float* g    = (const float*)d_in[25];
    const float* bb   = (const float*)d_in[26];

    const size_t NE = (size_t)NTOK * cE;   // 12.58M elements
    const size_t EE = (size_t)cE * cE;     // 589824

    // workspace layout (~245 MB)
    float* W0 = (float*)d_ws;                    // fp32 residual stream [NE]
    float* Wp = W0 + NE;                         // region reused as bf16 R [NE]
    unsigned short* Rb = (unsigned short*)Wp;    // bf16 projection/FFN output
    unsigned short* Xb = (unsigned short*)(Wp + NE);  // bf16 x_cur [NE]
    unsigned short* Qb = Xb + NE;
    unsigned short* Kbuf = Qb + NE;
    unsigned short* Vb = Kbuf + NE;
    unsigned short* Ob = Vb + NE;
    unsigned short* Hb = Qb;                     // bf16 hidden [NTOK*DFF] overlays Qb..Ob
    unsigned short* WT = Ob + NE;                // bf16 transposed weights
    unsigned short* sqT = WT;                    // [sq;sk;sv] contiguous -> QKV fused B
    unsigned short* skT = sqT + EE;
    unsigned short* svT = skT + EE;
    unsigned short* soT = svT + EE;
    unsigned short* tqT = soT + EE;              // [tq;tk;tv] contiguous
    unsigned short* tkT = tqT + EE;
    unsigned short* tvT = tkT + EE;
    unsigned short* toT = tvT + EE;
    unsigned short* w1T = toT + EE;              // [DFF][E]
    unsigned short* w2T = w1T + (size_t)cDFF * cE;  // [E][DFF]

    const dim3 blk(256);
    const dim3 blk512(512);
    const dim3 gLN(NTOK);
    const dim3 gQKV(1152);               // 64 M-blocks * 18 N-blocks (256x128)
    const dim3 gFF1(1536);               // 64 * 24 (256x128)
    const dim3 g128(cE / 128, NTOK / 128);   // (6, 128) = 768 blocks (128x128)

    // ---- prep: cast x, transpose+cast all weights to bf16 [N][K] ----
    cast_bf16_kernel<<<dim3(2048), blk, 0, stream>>>(x, Xb, (int)(NE / 4));
    {
        TP8 p;
        p.src[0] = sq_w; p.dst[0] = sqT;
        p.src[1] = sk_w; p.dst[1] = skT;
        p.src[2] = sv_w; p.dst[2] = svT;
        p.src[3] = so_w; p.dst[3] = soT;
        p.src[4] = tq_w; p.dst[4] = tqT;
        p.src[5] = tk_w; p.dst[5] = tkT;
        p.src[6] = tv_w; p.dst[6] = tvT;
        p.src[7] = to_w; p.dst[7] = toT;
        transpose_cast8_kernel<<<dim3(cE / 32, cE / 32, 8), blk, 0, stream>>>(p);
    }
    transpose_cast_kernel<<<dim3(cDFF / 32, cE / 32), blk, 0, stream>>>(w1, w1T, cE, cDFF);
    transpose_cast_kernel<<<dim3(cE / 32, cDFF / 32), blk, 0, stream>>>(w2, w2T, cDFF, cE);

    // ---- Spatial attention block ----
    gemm256_kernel<1,0,1><<<gQKV, blk512, 0, stream>>>(
        Xb, sqT, sq_b, sk_b, sv_b, Qb, Kbuf, Vb, NTOK, 2304, cE, 18);
    spatial_attn_mfma_kernel<<<dim3(cB * cT * cH), blk, 0, stream>>>(Qb, Kbuf, Vb, Ob);
    gemm128_kernel<1,0><<<g128, blk, 0, stream>>>(Ob, soT, so_b, Rb, NTOK, cE, cE);
    residual_ln_kernel<<<gLN, blk, 0, stream>>>(x, Rb, sg, sb, W0, Xb);

    // ---- Temporal attention block ----
    gemm256_kernel<1,0,1><<<gQKV, blk512, 0, stream>>>(
        Xb, tqT, tq_b, tk_b, tv_b, Qb, Kbuf, Vb, NTOK, 2304, cE, 18);
    temporal_attn_kernel<<<dim3(cB * cP * 2), dim3(128), 0, stream>>>(Qb, Kbuf, Vb, Ob);
    gemm128_kernel<1,0><<<g128, blk, 0, stream>>>(Ob, toT, to_b, Rb, NTOK, cE, cE);
    residual_ln_kernel<<<gLN, blk, 0, stream>>>(W0, Rb, tg, tb, W0, Xb);

    // ---- FFN ----
    gemm256_kernel<1,1,0><<<gFF1, blk512, 0, stream>>>(
        Xb, w1T, b1, nullptr, nullptr, Hb, nullptr, nullptr, NTOK, cDFF, cE, 24);
    gemm128_kernel<1,0><<<g128, blk, 0, stream>>>(Hb, w2T, b2, Rb, NTOK, cE, cDFF);
    residual_ln_kernel<<<gLN, blk, 0, stream>>>(W0, Rb, g, bb, (float*)d_out, nullptr);
}

// Round 12
// 705.518 us; speedup vs baseline: 1.1428x; 1.0081x over previous
//
#include <hip/hip_runtime.h>
#include <math.h>

// Problem constants
constexpr int cB   = 4;
constexpr int cT   = 16;
constexpr int cP   = 256;
constexpr int cE   = 768;
constexpr int cH   = 12;
constexpr int cD   = 64;
constexpr int cDFF = 3072;
constexpr int NTOK = cB * cT * cP;        // 16384
constexpr float cSCALE = 0.125f;          // 64^-0.5
constexpr float cEPS = 1e-5f;

typedef __attribute__((ext_vector_type(8))) short short8;
typedef __attribute__((ext_vector_type(4))) float f32x4;
typedef __attribute__((ext_vector_type(8))) unsigned short u16x8;
typedef __attribute__((ext_vector_type(4))) unsigned short u16x4;

#define AS1 __attribute__((address_space(1)))
#define AS3 __attribute__((address_space(3)))

__device__ inline float b2f(unsigned short u) {
    union { unsigned int i; float f; } c; c.i = ((unsigned int)u) << 16; return c.f;
}
__device__ inline unsigned short f2b(float f) {
    union { float f; unsigned int i; } c; c.f = f;
    unsigned int i = c.i;
    unsigned int r = i + 0x7FFFu + ((i >> 16) & 1u);   // RNE
    return (unsigned short)(r >> 16);
}

__device__ inline void gload16(const unsigned short* g, short* l) {
    __builtin_amdgcn_global_load_lds((AS1 const void*)g, (AS3 void*)l, 16, 0, 0);
}

// ---------------------------------------------------------------------------
// PERSISTENT 256x128 MFMA GEMM (r12): grid = 256 blocks; each block owns a
// contiguous chunk of output tiles (bm-major -> consecutive tiles share the
// A-panel in L2) and runs ONE continuous 3-buffer pipeline across
// tcount*nt K-steps. One prologue per BLOCK (not per tile); epilogues are
// interior events overlapped by in-flight staging. Counted-vmcnt ledger
// preserved across tile boundaries: boundary step's vmcnt(6) retires the 6
// needed loads + most of the 64 epilogue stores; deferred g+2 stage issued
// post-barrier; next step's vmcnt(6) retires leftover stores + g+2.
// r7 schedule core: BK=64, 8 waves (4M x 2N), T2 swizzle, T5 setprio,
// lgkm(8)/lgkm(0) split MFMA, ONE barrier per K-step.
// SPLIT3: N=2304 QKV fusion. OUTB: bf16/fp32 out. ACT: exact GELU.
// ---------------------------------------------------------------------------
template<int OUTB, int ACT, int SPLIT3>
__global__ __launch_bounds__(512, 1) void gemm256p_kernel(
    const unsigned short* __restrict__ A,   // [M][K] bf16
    const unsigned short* __restrict__ BT,  // [N][K] bf16
    const float* __restrict__ bias0, const float* __restrict__ bias1,
    const float* __restrict__ bias2,
    void* __restrict__ C0, void* __restrict__ C1, void* __restrict__ C2,
    int M, int N, int K, int nbn, int ntiles)
{
    __shared__ short LDS[3 * 24576];   // 144 KiB: 3 x (A[256][64] + B[128][64])

    const int tid = threadIdx.x;
    const int w = tid >> 6, l = tid & 63;
    const int l15 = l & 15, l16 = l >> 4;
    const int wm = w >> 1, wn = w & 1;      // 4 M-waves x 2 N-waves
    const int srow = l >> 3;
    const int sslot = l & 7;

    // bijective XCD swizzle + balanced contiguous chunk of tiles
    const int nblk = gridDim.x;
    const int blk = (blockIdx.x & 7) * (nblk >> 3) + (blockIdx.x >> 3);
    const int q = ntiles / nblk, r = ntiles % nblk;
    const int t0 = blk * q + (blk < r ? blk : r);
    const int tcount = q + (blk < r ? 1 : 0);
    const int nt = K >> 6;
    const int total = tcount * nt;
    if (total == 0) return;

    f32x4 acc[4][4];
    #pragma unroll
    for (int i = 0; i < 4; ++i)
        #pragma unroll
        for (int j = 0; j < 4; ++j)
            #pragma unroll
            for (int rr = 0; rr < 4; ++rr) acc[i][j][rr] = 0.f;

    // lane-constant staging offsets (elements) + LDS dest offsets
    size_t laneA[4]; int dAo[4];
    #pragma unroll
    for (int j = 0; j < 4; ++j) {
        const int rr = w * 32 + j * 8 + srow;
        laneA[j] = (size_t)rr * K + ((sslot ^ (rr & 7)) << 3);
        dAo[j] = rr * 64 + (sslot << 3);
    }
    size_t laneB[2]; int dBo[2];
    #pragma unroll
    for (int j = 0; j < 2; ++j) {
        const int rr = w * 8 + j * 64 + srow;
        laneB[j] = (size_t)rr * K + ((sslot ^ (rr & 7)) << 3);
        dBo[j] = 16384 + rr * 64 + (sslot << 3);
    }

    // hoisted ds_read byte offsets (relative to buffer base)
    int offA[4][2], offB[4][2];
    #pragma unroll
    for (int mm = 0; mm < 4; ++mm) {
        const int ra = wm * 64 + mm * 16 + l15;
        const int sw = (ra & 7) << 4;
        offA[mm][0] = ra * 128 + ((l16 * 16) ^ sw);
        offA[mm][1] = ra * 128 + ((64 + l16 * 16) ^ sw);
    }
    #pragma unroll
    for (int nf = 0; nf < 4; ++nf) {
        const int rb = wn * 64 + nf * 16 + l15;
        const int sw = (rb & 7) << 4;
        offB[nf][0] = 32768 + rb * 128 + ((l16 * 16) ^ sw);
        offB[nf][1] = 32768 + rb * 128 + ((64 + l16 * 16) ^ sw);
    }

    // staging cursor (advances through tile boundaries, no division in loop)
    int s_bm = t0 / nbn, s_bn = t0 % nbn, s_kt = 0;
    size_t sAb = (size_t)s_bm * 256 * K;
    size_t sBb = (size_t)s_bn * 128 * K;

    #define STAGE(buf_)                                                       \
        {                                                                     \
            const unsigned short* a_ = A + sAb + s_kt * 64;                   \
            const unsigned short* b_ = BT + sBb + s_kt * 64;                  \
            short* d_ = LDS + (buf_) * 24576;                                 \
            _Pragma("unroll")                                                 \
            for (int j_ = 0; j_ < 4; ++j_) gload16(a_ + laneA[j_], d_ + dAo[j_]); \
            _Pragma("unroll")                                                 \
            for (int j_ = 0; j_ < 2; ++j_) gload16(b_ + laneB[j_], d_ + dBo[j_]); \
            if (++s_kt == nt) {                                               \
                s_kt = 0;                                                     \
                if (++s_bn == nbn) { s_bn = 0; sBb = 0; sAb += (size_t)256 * K; } \
                else sBb += (size_t)128 * K;                                  \
            }                                                                 \
        }

    // prologue: stage global steps 0 and 1; retire step 0 only
    STAGE(0);
    STAGE(1);
    asm volatile("s_waitcnt vmcnt(6)" ::: "memory");
    __builtin_amdgcn_s_barrier();

    // compute cursor
    int cbm = t0 / nbn, cbn = t0 % nbn, ckt = 0;
    int buf = 0;

    for (int g = 0; g < total; ++g) {
        const char* Lb = (const char*)LDS + buf * 49152;
        const bool boundary = (ckt == nt - 1);

        short8 aF[4][2], bF[4][2];
        #pragma unroll
        for (int mm = 0; mm < 4; ++mm)
            aF[mm][0] = *(const short8*)(Lb + offA[mm][0]);
        #pragma unroll
        for (int nf = 0; nf < 4; ++nf)
            bF[nf][0] = *(const short8*)(Lb + offB[nf][0]);
        __builtin_amdgcn_sched_barrier(0);
        #pragma unroll
        for (int mm = 0; mm < 4; ++mm)
            aF[mm][1] = *(const short8*)(Lb + offA[mm][1]);
        #pragma unroll
        for (int nf = 0; nf < 4; ++nf)
            bF[nf][1] = *(const short8*)(Lb + offB[nf][1]);

        // normal steps: stage g+2 before MFMA (boundary steps defer it)
        if (!boundary && g + 2 < total) {
            const int b2 = (buf == 0) ? 2 : buf - 1;
            STAGE(b2);
        }

        asm volatile("s_waitcnt lgkmcnt(8)" ::: "memory");
        __builtin_amdgcn_sched_barrier(0);
        __builtin_amdgcn_s_setprio(1);
        #pragma unroll
        for (int nf = 0; nf < 4; ++nf)
            #pragma unroll
            for (int mm = 0; mm < 4; ++mm)
                acc[mm][nf] = __builtin_amdgcn_mfma_f32_16x16x32_bf16(
                    aF[mm][0], bF[nf][0], acc[mm][nf], 0, 0, 0);
        __builtin_amdgcn_s_setprio(0);
        asm volatile("s_waitcnt lgkmcnt(0)" ::: "memory");
        __builtin_amdgcn_sched_barrier(0);
        __builtin_amdgcn_s_setprio(1);
        #pragma unroll
        for (int nf = 0; nf < 4; ++nf)
            #pragma unroll
            for (int mm = 0; mm < 4; ++mm)
                acc[mm][nf] = __builtin_amdgcn_mfma_f32_16x16x32_bf16(
                    aF[mm][1], bF[nf][1], acc[mm][nf], 0, 0, 0);
        __builtin_amdgcn_s_setprio(0);

        if (boundary) {
            // ---- epilogue for tile (cbm, cbn); overlapped with pipeline ----
            const int m0 = cbm * 256;
            const int n0c = cbn * 128;
            #pragma unroll
            for (int mf = 0; mf < 4; ++mf) {
                #pragma unroll
                for (int nf = 0; nf < 4; ++nf) {
                    const int ng = n0c + wn * 64 + nf * 16 + l15;
                    int nl = ng;
                    const float* bp = bias0;
                    void* Cp = C0;
                    int Nout = N;
                    if (SPLIT3) {
                        const int which = ng / 768;
                        nl = ng - which * 768;
                        bp = (which == 0) ? bias0 : (which == 1) ? bias1 : bias2;
                        Cp = (which == 0) ? C0 : (which == 1) ? C1 : C2;
                        Nout = 768;
                    }
                    const float bs = bp[nl];
                    #pragma unroll
                    for (int rr = 0; rr < 4; ++rr) {
                        const int row = m0 + wm * 64 + mf * 16 + l16 * 4 + rr;
                        float v = acc[mf][nf][rr] + bs;
                        if (ACT) v = 0.5f * v * (1.f + erff(v * 0.70710678118654752f));
                        if (OUTB) ((unsigned short*)Cp)[(size_t)row * Nout + nl] = f2b(v);
                        else      ((float*)Cp)[(size_t)row * Nout + nl] = v;
                        acc[mf][nf][rr] = 0.f;
                    }
                }
            }
            if (g + 1 < total) {
                // outstanding: loads(g+1)=6 (oldest) + ~64 stores ->
                // vmcnt(6) retires the 6 needed loads + most stores
                asm volatile("s_waitcnt vmcnt(6)" ::: "memory");
                __builtin_amdgcn_s_barrier();
                if (g + 2 < total) {
                    const int b2 = (buf == 0) ? 2 : buf - 1;
                    STAGE(b2);
                }
            }
            ckt = 0;
            if (++cbn == nbn) { cbn = 0; ++cbm; }
        } else {
            if (g + 1 < total) {
                if (g + 2 < total)
                    asm volatile("s_waitcnt vmcnt(6)" ::: "memory");
                else
                    asm volatile("s_waitcnt vmcnt(0)" ::: "memory");
                __builtin_amdgcn_s_barrier();
            }
            ++ckt;
        }
        buf = (buf == 2) ? 0 : buf + 1;
    }
    #undef STAGE
}

// ---------------------------------------------------------------------------
// 128x128 MFMA GEMM (r5 structure, proven): used for OUT-proj x2 and FFN2.
// ---------------------------------------------------------------------------
template<int OUTB, int ACT>
__global__ __launch_bounds__(256) void gemm128_kernel(
    const unsigned short* __restrict__ A,   // [M][K] bf16
    const unsigned short* __restrict__ BT,  // [N][K] bf16
    const float* __restrict__ bias,         // [N]
    void* __restrict__ Cout,
    int M, int N, int K)
{
    __shared__ short As[8192];   // 2 x [128][32] bf16
    __shared__ short Bs[8192];

    const int tid = threadIdx.x;
    const int m0 = blockIdx.y * 128;
    const int n0 = blockIdx.x * 128;
    const int w  = tid >> 6;
    const int l  = tid & 63;
    const int wr = w >> 1, wc = w & 1;
    const int l15 = l & 15, l16 = l >> 4;

    f32x4 acc[4][4];
    #pragma unroll
    for (int i = 0; i < 4; ++i)
        #pragma unroll
        for (int j = 0; j < 4; ++j)
            #pragma unroll
            for (int r = 0; r < 4; ++r) acc[i][j][r] = 0.f;

    const int sr = tid >> 2;
    const int sc = (tid & 3) << 3;
    const unsigned short* ga0 = A  + (size_t)(m0 + sr) * K + sc;
    const unsigned short* ga1 = A  + (size_t)(m0 + 64 + sr) * K + sc;
    const unsigned short* gb0 = BT + (size_t)(n0 + sr) * K + sc;
    const unsigned short* gb1 = BT + (size_t)(n0 + 64 + sr) * K + sc;
    short* lA = As + tid * 8;
    short* lB = Bs + tid * 8;

    const int aoff = (wr * 64 + l15) * 32 + l16 * 8;
    const int boff = (wc * 64 + l15) * 32 + l16 * 8;

    gload16(ga0, lA);
    gload16(ga1, lA + 2048);
    gload16(gb0, lB);
    gload16(gb1, lB + 2048);
    __syncthreads();

    int cur = 0;
    for (int k0 = 0; k0 < K; k0 += 32) {
        if (k0 + 32 < K) {
            const int nb = (cur ^ 1) << 12;
            gload16(ga0 + k0 + 32, lA + nb);
            gload16(ga1 + k0 + 32, lA + nb + 2048);
            gload16(gb0 + k0 + 32, lB + nb);
            gload16(gb1 + k0 + 32, lB + nb + 2048);
        }
        const int cb = cur << 12;
        short8 aF[4], bF[4];
        #pragma unroll
        for (int mf = 0; mf < 4; ++mf)
            aF[mf] = *(const short8*)(As + cb + aoff + mf * 512);
        #pragma unroll
        for (int nf = 0; nf < 4; ++nf)
            bF[nf] = *(const short8*)(Bs + cb + boff + nf * 512);
        #pragma unroll
        for (int mf = 0; mf < 4; ++mf)
            #pragma unroll
            for (int nf = 0; nf < 4; ++nf)
                acc[mf][nf] = __builtin_amdgcn_mfma_f32_16x16x32_bf16(
                    aF[mf], bF[nf], acc[mf][nf], 0, 0, 0);
        __syncthreads();
        cur ^= 1;
    }

    #pragma unroll
    for (int mf = 0; mf < 4; ++mf) {
        #pragma unroll
        for (int nf = 0; nf < 4; ++nf) {
            const int col = n0 + wc * 64 + nf * 16 + l15;
            const float bs = bias[col];
            #pragma unroll
            for (int r = 0; r < 4; ++r) {
                const int row = m0 + wr * 64 + mf * 16 + l16 * 4 + r;
                float v = acc[mf][nf][r] + bs;
                if (ACT) v = 0.5f * v * (1.f + erff(v * 0.70710678118654752f));
                if (OUTB) ((unsigned short*)Cout)[(size_t)row * N + col] = f2b(v);
                else      ((float*)Cout)[(size_t)row * N + col] = v;
            }
        }
    }
}

// ---------------------------------------------------------------------------
// weight prep: W[K][N] fp32 -> WT[N][K] bf16  (32x32 LDS tile transpose)
// ---------------------------------------------------------------------------
__global__ __launch_bounds__(256) void transpose_cast_kernel(
    const float* __restrict__ W, unsigned short* __restrict__ WT,
    int K, int N)
{
    __shared__ float t[32][33];
    const int k0 = blockIdx.y * 32;
    const int n0 = blockIdx.x * 32;
    const int tx = threadIdx.x & 31;
    const int ty4 = (threadIdx.x >> 5) << 2;
    #pragma unroll
    for (int i = 0; i < 4; ++i)
        t[ty4 + i][tx] = W[(size_t)(k0 + ty4 + i) * N + n0 + tx];
    __syncthreads();
    #pragma unroll
    for (int i = 0; i < 4; ++i)
        WT[(size_t)(n0 + ty4 + i) * K + k0 + tx] = f2b(t[tx][ty4 + i]);
}

// fused prep for the 8 E x E attention weights (grid.z selects weight)
struct TP8 { const float* src[8]; unsigned short* dst[8]; };
__global__ __launch_bounds__(256) void transpose_cast8_kernel(TP8 p)
{
    __shared__ float t[32][33];
    const int z = blockIdx.z;
    const float* W = p.src[z];
    unsigned short* WT = p.dst[z];
    const int k0 = blockIdx.y * 32;
    const int n0 = blockIdx.x * 32;
    const int tx = threadIdx.x & 31;
    const int ty4 = (threadIdx.x >> 5) << 2;
    #pragma unroll
    for (int i = 0; i < 4; ++i)
        t[ty4 + i][tx] = W[(size_t)(k0 + ty4 + i) * cE + n0 + tx];
    __syncthreads();
    #pragma unroll
    for (int i = 0; i < 4; ++i)
        WT[(size_t)(n0 + ty4 + i) * cE + k0 + tx] = f2b(t[tx][ty4 + i]);
}

// fp32 -> bf16 elementwise (n multiple of 4)
__global__ __launch_bounds__(256) void cast_bf16_kernel(
    const float* __restrict__ in, unsigned short* __restrict__ out, int n4)
{
    for (int i = blockIdx.x * blockDim.x + threadIdx.x; i < n4;
         i += gridDim.x * blockDim.x) {
        float4 v = ((const float4*)in)[i];
        u16x4 o;
        o[0] = f2b(v.x); o[1] = f2b(v.y); o[2] = f2b(v.z); o[3] = f2b(v.w);
        *(u16x4*)(out + (size_t)i * 4) = o;
    }
}

// ---------------------------------------------------------------------------
// residual + layernorm: out = LN(X + R) * gamma + beta; X fp32, R bf16.
// ---------------------------------------------------------------------------
__global__ __launch_bounds__(256) void residual_ln_kernel(
    const float* __restrict__ X, const unsigned short* __restrict__ R,
    const float* __restrict__ gamma, const float* __restrict__ beta,
    float* __restrict__ out, unsigned short* __restrict__ outb)
{
    const int row = blockIdx.x;
    const size_t off = (size_t)row * cE;
    const int tid = threadIdx.x;

    float v[3];
    float s = 0.f, ss = 0.f;
    #pragma unroll
    for (int i = 0; i < 3; ++i) {
        const int e = tid + i * 256;
        const float t = X[off + e] + b2f(R[off + e]);
        v[i] = t; s += t; ss += t * t;
    }
    #pragma unroll
    for (int o = 32; o > 0; o >>= 1) {
        s  += __shfl_down(s, o);
        ss += __shfl_down(ss, o);
    }
    __shared__ float rs[4], rss[4];
    const int wid = tid >> 6;
    if ((tid & 63) == 0) { rs[wid] = s; rss[wid] = ss; }
    __syncthreads();
    s  = rs[0] + rs[1] + rs[2] + rs[3];
    ss = rss[0] + rss[1] + rss[2] + rss[3];

    const float mean = s * (1.f / cE);
    const float var  = ss * (1.f / cE) - mean * mean;
    const float inv  = rsqrtf(var + cEPS);
    #pragma unroll
    for (int i = 0; i < 3; ++i) {
        const int e = tid + i * 256;
        const float r = (v[i] - mean) * inv * gamma[e] + beta[e];
        out[off + e] = r;
        if (outb) outb[off + e] = f2b(r);
    }
}

// ---------------------------------------------------------------------------
// Spatial attention, MFMA flash version (verified round 4).
// ---------------------------------------------------------------------------
__global__ __launch_bounds__(256) void spatial_attn_mfma_kernel(
    const unsigned short* __restrict__ Q, const unsigned short* __restrict__ K,
    const unsigned short* __restrict__ V, unsigned short* __restrict__ O)
{
    __shared__ short Ks[64 * 64];      // [j][d] swizzled, row 128B
    __shared__ short Vt[64 * 64];      // [d][j] swizzled
    __shared__ short Ps[4][64 * 64];   // per-wave [q][j] swizzled

    const int bid = blockIdx.x;        // b*T*H + t*H + h
    const int h  = bid % cH;
    const int bt = bid / cH;
    const size_t base = (size_t)bt * cP * cE + h * cD;

    const int tid = threadIdx.x;
    const int w = tid >> 6, l = tid & 63;
    const int l15 = l & 15, l16 = l >> 4;

    short8 qf[4][2];
    #pragma unroll
    for (int mf = 0; mf < 4; ++mf)
        #pragma unroll
        for (int kf = 0; kf < 2; ++kf)
            qf[mf][kf] = *(const short8*)(
                Q + base + (size_t)(w * 64 + mf * 16 + l15) * cE + kf * 32 + l16 * 8);

    f32x4 o[4][4];
    float mrun[4][4], lrun[4][4];
    #pragma unroll
    for (int mf = 0; mf < 4; ++mf)
        #pragma unroll
        for (int j = 0; j < 4; ++j) {
            #pragma unroll
            for (int r = 0; r < 4; ++r) o[mf][j][r] = 0.f;
            mrun[mf][j] = -INFINITY; lrun[mf][j] = 0.f;
        }

    const int krow = w * 8 + (l >> 3);
    const int kc16 = l & 7;
    const int vj  = tid & 31;
    const int vd0 = (tid >> 5) * 8;

    for (int c0 = 0; c0 < cP; c0 += 64) {
        __syncthreads();
        #pragma unroll
        for (int p = 0; p < 2; ++p) {
            const int row = p * 32 + krow;
            gload16(K + base + (size_t)(c0 + row) * cE + ((kc16 ^ (row & 7)) << 3),
                    Ks + row * 64 + kc16 * 8);
        }
        #pragma unroll
        for (int p = 0; p < 2; ++p) {
            const int j = p * 32 + vj;
            short8 vv = *(const short8*)(V + base + (size_t)(c0 + j) * cE + vd0);
            char* vb = (char*)Vt;
            #pragma unroll
            for (int e = 0; e < 8; ++e) {
                const int row = vd0 + e;
                *(short*)(vb + row * 128 + ((2 * j) ^ ((row & 7) << 4))) = vv[e];
            }
        }
        __syncthreads();

        f32x4 s[4][4];
        #pragma unroll
        for (int mf = 0; mf < 4; ++mf)
            #pragma unroll
            for (int nf = 0; nf < 4; ++nf)
                #pragma unroll
                for (int r = 0; r < 4; ++r) s[mf][nf][r] = 0.f;

        #pragma unroll
        for (int nf = 0; nf < 4; ++nf) {
            const int row = nf * 16 + l15;
            const char* kb = (const char*)Ks + row * 128;
            const int sw = (row & 7) << 4;
            short8 k0 = *(const short8*)(kb + ((l16 * 16) ^ sw));
            short8 k1 = *(const short8*)(kb + ((64 + l16 * 16) ^ sw));
            #pragma unroll
            for (int mf = 0; mf < 4; ++mf) {
                s[mf][nf] = __builtin_amdgcn_mfma_f32_16x16x32_bf16(qf[mf][0], k0, s[mf][nf], 0, 0, 0);
                s[mf][nf] = __builtin_amdgcn_mfma_f32_16x16x32_bf16(qf[mf][1], k1, s[mf][nf], 0, 0, 0);
            }
        }

        #pragma unroll
        for (int mf = 0; mf < 4; ++mf)
            #pragma unroll
            for (int nf = 0; nf < 4; ++nf)
                #pragma unroll
                for (int r = 0; r < 4; ++r) s[mf][nf][r] *= cSCALE;

        #pragma unroll
        for (int mf = 0; mf < 4; ++mf) {
            #pragma unroll
            for (int r = 0; r < 4; ++r) {
                float rv = fmaxf(fmaxf(s[mf][0][r], s[mf][1][r]),
                                 fmaxf(s[mf][2][r], s[mf][3][r]));
                rv = fmaxf(rv, __shfl_xor(rv, 1));
                rv = fmaxf(rv, __shfl_xor(rv, 2));
                rv = fmaxf(rv, __shfl_xor(rv, 4));
                rv = fmaxf(rv, __shfl_xor(rv, 8));
                const float mn = fmaxf(mrun[mf][r], rv);
                const float al = __expf(mrun[mf][r] - mn);
                mrun[mf][r] = mn;
                float ps = 0.f;
                #pragma unroll
                for (int nf = 0; nf < 4; ++nf) {
                    const float pe = __expf(s[mf][nf][r] - mn);
                    s[mf][nf][r] = pe;
                    ps += pe;
                }
                ps += __shfl_xor(ps, 1);
                ps += __shfl_xor(ps, 2);
                ps += __shfl_xor(ps, 4);
                ps += __shfl_xor(ps, 8);
                lrun[mf][r] = lrun[mf][r] * al + ps;
                #pragma unroll
                for (int df = 0; df < 4; ++df) o[mf][df][r] *= al;
            }
        }

        char* pw = (char*)&Ps[w][0];
        #pragma unroll
        for (int mf = 0; mf < 4; ++mf)
            #pragma unroll
            for (int nf = 0; nf < 4; ++nf)
                #pragma unroll
                for (int r = 0; r < 4; ++r) {
                    const int row = mf * 16 + l16 * 4 + r;
                    *(short*)(pw + row * 128 + (((nf * 16 + l15) * 2) ^ ((row & 7) << 4))) =
                        (short)f2b(s[mf][nf][r]);
                }

        short8 pa[4][2];
        #pragma unroll
        for (int mf = 0; mf < 4; ++mf) {
            const int prow = mf * 16 + l15;
            const char* pb = (const char*)&Ps[w][0] + prow * 128;
            const int sw = (prow & 7) << 4;
            pa[mf][0] = *(const short8*)(pb + ((l16 * 16) ^ sw));
            pa[mf][1] = *(const short8*)(pb + ((64 + l16 * 16) ^ sw));
        }
        #pragma unroll
        for (int df = 0; df < 4; ++df) {
            const int vrow = df * 16 + l15;
            const char* vbb = (const char*)Vt + vrow * 128;
            const int sw = (vrow & 7) << 4;
            short8 v0 = *(const short8*)(vbb + ((l16 * 16) ^ sw));
            short8 v1 = *(const short8*)(vbb + ((64 + l16 * 16) ^ sw));
            #pragma unroll
            for (int mf = 0; mf < 4; ++mf) {
                o[mf][df] = __builtin_amdgcn_mfma_f32_16x16x32_bf16(pa[mf][0], v0, o[mf][df], 0, 0, 0);
                o[mf][df] = __builtin_amdgcn_mfma_f32_16x16x32_bf16(pa[mf][1], v1, o[mf][df], 0, 0, 0);
            }
        }
    }

    #pragma unroll
    for (int mf = 0; mf < 4; ++mf)
        #pragma unroll
        for (int r = 0; r < 4; ++r) {
            const float inv = 1.f / lrun[mf][r];
            const size_t rowoff = base + (size_t)(w * 64 + mf * 16 + l16 * 4 + r) * cE;
            #pragma unroll
            for (int df = 0; df < 4; ++df)
                O[rowoff + df * 16 + l15] = f2b(o[mf][df][r] * inv);
        }
}

// ---------------------------------------------------------------------------
// Temporal causal attention (bf16 I/O): per (b,p,head-group of 6). T=16.
// ---------------------------------------------------------------------------
__global__ __launch_bounds__(128) void temporal_attn_kernel(
    const unsigned short* __restrict__ Q, const unsigned short* __restrict__ Kb,
    const unsigned short* __restrict__ V, unsigned short* __restrict__ O)
{
    const int bid = blockIdx.x;          // (b*P + p)*2 + hg
    const int hg  = bid & 1;
    const int bp  = bid >> 1;
    const int p   = bp % cP;
    const int b   = bp / cP;

    __shared__ float Ks[cT][6][cD + 1];
    __shared__ float Vs[cT][6][cD + 1];

    const size_t framestride = (size_t)cP * cE;
    const size_t base0 = ((size_t)(b * cT) * cP + p) * cE + hg * 384;

    for (int li = threadIdx.x; li < cT * 384; li += 128) {
        const int s = li / 384;
        const int r = li % 384;
        const size_t src = base0 + (size_t)s * framestride + r;
        Ks[s][r / 64][r & 63] = b2f(Kb[src]);
        Vs[s][r / 64][r & 63] = b2f(V[src]);
    }
    __syncthreads();
    if (threadIdx.x >= 96) return;

    const int hh = threadIdx.x >> 4;
    const int t  = threadIdx.x & 15;
    const size_t qoff = ((size_t)(b * cT + t) * cP + p) * cE + hg * 384 + hh * cD;

    float q[cD];
    #pragma unroll
    for (int d = 0; d < cD; d += 8) {
        short8 f = *(const short8*)(Q + qoff + d);
        #pragma unroll
        for (int j = 0; j < 8; ++j) q[d + j] = b2f((unsigned short)f[j]);
    }

    float sc[cT];
    float mx = -INFINITY;
    #pragma unroll
    for (int s = 0; s < cT; ++s) {
        float acc = 0.f;
        #pragma unroll
        for (int d = 0; d < cD; ++d) acc = fmaf(q[d], Ks[s][hh][d], acc);
        sc[s] = (s <= t) ? acc * cSCALE : -INFINITY;
        mx = fmaxf(mx, sc[s]);
    }
    float l = 0.f;
    #pragma unroll
    for (int s = 0; s < cT; ++s) {
        const float e_ = __expf(sc[s] - mx);
        sc[s] = e_;
        l += e_;
    }
    float o[cD];
    #pragma unroll
    for (int d = 0; d < cD; ++d) o[d] = 0.f;
    #pragma unroll
    for (int s = 0; s < cT; ++s) {
        const float pj = sc[s];
        #pragma unroll
        for (int d = 0; d < cD; ++d) o[d] = fmaf(pj, Vs[s][hh][d], o[d]);
    }
    const float invl = 1.f / l;
    unsigned short* op = O + qoff;
    #pragma unroll
    for (int d = 0; d < cD; d += 8) {
        u16x8 f;
        #pragma unroll
        for (int j = 0; j < 8; ++j) f[j] = f2b(o[d + j] * invl);
        *(u16x8*)(op + d) = f;
    }
}

// ---------------------------------------------------------------------------
extern "C" void kernel_launch(void* const* d_in, const int* in_sizes, int n_in,
                              void* d_out, int out_size, void* d_ws, size_t ws_size,
                              hipStream_t stream)
{
    const float* x    = (const float*)d_in[0];
    const float* sq_w = (const float*)d_in[1];
    const float* sk_w = (const float*)d_in[2];
    const float* sv_w = (const float*)d_in[3];
    const float* so_w = (const float*)d_in[4];
    const float* sq_b = (const float*)d_in[5];
    const float* sk_b = (const float*)d_in[6];
    const float* sv_b = (const float*)d_in[7];
    const float* so_b = (const float*)d_in[8];
    const float* sg   = (const float*)d_in[9];
    const float* sb   = (const float*)d_in[10];
    const float* tq_w = (const float*)d_in[11];
    const float* tk_w = (const float*)d_in[12];
    const float* tv_w = (const float*)d_in[13];
    const float* to_w = (const float*)d_in[14];
    const float* tq_b = (const float*)d_in[15];
    const float* tk_b = (const float*)d_in[16];
    const float* tv_b = (const float*)d_in[17];
    const float* to_b = (const float*)d_in[18];
    const float* tg   = (const float*)d_in[19];
    const float* tb   = (const float*)d_in[20];
    const float* w1   = (const float*)d_in[21];
    const float* b1   = (const float*)d_in[22];
    const float* w2   = (const float*)d_in[23];
    const float* b2   = (const float*)d_in[24];
    const float* g    = (const float*)d_in[25];
    const float* bb   = (const float*)d_in[26];

    const size_t NE = (size_t)NTOK * cE;   // 12.58M elements
    const size_t EE = (size_t)cE * cE;     // 589824

    // workspace layout (~245 MB)
    float* W0 = (float*)d_ws;                    // fp32 residual stream [NE]
    float* Wp = W0 + NE;                         // region reused as bf16 R [NE]
    unsigned short* Rb = (unsigned short*)Wp;    // bf16 projection/FFN output
    unsigned short* Xb = (unsigned short*)(Wp + NE);  // bf16 x_cur [NE]
    unsigned short* Qb = Xb + NE;
    unsigned short* Kbuf = Qb + NE;
    unsigned short* Vb = Kbuf + NE;
    unsigned short* Ob = Vb + NE;
    unsigned short* Hb = Qb;                     // bf16 hidden [NTOK*DFF] overlays Qb..Ob
    unsigned short* WT = Ob + NE;                // bf16 transposed weights
    unsigned short* sqT = WT;                    // [sq;sk;sv] contiguous -> QKV fused B
    unsigned short* skT = sqT + EE;
    unsigned short* svT = skT + EE;
    unsigned short* soT = svT + EE;
    unsigned short* tqT = soT + EE;              // [tq;tk;tv] contiguous
    unsigned short* tkT = tqT + EE;
    unsigned short* tvT = tkT + EE;
    unsigned short* toT = tvT + EE;
    unsigned short* w1T = toT + EE;              // [DFF][E]
    unsigned short* w2T = w1T + (size_t)cDFF * cE;  // [E][DFF]

    const dim3 blk(256);
    const dim3 blk512(512);
    const dim3 gLN(NTOK);
    const dim3 gP(256);                      // persistent gemm256p grid
    const dim3 g128(cE / 128, NTOK / 128);   // (6, 128) = 768 blocks (128x128)

    // ---- prep: cast x, transpose+cast all weights to bf16 [N][K] ----
    cast_bf16_kernel<<<dim3(2048), blk, 0, stream>>>(x, Xb, (int)(NE / 4));
    {
        TP8 p;
        p.src[0] = sq_w; p.dst[0] = sqT;
        p.src[1] = sk_w; p.dst[1] = skT;
        p.src[2] = sv_w; p.dst[2] = svT;
        p.src[3] = so_w; p.dst[3] = soT;
        p.src[4] = tq_w; p.dst[4] = tqT;
        p.src[5] = tk_w; p.dst[5] = tkT;
        p.src[6] = tv_w; p.dst[6] = tvT;
        p.src[7] = to_w; p.dst[7] = toT;
        transpose_cast8_kernel<<<dim3(cE / 32, cE / 32, 8), blk, 0, stream>>>(p);
    }
    transpose_cast_kernel<<<dim3(cDFF / 32, cE / 32), blk, 0, stream>>>(w1, w1T, cE, cDFF);
    transpose_cast_kernel<<<dim3(cE / 32, cDFF / 32), blk, 0, stream>>>(w2, w2T, cDFF, cE);

    // ---- Spatial attention block ----
    gemm256p_kernel<1,0,1><<<gP, blk512, 0, stream>>>(
        Xb, sqT, sq_b, sk_b, sv_b, Qb, Kbuf, Vb, NTOK, 2304, cE, 18, 1152);
    spatial_attn_mfma_kernel<<<dim3(cB * cT * cH), blk, 0, stream>>>(Qb, Kbuf, Vb, Ob);
    gemm128_kernel<1,0><<<g128, blk, 0, stream>>>(Ob, soT, so_b, Rb, NTOK, cE, cE);
    residual_ln_kernel<<<gLN, blk, 0, stream>>>(x, Rb, sg, sb, W0, Xb);

    // ---- Temporal attention block ----
    gemm256p_kernel<1,0,1><<<gP, blk512, 0, stream>>>(
        Xb, tqT, tq_b, tk_b, tv_b, Qb, Kbuf, Vb, NTOK, 2304, cE, 18, 1152);
    temporal_attn_kernel<<<dim3(cB * cP * 2), dim3(128), 0, stream>>>(Qb, Kbuf, Vb, Ob);
    gemm128_kernel<1,0><<<g128, blk, 0, stream>>>(Ob, toT, to_b, Rb, NTOK, cE, cE);
    residual_ln_kernel<<<gLN, blk, 0, stream>>>(W0, Rb, tg, tb, W0, Xb);

    // ---- FFN ----
    gemm256p_kernel<1,1,0><<<gP, blk512, 0, stream>>>(
        Xb, w1T, b1, nullptr, nullptr, Hb, nullptr, nullptr, NTOK, cDFF, cE, 24, 1536);
    gemm128_kernel<1,0><<<g128, blk, 0, stream>>>(Hb, w2T, b2, Rb, NTOK, cE, cDFF);
    residual_ln_kernel<<<gLN, blk, 0, stream>>>(W0, Rb, g, bb, (float*)d_out, nullptr);
}

// Round 14
// 704.064 us; speedup vs baseline: 1.1452x; 1.0021x over previous
//
#include <hip/hip_runtime.h>
#include <math.h>

// Problem constants
constexpr int cB   = 4;
constexpr int cT   = 16;
constexpr int cP   = 256;
constexpr int cE   = 768;
constexpr int cH   = 12;
constexpr int cD   = 64;
constexpr int cDFF = 3072;
constexpr int NTOK = cB * cT * cP;        // 16384
constexpr float cSCALE = 0.125f;          // 64^-0.5
constexpr float cEPS = 1e-5f;

typedef __attribute__((ext_vector_type(8))) short short8;
typedef __attribute__((ext_vector_type(4))) float f32x4;
typedef __attribute__((ext_vector_type(8))) unsigned short u16x8;
typedef __attribute__((ext_vector_type(4))) unsigned short u16x4;

#define AS1 __attribute__((address_space(1)))
#define AS3 __attribute__((address_space(3)))

__device__ inline float b2f(unsigned short u) {
    union { unsigned int i; float f; } c; c.i = ((unsigned int)u) << 16; return c.f;
}
__device__ inline unsigned short f2b(float f) {
    union { float f; unsigned int i; } c; c.f = f;
    unsigned int i = c.i;
    unsigned int r = i + 0x7FFFu + ((i >> 16) & 1u);   // RNE
    return (unsigned short)(r >> 16);
}

__device__ inline void gload16(const unsigned short* g, short* l) {
    __builtin_amdgcn_global_load_lds((AS1 const void*)g, (AS3 void*)l, 16, 0, 0);
}

// ---------------------------------------------------------------------------
// 256x256 MFMA GEMM, per-wave 128x64 (r13 kernel, r14: now isolated):
// 8 waves (2M x 4N), BK=64, 2 LDS buffers (128 KiB). Per wave-K-tile
// 24 ds_read_b128 feed 64 MFMA (0.375 reads/MFMA vs 0.5 before) -> MFMA:LDS
// pipe ratio 0.44 -> 0.89. Schedule: stage t+1 FIRST, kk-split
// lgkm(12)/lgkm(0)+sched_barrier, T5 setprio, T2 both-sides swizzle,
// T1 XCD swizzle bm-major, vmcnt(0)+barrier per K-tile.
// SPLIT3: N=2304 QKV fusion. OUTB: bf16/fp32 out. ACT: exact GELU.
// ---------------------------------------------------------------------------
template<int OUTB, int ACT, int SPLIT3>
__global__ __launch_bounds__(512, 1) void gemm256w_kernel(
    const unsigned short* __restrict__ A,   // [M][K] bf16
    const unsigned short* __restrict__ BT,  // [N][K] bf16
    const float* __restrict__ bias0, const float* __restrict__ bias1,
    const float* __restrict__ bias2,
    void* __restrict__ C0, void* __restrict__ C1, void* __restrict__ C2,
    int M, int N, int K, int nbn)
{
    __shared__ short LDS[2 * 32768];   // 128 KiB: 2 x (A[256][64] + B[256][64])

    const int tid = threadIdx.x;
    const int w = tid >> 6, l = tid & 63;
    const int l15 = l & 15, l16 = l >> 4;
    const int wm = w >> 2, wn = w & 3;      // 2 M-waves x 4 N-waves
    const int strow = tid >> 3;             // staging row-in-group 0..63
    const int stslot = tid & 7;             // staging 16B slot 0..7

    // bijective XCD swizzle (nwg % 8 == 0), bm-major
    const int nwg = gridDim.x;
    const int wg = (blockIdx.x & 7) * (nwg >> 3) + (blockIdx.x >> 3);
    const int bm = wg / nbn, bn = wg % nbn;
    const int m0 = bm * 256, n0 = bn * 256;

    const unsigned short* pA = A + (size_t)m0 * K;
    const unsigned short* pB = BT + (size_t)n0 * K;

    f32x4 acc[8][4];
    #pragma unroll
    for (int i = 0; i < 8; ++i)
        #pragma unroll
        for (int j = 0; j < 4; ++j)
            #pragma unroll
            for (int r = 0; r < 4; ++r) acc[i][j][r] = 0.f;

    const int nt = K >> 6;

    // staging: load j covers rows j*64..j*64+63; 16B/lane; linear LDS dest,
    // inverse-swizzled global source column (both-sides rule)
    size_t laneS[4]; int dS[4];
    #pragma unroll
    for (int j = 0; j < 4; ++j) {
        const int row = j * 64 + strow;
        laneS[j] = (size_t)row * K + ((stslot ^ (row & 7)) << 3);
        dS[j] = row * 64 + (stslot << 3);
    }

    #define STAGE(buf_, kt_)                                                  \
        {                                                                     \
            const unsigned short* a_ = pA + (kt_) * 64;                       \
            const unsigned short* b_ = pB + (kt_) * 64;                       \
            short* d_ = LDS + (buf_) * 32768;                                 \
            _Pragma("unroll")                                                 \
            for (int j_ = 0; j_ < 4; ++j_) {                                  \
                gload16(a_ + laneS[j_], d_ + dS[j_]);                         \
                gload16(b_ + laneS[j_], d_ + 16384 + dS[j_]);                 \
            }                                                                 \
        }

    // hoisted ds_read byte offsets (relative to buffer base)
    int offA[8][2], offB[4][2];
    #pragma unroll
    for (int mm = 0; mm < 8; ++mm) {
        const int ra = wm * 128 + mm * 16 + l15;
        const int sw = (ra & 7) << 4;
        offA[mm][0] = ra * 128 + ((l16 * 16) ^ sw);
        offA[mm][1] = ra * 128 + ((64 + l16 * 16) ^ sw);
    }
    #pragma unroll
    for (int nf = 0; nf < 4; ++nf) {
        const int rb = wn * 64 + nf * 16 + l15;
        const int sw = (rb & 7) << 4;
        offB[nf][0] = 32768 + rb * 128 + ((l16 * 16) ^ sw);
        offB[nf][1] = 32768 + rb * 128 + ((64 + l16 * 16) ^ sw);
    }

    // prologue: stage tile 0 into buffer 0
    STAGE(0, 0);
    asm volatile("s_waitcnt vmcnt(0)" ::: "memory");
    __builtin_amdgcn_s_barrier();

    int buf = 0;
    for (int t = 0; t < nt; ++t) {
        // issue next-tile staging FIRST (latency covered by this tile's MFMA)
        if (t + 1 < nt) STAGE(buf ^ 1, t + 1);

        const char* Lb = (const char*)LDS + buf * 65536;
        short8 aF[8][2], bF[4][2];
        // kk0 group: 12 ds_read_b128
        #pragma unroll
        for (int mm = 0; mm < 8; ++mm)
            aF[mm][0] = *(const short8*)(Lb + offA[mm][0]);
        #pragma unroll
        for (int nf = 0; nf < 4; ++nf)
            bF[nf][0] = *(const short8*)(Lb + offB[nf][0]);
        __builtin_amdgcn_sched_barrier(0);   // pin kk0-group issue order
        // kk1 group: 12 ds_read_b128
        #pragma unroll
        for (int mm = 0; mm < 8; ++mm)
            aF[mm][1] = *(const short8*)(Lb + offA[mm][1]);
        #pragma unroll
        for (int nf = 0; nf < 4; ++nf)
            bF[nf][1] = *(const short8*)(Lb + offB[nf][1]);

        asm volatile("s_waitcnt lgkmcnt(12)" ::: "memory");   // kk0 ready
        __builtin_amdgcn_sched_barrier(0);
        __builtin_amdgcn_s_setprio(1);
        #pragma unroll
        for (int nf = 0; nf < 4; ++nf)
            #pragma unroll
            for (int mm = 0; mm < 8; ++mm)
                acc[mm][nf] = __builtin_amdgcn_mfma_f32_16x16x32_bf16(
                    aF[mm][0], bF[nf][0], acc[mm][nf], 0, 0, 0);
        __builtin_amdgcn_s_setprio(0);
        asm volatile("s_waitcnt lgkmcnt(0)" ::: "memory");    // kk1 ready
        __builtin_amdgcn_sched_barrier(0);
        __builtin_amdgcn_s_setprio(1);
        #pragma unroll
        for (int nf = 0; nf < 4; ++nf)
            #pragma unroll
            for (int mm = 0; mm < 8; ++mm)
                acc[mm][nf] = __builtin_amdgcn_mfma_f32_16x16x32_bf16(
                    aF[mm][1], bF[nf][1], acc[mm][nf], 0, 0, 0);
        __builtin_amdgcn_s_setprio(0);

        if (t + 1 < nt) {
            asm volatile("s_waitcnt vmcnt(0)" ::: "memory");  // t+1 landed
            __builtin_amdgcn_s_barrier();
        }
        buf ^= 1;
    }
    #undef STAGE

    // ---- epilogue: C/D layout col = lane&15, row = (lane>>4)*4 + reg ----
    #pragma unroll
    for (int mf = 0; mf < 8; ++mf) {
        #pragma unroll
        for (int nf = 0; nf < 4; ++nf) {
            const int ng = n0 + wn * 64 + nf * 16 + l15;
            int nl = ng;
            const float* bp = bias0;
            void* Cp = C0;
            int Nout = N;
            if (SPLIT3) {
                const int which = ng / 768;
                nl = ng - which * 768;
                bp = (which == 0) ? bias0 : (which == 1) ? bias1 : bias2;
                Cp = (which == 0) ? C0 : (which == 1) ? C1 : C2;
                Nout = 768;
            }
            const float bs = bp[nl];
            #pragma unroll
            for (int r = 0; r < 4; ++r) {
                const int row = m0 + wm * 128 + mf * 16 + l16 * 4 + r;
                float v = acc[mf][nf][r] + bs;
                if (ACT) v = 0.5f * v * (1.f + erff(v * 0.70710678118654752f));
                if (OUTB) ((unsigned short*)Cp)[(size_t)row * Nout + nl] = f2b(v);
                else      ((float*)Cp)[(size_t)row * Nout + nl] = v;
            }
        }
    }
}

// ---------------------------------------------------------------------------
// 128x128 MFMA GEMM (r5 structure, proven): used for OUT-proj x2 and FFN2.
// ---------------------------------------------------------------------------
template<int OUTB, int ACT>
__global__ __launch_bounds__(256) void gemm128_kernel(
    const unsigned short* __restrict__ A,   // [M][K] bf16
    const unsigned short* __restrict__ BT,  // [N][K] bf16
    const float* __restrict__ bias,         // [N]
    void* __restrict__ Cout,
    int M, int N, int K)
{
    __shared__ short As[8192];   // 2 x [128][32] bf16
    __shared__ short Bs[8192];

    const int tid = threadIdx.x;
    const int m0 = blockIdx.y * 128;
    const int n0 = blockIdx.x * 128;
    const int w  = tid >> 6;
    const int l  = tid & 63;
    const int wr = w >> 1, wc = w & 1;
    const int l15 = l & 15, l16 = l >> 4;

    f32x4 acc[4][4];
    #pragma unroll
    for (int i = 0; i < 4; ++i)
        #pragma unroll
        for (int j = 0; j < 4; ++j)
            #pragma unroll
            for (int r = 0; r < 4; ++r) acc[i][j][r] = 0.f;

    const int sr = tid >> 2;
    const int sc = (tid & 3) << 3;
    const unsigned short* ga0 = A  + (size_t)(m0 + sr) * K + sc;
    const unsigned short* ga1 = A  + (size_t)(m0 + 64 + sr) * K + sc;
    const unsigned short* gb0 = BT + (size_t)(n0 + sr) * K + sc;
    const unsigned short* gb1 = BT + (size_t)(n0 + 64 + sr) * K + sc;
    short* lA = As + tid * 8;
    short* lB = Bs + tid * 8;

    const int aoff = (wr * 64 + l15) * 32 + l16 * 8;
    const int boff = (wc * 64 + l15) * 32 + l16 * 8;

    gload16(ga0, lA);
    gload16(ga1, lA + 2048);
    gload16(gb0, lB);
    gload16(gb1, lB + 2048);
    __syncthreads();

    int cur = 0;
    for (int k0 = 0; k0 < K; k0 += 32) {
        if (k0 + 32 < K) {
            const int nb = (cur ^ 1) << 12;
            gload16(ga0 + k0 + 32, lA + nb);
            gload16(ga1 + k0 + 32, lA + nb + 2048);
            gload16(gb0 + k0 + 32, lB + nb);
            gload16(gb1 + k0 + 32, lB + nb + 2048);
        }
        const int cb = cur << 12;
        short8 aF[4], bF[4];
        #pragma unroll
        for (int mf = 0; mf < 4; ++mf)
            aF[mf] = *(const short8*)(As + cb + aoff + mf * 512);
        #pragma unroll
        for (int nf = 0; nf < 4; ++nf)
            bF[nf] = *(const short8*)(Bs + cb + boff + nf * 512);
        #pragma unroll
        for (int mf = 0; mf < 4; ++mf)
            #pragma unroll
            for (int nf = 0; nf < 4; ++nf)
                acc[mf][nf] = __builtin_amdgcn_mfma_f32_16x16x32_bf16(
                    aF[mf], bF[nf], acc[mf][nf], 0, 0, 0);
        __syncthreads();
        cur ^= 1;
    }

    #pragma unroll
    for (int mf = 0; mf < 4; ++mf) {
        #pragma unroll
        for (int nf = 0; nf < 4; ++nf) {
            const int col = n0 + wc * 64 + nf * 16 + l15;
            const float bs = bias[col];
            #pragma unroll
            for (int r = 0; r < 4; ++r) {
                const int row = m0 + wr * 64 + mf * 16 + l16 * 4 + r;
                float v = acc[mf][nf][r] + bs;
                if (ACT) v = 0.5f * v * (1.f + erff(v * 0.70710678118654752f));
                if (OUTB) ((unsigned short*)Cout)[(size_t)row * N + col] = f2b(v);
                else      ((float*)Cout)[(size_t)row * N + col] = v;
            }
        }
    }
}

// ---------------------------------------------------------------------------
// weight prep: W[K][N] fp32 -> WT[N][K] bf16  (32x32 LDS tile transpose)
// ---------------------------------------------------------------------------
__global__ __launch_bounds__(256) void transpose_cast_kernel(
    const float* __restrict__ W, unsigned short* __restrict__ WT,
    int K, int N)
{
    __shared__ float t[32][33];
    const int k0 = blockIdx.y * 32;
    const int n0 = blockIdx.x * 32;
    const int tx = threadIdx.x & 31;
    const int ty4 = (threadIdx.x >> 5) << 2;
    #pragma unroll
    for (int i = 0; i < 4; ++i)
        t[ty4 + i][tx] = W[(size_t)(k0 + ty4 + i) * N + n0 + tx];
    __syncthreads();
    #pragma unroll
    for (int i = 0; i < 4; ++i)
        WT[(size_t)(n0 + ty4 + i) * K + k0 + tx] = f2b(t[tx][ty4 + i]);
}

// fused prep for the 8 E x E attention weights (grid.z selects weight)
struct TP8 { const float* src[8]; unsigned short* dst[8]; };
__global__ __launch_bounds__(256) void transpose_cast8_kernel(TP8 p)
{
    __shared__ float t[32][33];
    const int z = blockIdx.z;
    const float* W = p.src[z];
    unsigned short* WT = p.dst[z];
    const int k0 = blockIdx.y * 32;
    const int n0 = blockIdx.x * 32;
    const int tx = threadIdx.x & 31;
    const int ty4 = (threadIdx.x >> 5) << 2;
    #pragma unroll
    for (int i = 0; i < 4; ++i)
        t[ty4 + i][tx] = W[(size_t)(k0 + ty4 + i) * cE + n0 + tx];
    __syncthreads();
    #pragma unroll
    for (int i = 0; i < 4; ++i)
        WT[(size_t)(n0 + ty4 + i) * cE + k0 + tx] = f2b(t[tx][ty4 + i]);
}

// fp32 -> bf16 elementwise (n multiple of 4)
__global__ __launch_bounds__(256) void cast_bf16_kernel(
    const float* __restrict__ in, unsigned short* __restrict__ out, int n4)
{
    for (int i = blockIdx.x * blockDim.x + threadIdx.x; i < n4;
         i += gridDim.x * blockDim.x) {
        float4 v = ((const float4*)in)[i];
        u16x4 o;
        o[0] = f2b(v.x); o[1] = f2b(v.y); o[2] = f2b(v.z); o[3] = f2b(v.w);
        *(u16x4*)(out + (size_t)i * 4) = o;
    }
}

// ---------------------------------------------------------------------------
// residual + layernorm (r10 proven): out = LN(X + R) * gamma + beta;
// X fp32, R bf16. Writes fp32 residual/out + optional bf16 copy.
// ---------------------------------------------------------------------------
__global__ __launch_bounds__(256) void residual_ln_kernel(
    const float* __restrict__ X, const unsigned short* __restrict__ R,
    const float* __restrict__ gamma, const float* __restrict__ beta,
    float* __restrict__ out, unsigned short* __restrict__ outb)
{
    const int row = blockIdx.x;
    const size_t off = (size_t)row * cE;
    const int tid = threadIdx.x;

    float v[3];
    float s = 0.f, ss = 0.f;
    #pragma unroll
    for (int i = 0; i < 3; ++i) {
        const int e = tid + i * 256;
        const float t = X[off + e] + b2f(R[off + e]);
        v[i] = t; s += t; ss += t * t;
    }
    #pragma unroll
    for (int o = 32; o > 0; o >>= 1) {
        s  += __shfl_down(s, o);
        ss += __shfl_down(ss, o);
    }
    __shared__ float rs[4], rss[4];
    const int wid = tid >> 6;
    if ((tid & 63) == 0) { rs[wid] = s; rss[wid] = ss; }
    __syncthreads();
    s  = rs[0] + rs[1] + rs[2] + rs[3];
    ss = rss[0] + rss[1] + rss[2] + rss[3];

    const float mean = s * (1.f / cE);
    const float var  = ss * (1.f / cE) - mean * mean;
    const float inv  = rsqrtf(var + cEPS);
    #pragma unroll
    for (int i = 0; i < 3; ++i) {
        const int e = tid + i * 256;
        const float r = (v[i] - mean) * inv * gamma[e] + beta[e];
        out[off + e] = r;
        if (outb) outb[off + e] = f2b(r);
    }
}

// NOTE: the residual stream must stay fp32 (r13 lesson: bf16 residual
// compounds rounding across 3 LN stages -> absmax 0.165 > 0.104 threshold).

// ---------------------------------------------------------------------------
// Spatial attention, MFMA flash version (verified round 4).
// ---------------------------------------------------------------------------
__global__ __launch_bounds__(256) void spatial_attn_mfma_kernel(
    const unsigned short* __restrict__ Q, const unsigned short* __restrict__ K,
    const unsigned short* __restrict__ V, unsigned short* __restrict__ O)
{
    __shared__ short Ks[64 * 64];      // [j][d] swizzled, row 128B
    __shared__ short Vt[64 * 64];      // [d][j] swizzled
    __shared__ short Ps[4][64 * 64];   // per-wave [q][j] swizzled

    const int bid = blockIdx.x;        // b*T*H + t*H + h
    const int h  = bid % cH;
    const int bt = bid / cH;
    const size_t base = (size_t)bt * cP * cE + h * cD;

    const int tid = threadIdx.x;
    const int w = tid >> 6, l = tid & 63;
    const int l15 = l & 15, l16 = l >> 4;

    short8 qf[4][2];
    #pragma unroll
    for (int mf = 0; mf < 4; ++mf)
        #pragma unroll
        for (int kf = 0; kf < 2; ++kf)
            qf[mf][kf] = *(const short8*)(
                Q + base + (size_t)(w * 64 + mf * 16 + l15) * cE + kf * 32 + l16 * 8);

    f32x4 o[4][4];
    float mrun[4][4], lrun[4][4];
    #pragma unroll
    for (int mf = 0; mf < 4; ++mf)
        #pragma unroll
        for (int j = 0; j < 4; ++j) {
            #pragma unroll
            for (int r = 0; r < 4; ++r) o[mf][j][r] = 0.f;
            mrun[mf][j] = -INFINITY; lrun[mf][j] = 0.f;
        }

    const int krow = w * 8 + (l >> 3);
    const int kc16 = l & 7;
    const int vj  = tid & 31;
    const int vd0 = (tid >> 5) * 8;

    for (int c0 = 0; c0 < cP; c0 += 64) {
        __syncthreads();
        #pragma unroll
        for (int p = 0; p < 2; ++p) {
            const int row = p * 32 + krow;
            gload16(K + base + (size_t)(c0 + row) * cE + ((kc16 ^ (row & 7)) << 3),
                    Ks + row * 64 + kc16 * 8);
        }
        #pragma unroll
        for (int p = 0; p < 2; ++p) {
            const int j = p * 32 + vj;
            short8 vv = *(const short8*)(V + base + (size_t)(c0 + j) * cE + vd0);
            char* vb = (char*)Vt;
            #pragma unroll
            for (int e = 0; e < 8; ++e) {
                const int row = vd0 + e;
                *(short*)(vb + row * 128 + ((2 * j) ^ ((row & 7) << 4))) = vv[e];
            }
        }
        __syncthreads();

        f32x4 s[4][4];
        #pragma unroll
        for (int mf = 0; mf < 4; ++mf)
            #pragma unroll
            for (int nf = 0; nf < 4; ++nf)
                #pragma unroll
                for (int r = 0; r < 4; ++r) s[mf][nf][r] = 0.f;

        #pragma unroll
        for (int nf = 0; nf < 4; ++nf) {
            const int row = nf * 16 + l15;
            const char* kb = (const char*)Ks + row * 128;
            const int sw = (row & 7) << 4;
            short8 k0 = *(const short8*)(kb + ((l16 * 16) ^ sw));
            short8 k1 = *(const short8*)(kb + ((64 + l16 * 16) ^ sw));
            #pragma unroll
            for (int mf = 0; mf < 4; ++mf) {
                s[mf][nf] = __builtin_amdgcn_mfma_f32_16x16x32_bf16(qf[mf][0], k0, s[mf][nf], 0, 0, 0);
                s[mf][nf] = __builtin_amdgcn_mfma_f32_16x16x32_bf16(qf[mf][1], k1, s[mf][nf], 0, 0, 0);
            }
        }

        #pragma unroll
        for (int mf = 0; mf < 4; ++mf)
            #pragma unroll
            for (int nf = 0; nf < 4; ++nf)
                #pragma unroll
                for (int r = 0; r < 4; ++r) s[mf][nf][r] *= cSCALE;

        #pragma unroll
        for (int mf = 0; mf < 4; ++mf) {
            #pragma unroll
            for (int r = 0; r < 4; ++r) {
                float rv = fmaxf(fmaxf(s[mf][0][r], s[mf][1][r]),
                                 fmaxf(s[mf][2][r], s[mf][3][r]));
                rv = fmaxf(rv, __shfl_xor(rv, 1));
                rv = fmaxf(rv, __shfl_xor(rv, 2));
                rv = fmaxf(rv, __shfl_xor(rv, 4));
                rv = fmaxf(rv, __shfl_xor(rv, 8));
                const float mn = fmaxf(mrun[mf][r], rv);
                const float al = __expf(mrun[mf][r] - mn);
                mrun[mf][r] = mn;
                float ps = 0.f;
                #pragma unroll
                for (int nf = 0; nf < 4; ++nf) {
                    const float pe = __expf(s[mf][nf][r] - mn);
                    s[mf][nf][r] = pe;
                    ps += pe;
                }
                ps += __shfl_xor(ps, 1);
                ps += __shfl_xor(ps, 2);
                ps += __shfl_xor(ps, 4);
                ps += __shfl_xor(ps, 8);
                lrun[mf][r] = lrun[mf][r] * al + ps;
                #pragma unroll
                for (int df = 0; df < 4; ++df) o[mf][df][r] *= al;
            }
        }

        char* pw = (char*)&Ps[w][0];
        #pragma unroll
        for (int mf = 0; mf < 4; ++mf)
            #pragma unroll
            for (int nf = 0; nf < 4; ++nf)
                #pragma unroll
                for (int r = 0; r < 4; ++r) {
                    const int row = mf * 16 + l16 * 4 + r;
                    *(short*)(pw + row * 128 + (((nf * 16 + l15) * 2) ^ ((row & 7) << 4))) =
                        (short)f2b(s[mf][nf][r]);
                }

        short8 pa[4][2];
        #pragma unroll
        for (int mf = 0; mf < 4; ++mf) {
            const int prow = mf * 16 + l15;
            const char* pb = (const char*)&Ps[w][0] + prow * 128;
            const int sw = (prow & 7) << 4;
            pa[mf][0] = *(const short8*)(pb + ((l16 * 16) ^ sw));
            pa[mf][1] = *(const short8*)(pb + ((64 + l16 * 16) ^ sw));
        }
        #pragma unroll
        for (int df = 0; df < 4; ++df) {
            const int vrow = df * 16 + l15;
            const char* vbb = (const char*)Vt + vrow * 128;
            const int sw = (vrow & 7) << 4;
            short8 v0 = *(const short8*)(vbb + ((l16 * 16) ^ sw));
            short8 v1 = *(const short8*)(vbb + ((64 + l16 * 16) ^ sw));
            #pragma unroll
            for (int mf = 0; mf < 4; ++mf) {
                o[mf][df] = __builtin_amdgcn_mfma_f32_16x16x32_bf16(pa[mf][0], v0, o[mf][df], 0, 0, 0);
                o[mf][df] = __builtin_amdgcn_mfma_f32_16x16x32_bf16(pa[mf][1], v1, o[mf][df], 0, 0, 0);
            }
        }
    }

    #pragma unroll
    for (int mf = 0; mf < 4; ++mf)
        #pragma unroll
        for (int r = 0; r < 4; ++r) {
            const float inv = 1.f / lrun[mf][r];
            const size_t rowoff = base + (size_t)(w * 64 + mf * 16 + l16 * 4 + r) * cE;
            #pragma unroll
            for (int df = 0; df < 4; ++df)
                O[rowoff + df * 16 + l15] = f2b(o[mf][df][r] * inv);
        }
}

// ---------------------------------------------------------------------------
// Temporal causal attention (bf16 I/O): per (b,p,head-group of 6). T=16.
// ---------------------------------------------------------------------------
__global__ __launch_bounds__(128) void temporal_attn_kernel(
    const unsigned short* __restrict__ Q, const unsigned short* __restrict__ Kb,
    const unsigned short* __restrict__ V, unsigned short* __restrict__ O)
{
    const int bid = blockIdx.x;          // (b*P + p)*2 + hg
    const int hg  = bid & 1;
    const int bp  = bid >> 1;
    const int p   = bp % cP;
    const int b   = bp / cP;

    __shared__ float Ks[cT][6][cD + 1];
    __shared__ float Vs[cT][6][cD + 1];

    const size_t framestride = (size_t)cP * cE;
    const size_t base0 = ((size_t)(b * cT) * cP + p) * cE + hg * 384;

    for (int li = threadIdx.x; li < cT * 384; li += 128) {
        const int s = li / 384;
        const int r = li % 384;
        const size_t src = base0 + (size_t)s * framestride + r;
        Ks[s][r / 64][r & 63] = b2f(Kb[src]);
        Vs[s][r / 64][r & 63] = b2f(V[src]);
    }
    __syncthreads();
    if (threadIdx.x >= 96) return;

    const int hh = threadIdx.x >> 4;
    const int t  = threadIdx.x & 15;
    const size_t qoff = ((size_t)(b * cT + t) * cP + p) * cE + hg * 384 + hh * cD;

    float q[cD];
    #pragma unroll
    for (int d = 0; d < cD; d += 8) {
        short8 f = *(const short8*)(Q + qoff + d);
        #pragma unroll
        for (int j = 0; j < 8; ++j) q[d + j] = b2f((unsigned short)f[j]);
    }

    float sc[cT];
    float mx = -INFINITY;
    #pragma unroll
    for (int s = 0; s < cT; ++s) {
        float acc = 0.f;
        #pragma unroll
        for (int d = 0; d < cD; ++d) acc = fmaf(q[d], Ks[s][hh][d], acc);
        sc[s] = (s <= t) ? acc * cSCALE : -INFINITY;
        mx = fmaxf(mx, sc[s]);
    }
    float l = 0.f;
    #pragma unroll
    for (int s = 0; s < cT; ++s) {
        const float e_ = __expf(sc[s] - mx);
        sc[s] = e_;
        l += e_;
    }
    float o[cD];
    #pragma unroll
    for (int d = 0; d < cD; ++d) o[d] = 0.f;
    #pragma unroll
    for (int s = 0; s < cT; ++s) {
        const float pj = sc[s];
        #pragma unroll
        for (int d = 0; d < cD; ++d) o[d] = fmaf(pj, Vs[s][hh][d], o[d]);
    }
    const float invl = 1.f / l;
    unsigned short* op = O + qoff;
    #pragma unroll
    for (int d = 0; d < cD; d += 8) {
        u16x8 f;
        #pragma unroll
        for (int j = 0; j < 8; ++j) f[j] = f2b(o[d + j] * invl);
        *(u16x8*)(op + d) = f;
    }
}

// ---------------------------------------------------------------------------
extern "C" void kernel_launch(void* const* d_in, const int* in_sizes, int n_in,
                              void* d_out, int out_size, void* d_ws, size_t ws_size,
                              hipStream_t stream)
{
    const float* x    = (const float*)d_in[0];
    const float* sq_w = (const float*)d_in[1];
    const float* sk_w = (const float*)d_in[2];
    const float* sv_w = (const float*)d_in[3];
    const float* so_w = (const float*)d_in[4];
    const float* sq_b = (const float*)d_in[5];
    const float* sk_b = (const float*)d_in[6];
    const float* sv_b = (const float*)d_in[7];
    const float* so_b = (const float*)d_in[8];
    const float* sg   = (const float*)d_in[9];
    const float* sb   = (const float*)d_in[10];
    const float* tq_w = (const float*)d_in[11];
    const float* tk_w = (const float*)d_in[12];
    const float* tv_w = (const float*)d_in[13];
    const float* to_w = (const float*)d_in[14];
    const float* tq_b = (const float*)d_in[15];
    const float* tk_b = (const float*)d_in[16];
    const float* tv_b = (const float*)d_in[17];
    const float* to_b = (const float*)d_in[18];
    const float* tg   = (const float*)d_in[19];
    const float* tb   = (const float*)d_in[20];
    const float* w1   = (const float*)d_in[21];
    const float* b1   = (const float*)d_in[22];
    const float* w2   = (const float*)d_in[23];
    const float* b2   = (const float*)d_in[24];
    const float* g    = (const float*)d_in[25];
    const float* bb   = (const float*)d_in[26];

    const size_t NE = (size_t)NTOK * cE;   // 12.58M elements
    const size_t EE = (size_t)cE * cE;     // 589824

    // workspace layout (~245 MB)
    float* W0 = (float*)d_ws;                    // fp32 residual stream [NE]
    float* Wp = W0 + NE;                         // region reused as bf16 R [NE]
    unsigned short* Rb = (unsigned short*)Wp;    // bf16 projection/FFN output
    unsigned short* Xb = (unsigned short*)(Wp + NE);  // bf16 x_cur [NE]
    unsigned short* Qb = Xb + NE;
    unsigned short* Kbuf = Qb + NE;
    unsigned short* Vb = Kbuf + NE;
    unsigned short* Ob = Vb + NE;
    unsigned short* Hb = Qb;                     // bf16 hidden overlays Qb..Ob
    unsigned short* WT = Ob + NE;                // bf16 transposed weights
    unsigned short* sqT = WT;                    // [sq;sk;sv] contiguous
    unsigned short* skT = sqT + EE;
    unsigned short* svT = skT + EE;
    unsigned short* soT = svT + EE;
    unsigned short* tqT = soT + EE;
    unsigned short* tkT = tqT + EE;
    unsigned short* tvT = tkT + EE;
    unsigned short* toT = tvT + EE;
    unsigned short* w1T = toT + EE;              // [DFF][E]
    unsigned short* w2T = w1T + (size_t)cDFF * cE;  // [E][DFF]

    const dim3 blk(256);
    const dim3 blk512(512);
    const dim3 gLN(NTOK);
    const dim3 gQKV(576);                    // 64 M-blocks * 9 N-blocks (256x256)
    const dim3 gFF1(768);                    // 64 * 12 (256x256)
    const dim3 g128(cE / 128, NTOK / 128);   // (6, 128) = 768 blocks (128x128)

    // ---- prep: cast x, transpose+cast all weights to bf16 [N][K] ----
    cast_bf16_kernel<<<dim3(2048), blk, 0, stream>>>(x, Xb, (int)(NE / 4));
    {
        TP8 p;
        p.src[0] = sq_w; p.dst[0] = sqT;
        p.src[1] = sk_w; p.dst[1] = skT;
        p.src[2] = sv_w; p.dst[2] = svT;
        p.src[3] = so_w; p.dst[3] = soT;
        p.src[4] = tq_w; p.dst[4] = tqT;
        p.src[5] = tk_w; p.dst[5] = tkT;
        p.src[6] = tv_w; p.dst[6] = tvT;
        p.src[7] = to_w; p.dst[7] = toT;
        transpose_cast8_kernel<<<dim3(cE / 32, cE / 32, 8), blk, 0, stream>>>(p);
    }
    transpose_cast_kernel<<<dim3(cDFF / 32, cE / 32), blk, 0, stream>>>(w1, w1T, cE, cDFF);
    transpose_cast_kernel<<<dim3(cE / 32, cDFF / 32), blk, 0, stream>>>(w2, w2T, cDFF, cE);

    // ---- Spatial attention block ----
    gemm256w_kernel<1,0,1><<<gQKV, blk512, 0, stream>>>(
        Xb, sqT, sq_b, sk_b, sv_b, Qb, Kbuf, Vb, NTOK, 2304, cE, 9);
    spatial_attn_mfma_kernel<<<dim3(cB * cT * cH), blk, 0, stream>>>(Qb, Kbuf, Vb, Ob);
    gemm128_kernel<1,0><<<g128, blk, 0, stream>>>(Ob, soT, so_b, Rb, NTOK, cE, cE);
    residual_ln_kernel<<<gLN, blk, 0, stream>>>(x, Rb, sg, sb, W0, Xb);

    // ---- Temporal attention block ----
    gemm256w_kernel<1,0,1><<<gQKV, blk512, 0, stream>>>(
        Xb, tqT, tq_b, tk_b, tv_b, Qb, Kbuf, Vb, NTOK, 2304, cE, 9);
    temporal_attn_kernel<<<dim3(cB * cP * 2), dim3(128), 0, stream>>>(Qb, Kbuf, Vb, Ob);
    gemm128_kernel<1,0><<<g128, blk, 0, stream>>>(Ob, toT, to_b, Rb, NTOK, cE, cE);
    residual_ln_kernel<<<gLN, blk, 0, stream>>>(W0, Rb, tg, tb, W0, Xb);

    // ---- FFN ----
    gemm256w_kernel<1,1,0><<<gFF1, blk512, 0, stream>>>(
        Xb, w1T, b1, nullptr, nullptr, Hb, nullptr, nullptr, NTOK, cDFF, cE, 12);
    gemm128_kernel<1,0><<<g128, blk, 0, stream>>>(Hb, w2T, b2, Rb, NTOK, cE, cDFF);
    residual_ln_kernel<<<gLN, blk, 0, stream>>>(W0, Rb, g, bb, (float*)d_out, nullptr);
}

// Round 15
// 694.611 us; speedup vs baseline: 1.1608x; 1.0136x over previous
//
#include <hip/hip_runtime.h>
#include <math.h>

// Problem constants
constexpr int cB   = 4;
constexpr int cT   = 16;
constexpr int cP   = 256;
constexpr int cE   = 768;
constexpr int cH   = 12;
constexpr int cD   = 64;
constexpr int cDFF = 3072;
constexpr int NTOK = cB * cT * cP;        // 16384
constexpr float cSCALE = 0.125f;          // 64^-0.5
constexpr float cEPS = 1e-5f;

typedef __attribute__((ext_vector_type(8))) short short8;
typedef __attribute__((ext_vector_type(4))) float f32x4;
typedef __attribute__((ext_vector_type(8))) unsigned short u16x8;
typedef __attribute__((ext_vector_type(4))) unsigned short u16x4;

#define AS1 __attribute__((address_space(1)))
#define AS3 __attribute__((address_space(3)))

__device__ inline float b2f(unsigned short u) {
    union { unsigned int i; float f; } c; c.i = ((unsigned int)u) << 16; return c.f;
}
__device__ inline unsigned short f2b(float f) {
    union { float f; unsigned int i; } c; c.f = f;
    unsigned int i = c.i;
    unsigned int r = i + 0x7FFFu + ((i >> 16) & 1u);   // RNE
    return (unsigned short)(r >> 16);
}

__device__ inline void gload16(const unsigned short* g, short* l) {
    __builtin_amdgcn_global_load_lds((AS1 const void*)g, (AS3 void*)l, 16, 0, 0);
}

// ---------------------------------------------------------------------------
// 256x256 MFMA GEMM, per-wave 128x64 (r15: PURE COMPILER SCHEDULING):
// 8 waves (2M x 4N), BK=64, 2 LDS buffers (128 KiB), STAGE(t+1) issued at
// loop top, plain __syncthreads per K-tile. No inline-asm waits, no
// sched_barrier, no setprio — m141 showed order-pinning can cost 40%, and
// m97 asm analysis shows the compiler interleaves ds_read->MFMA with
// fine-grained lgkmcnt(4/3/1/0) when left alone. T2 both-sides swizzle,
// T1 XCD swizzle bm-major unchanged (r14-verified fragment math).
// SPLIT3: N=2304 QKV fusion. OUTB: bf16/fp32 out. ACT: exact GELU.
// ---------------------------------------------------------------------------
template<int OUTB, int ACT, int SPLIT3>
__global__ __launch_bounds__(512, 1) void gemm256w_kernel(
    const unsigned short* __restrict__ A,   // [M][K] bf16
    const unsigned short* __restrict__ BT,  // [N][K] bf16
    const float* __restrict__ bias0, const float* __restrict__ bias1,
    const float* __restrict__ bias2,
    void* __restrict__ C0, void* __restrict__ C1, void* __restrict__ C2,
    int M, int N, int K, int nbn)
{
    __shared__ short LDS[2 * 32768];   // 128 KiB: 2 x (A[256][64] + B[256][64])

    const int tid = threadIdx.x;
    const int w = tid >> 6, l = tid & 63;
    const int l15 = l & 15, l16 = l >> 4;
    const int wm = w >> 2, wn = w & 3;      // 2 M-waves x 4 N-waves
    const int strow = tid >> 3;             // staging row-in-group 0..63
    const int stslot = tid & 7;             // staging 16B slot 0..7

    // bijective XCD swizzle (nwg % 8 == 0), bm-major
    const int nwg = gridDim.x;
    const int wg = (blockIdx.x & 7) * (nwg >> 3) + (blockIdx.x >> 3);
    const int bm = wg / nbn, bn = wg % nbn;
    const int m0 = bm * 256, n0 = bn * 256;

    const unsigned short* pA = A + (size_t)m0 * K;
    const unsigned short* pB = BT + (size_t)n0 * K;

    f32x4 acc[8][4];
    #pragma unroll
    for (int i = 0; i < 8; ++i)
        #pragma unroll
        for (int j = 0; j < 4; ++j)
            #pragma unroll
            for (int r = 0; r < 4; ++r) acc[i][j][r] = 0.f;

    const int nt = K >> 6;

    // staging: load j covers rows j*64..j*64+63; 16B/lane; linear LDS dest,
    // inverse-swizzled global source column (both-sides rule)
    size_t laneS[4]; int dS[4];
    #pragma unroll
    for (int j = 0; j < 4; ++j) {
        const int row = j * 64 + strow;
        laneS[j] = (size_t)row * K + ((stslot ^ (row & 7)) << 3);
        dS[j] = row * 64 + (stslot << 3);
    }

    #define STAGE(buf_, kt_)                                                  \
        {                                                                     \
            const unsigned short* a_ = pA + (kt_) * 64;                       \
            const unsigned short* b_ = pB + (kt_) * 64;                       \
            short* d_ = LDS + (buf_) * 32768;                                 \
            _Pragma("unroll")                                                 \
            for (int j_ = 0; j_ < 4; ++j_) {                                  \
                gload16(a_ + laneS[j_], d_ + dS[j_]);                         \
                gload16(b_ + laneS[j_], d_ + 16384 + dS[j_]);                 \
            }                                                                 \
        }

    // hoisted ds_read byte offsets (relative to buffer base)
    int offA[8][2], offB[4][2];
    #pragma unroll
    for (int mm = 0; mm < 8; ++mm) {
        const int ra = wm * 128 + mm * 16 + l15;
        const int sw = (ra & 7) << 4;
        offA[mm][0] = ra * 128 + ((l16 * 16) ^ sw);
        offA[mm][1] = ra * 128 + ((64 + l16 * 16) ^ sw);
    }
    #pragma unroll
    for (int nf = 0; nf < 4; ++nf) {
        const int rb = wn * 64 + nf * 16 + l15;
        const int sw = (rb & 7) << 4;
        offB[nf][0] = 32768 + rb * 128 + ((l16 * 16) ^ sw);
        offB[nf][1] = 32768 + rb * 128 + ((64 + l16 * 16) ^ sw);
    }

    // prologue: stage tile 0 into buffer 0
    STAGE(0, 0);
    __syncthreads();

    int buf = 0;
    for (int t = 0; t < nt; ++t) {
        // issue next-tile staging (async, other buffer)
        if (t + 1 < nt) STAGE(buf ^ 1, t + 1);

        const char* Lb = (const char*)LDS + buf * 65536;
        short8 aF[8][2], bF[4][2];
        #pragma unroll
        for (int mm = 0; mm < 8; ++mm) {
            aF[mm][0] = *(const short8*)(Lb + offA[mm][0]);
            aF[mm][1] = *(const short8*)(Lb + offA[mm][1]);
        }
        #pragma unroll
        for (int nf = 0; nf < 4; ++nf) {
            bF[nf][0] = *(const short8*)(Lb + offB[nf][0]);
            bF[nf][1] = *(const short8*)(Lb + offB[nf][1]);
        }
        #pragma unroll
        for (int kk = 0; kk < 2; ++kk)
            #pragma unroll
            for (int nf = 0; nf < 4; ++nf)
                #pragma unroll
                for (int mm = 0; mm < 8; ++mm)
                    acc[mm][nf] = __builtin_amdgcn_mfma_f32_16x16x32_bf16(
                        aF[mm][kk], bF[nf][kk], acc[mm][nf], 0, 0, 0);

        __syncthreads();   // drains staging (vmcnt0) + barrier; compiler
                           // fine-schedules the ds_read->MFMA interleave
        buf ^= 1;
    }
    #undef STAGE

    // ---- epilogue: C/D layout col = lane&15, row = (lane>>4)*4 + reg ----
    #pragma unroll
    for (int mf = 0; mf < 8; ++mf) {
        #pragma unroll
        for (int nf = 0; nf < 4; ++nf) {
            const int ng = n0 + wn * 64 + nf * 16 + l15;
            int nl = ng;
            const float* bp = bias0;
            void* Cp = C0;
            int Nout = N;
            if (SPLIT3) {
                const int which = ng / 768;
                nl = ng - which * 768;
                bp = (which == 0) ? bias0 : (which == 1) ? bias1 : bias2;
                Cp = (which == 0) ? C0 : (which == 1) ? C1 : C2;
                Nout = 768;
            }
            const float bs = bp[nl];
            #pragma unroll
            for (int r = 0; r < 4; ++r) {
                const int row = m0 + wm * 128 + mf * 16 + l16 * 4 + r;
                float v = acc[mf][nf][r] + bs;
                if (ACT) v = 0.5f * v * (1.f + erff(v * 0.70710678118654752f));
                if (OUTB) ((unsigned short*)Cp)[(size_t)row * Nout + nl] = f2b(v);
                else      ((float*)Cp)[(size_t)row * Nout + nl] = v;
            }
        }
    }
}

// ---------------------------------------------------------------------------
// 128x128 MFMA GEMM (r5 structure, proven): used for OUT-proj x2 and FFN2.
// ---------------------------------------------------------------------------
template<int OUTB, int ACT>
__global__ __launch_bounds__(256) void gemm128_kernel(
    const unsigned short* __restrict__ A,   // [M][K] bf16
    const unsigned short* __restrict__ BT,  // [N][K] bf16
    const float* __restrict__ bias,         // [N]
    void* __restrict__ Cout,
    int M, int N, int K)
{
    __shared__ short As[8192];   // 2 x [128][32] bf16
    __shared__ short Bs[8192];

    const int tid = threadIdx.x;
    const int m0 = blockIdx.y * 128;
    const int n0 = blockIdx.x * 128;
    const int w  = tid >> 6;
    const int l  = tid & 63;
    const int wr = w >> 1, wc = w & 1;
    const int l15 = l & 15, l16 = l >> 4;

    f32x4 acc[4][4];
    #pragma unroll
    for (int i = 0; i < 4; ++i)
        #pragma unroll
        for (int j = 0; j < 4; ++j)
            #pragma unroll
            for (int r = 0; r < 4; ++r) acc[i][j][r] = 0.f;

    const int sr = tid >> 2;
    const int sc = (tid & 3) << 3;
    const unsigned short* ga0 = A  + (size_t)(m0 + sr) * K + sc;
    const unsigned short* ga1 = A  + (size_t)(m0 + 64 + sr) * K + sc;
    const unsigned short* gb0 = BT + (size_t)(n0 + sr) * K + sc;
    const unsigned short* gb1 = BT + (size_t)(n0 + 64 + sr) * K + sc;
    short* lA = As + tid * 8;
    short* lB = Bs + tid * 8;

    const int aoff = (wr * 64 + l15) * 32 + l16 * 8;
    const int boff = (wc * 64 + l15) * 32 + l16 * 8;

    gload16(ga0, lA);
    gload16(ga1, lA + 2048);
    gload16(gb0, lB);
    gload16(gb1, lB + 2048);
    __syncthreads();

    int cur = 0;
    for (int k0 = 0; k0 < K; k0 += 32) {
        if (k0 + 32 < K) {
            const int nb = (cur ^ 1) << 12;
            gload16(ga0 + k0 + 32, lA + nb);
            gload16(ga1 + k0 + 32, lA + nb + 2048);
            gload16(gb0 + k0 + 32, lB + nb);
            gload16(gb1 + k0 + 32, lB + nb + 2048);
        }
        const int cb = cur << 12;
        short8 aF[4], bF[4];
        #pragma unroll
        for (int mf = 0; mf < 4; ++mf)
            aF[mf] = *(const short8*)(As + cb + aoff + mf * 512);
        #pragma unroll
        for (int nf = 0; nf < 4; ++nf)
            bF[nf] = *(const short8*)(Bs + cb + boff + nf * 512);
        #pragma unroll
        for (int mf = 0; mf < 4; ++mf)
            #pragma unroll
            for (int nf = 0; nf < 4; ++nf)
                acc[mf][nf] = __builtin_amdgcn_mfma_f32_16x16x32_bf16(
                    aF[mf], bF[nf], acc[mf][nf], 0, 0, 0);
        __syncthreads();
        cur ^= 1;
    }

    #pragma unroll
    for (int mf = 0; mf < 4; ++mf) {
        #pragma unroll
        for (int nf = 0; nf < 4; ++nf) {
            const int col = n0 + wc * 64 + nf * 16 + l15;
            const float bs = bias[col];
            #pragma unroll
            for (int r = 0; r < 4; ++r) {
                const int row = m0 + wr * 64 + mf * 16 + l16 * 4 + r;
                float v = acc[mf][nf][r] + bs;
                if (ACT) v = 0.5f * v * (1.f + erff(v * 0.70710678118654752f));
                if (OUTB) ((unsigned short*)Cout)[(size_t)row * N + col] = f2b(v);
                else      ((float*)Cout)[(size_t)row * N + col] = v;
            }
        }
    }
}

// ---------------------------------------------------------------------------
// weight prep: W[K][N] fp32 -> WT[N][K] bf16  (32x32 LDS tile transpose)
// ---------------------------------------------------------------------------
__global__ __launch_bounds__(256) void transpose_cast_kernel(
    const float* __restrict__ W, unsigned short* __restrict__ WT,
    int K, int N)
{
    __shared__ float t[32][33];
    const int k0 = blockIdx.y * 32;
    const int n0 = blockIdx.x * 32;
    const int tx = threadIdx.x & 31;
    const int ty4 = (threadIdx.x >> 5) << 2;
    #pragma unroll
    for (int i = 0; i < 4; ++i)
        t[ty4 + i][tx] = W[(size_t)(k0 + ty4 + i) * N + n0 + tx];
    __syncthreads();
    #pragma unroll
    for (int i = 0; i < 4; ++i)
        WT[(size_t)(n0 + ty4 + i) * K + k0 + tx] = f2b(t[tx][ty4 + i]);
}

// fused prep for the 8 E x E attention weights (grid.z selects weight)
struct TP8 { const float* src[8]; unsigned short* dst[8]; };
__global__ __launch_bounds__(256) void transpose_cast8_kernel(TP8 p)
{
    __shared__ float t[32][33];
    const int z = blockIdx.z;
    const float* W = p.src[z];
    unsigned short* WT = p.dst[z];
    const int k0 = blockIdx.y * 32;
    const int n0 = blockIdx.x * 32;
    const int tx = threadIdx.x & 31;
    const int ty4 = (threadIdx.x >> 5) << 2;
    #pragma unroll
    for (int i = 0; i < 4; ++i)
        t[ty4 + i][tx] = W[(size_t)(k0 + ty4 + i) * cE + n0 + tx];
    __syncthreads();
    #pragma unroll
    for (int i = 0; i < 4; ++i)
        WT[(size_t)(n0 + ty4 + i) * cE + k0 + tx] = f2b(t[tx][ty4 + i]);
}

// fp32 -> bf16 elementwise (n multiple of 4)
__global__ __launch_bounds__(256) void cast_bf16_kernel(
    const float* __restrict__ in, unsigned short* __restrict__ out, int n4)
{
    for (int i = blockIdx.x * blockDim.x + threadIdx.x; i < n4;
         i += gridDim.x * blockDim.x) {
        float4 v = ((const float4*)in)[i];
        u16x4 o;
        o[0] = f2b(v.x); o[1] = f2b(v.y); o[2] = f2b(v.z); o[3] = f2b(v.w);
        *(u16x4*)(out + (size_t)i * 4) = o;
    }
}

// ---------------------------------------------------------------------------
// residual + layernorm (r10 proven): out = LN(X + R) * gamma + beta;
// X fp32, R bf16. Writes fp32 residual/out + optional bf16 copy.
// NOTE: residual stream must stay fp32 (r13: bf16 residual -> absmax 0.165).
// ---------------------------------------------------------------------------
__global__ __launch_bounds__(256) void residual_ln_kernel(
    const float* __restrict__ X, const unsigned short* __restrict__ R,
    const float* __restrict__ gamma, const float* __restrict__ beta,
    float* __restrict__ out, unsigned short* __restrict__ outb)
{
    const int row = blockIdx.x;
    const size_t off = (size_t)row * cE;
    const int tid = threadIdx.x;

    float v[3];
    float s = 0.f, ss = 0.f;
    #pragma unroll
    for (int i = 0; i < 3; ++i) {
        const int e = tid + i * 256;
        const float t = X[off + e] + b2f(R[off + e]);
        v[i] = t; s += t; ss += t * t;
    }
    #pragma unroll
    for (int o = 32; o > 0; o >>= 1) {
        s  += __shfl_down(s, o);
        ss += __shfl_down(ss, o);
    }
    __shared__ float rs[4], rss[4];
    const int wid = tid >> 6;
    if ((tid & 63) == 0) { rs[wid] = s; rss[wid] = ss; }
    __syncthreads();
    s  = rs[0] + rs[1] + rs[2] + rs[3];
    ss = rss[0] + rss[1] + rss[2] + rss[3];

    const float mean = s * (1.f / cE);
    const float var  = ss * (1.f / cE) - mean * mean;
    const float inv  = rsqrtf(var + cEPS);
    #pragma unroll
    for (int i = 0; i < 3; ++i) {
        const int e = tid + i * 256;
        const float r = (v[i] - mean) * inv * gamma[e] + beta[e];
        out[off + e] = r;
        if (outb) outb[off + e] = f2b(r);
    }
}

// ---------------------------------------------------------------------------
// Spatial attention, MFMA flash version (verified round 4).
// ---------------------------------------------------------------------------
__global__ __launch_bounds__(256) void spatial_attn_mfma_kernel(
    const unsigned short* __restrict__ Q, const unsigned short* __restrict__ K,
    const unsigned short* __restrict__ V, unsigned short* __restrict__ O)
{
    __shared__ short Ks[64 * 64];      // [j][d] swizzled, row 128B
    __shared__ short Vt[64 * 64];      // [d][j] swizzled
    __shared__ short Ps[4][64 * 64];   // per-wave [q][j] swizzled

    const int bid = blockIdx.x;        // b*T*H + t*H + h
    const int h  = bid % cH;
    const int bt = bid / cH;
    const size_t base = (size_t)bt * cP * cE + h * cD;

    const int tid = threadIdx.x;
    const int w = tid >> 6, l = tid & 63;
    const int l15 = l & 15, l16 = l >> 4;

    short8 qf[4][2];
    #pragma unroll
    for (int mf = 0; mf < 4; ++mf)
        #pragma unroll
        for (int kf = 0; kf < 2; ++kf)
            qf[mf][kf] = *(const short8*)(
                Q + base + (size_t)(w * 64 + mf * 16 + l15) * cE + kf * 32 + l16 * 8);

    f32x4 o[4][4];
    float mrun[4][4], lrun[4][4];
    #pragma unroll
    for (int mf = 0; mf < 4; ++mf)
        #pragma unroll
        for (int j = 0; j < 4; ++j) {
            #pragma unroll
            for (int r = 0; r < 4; ++r) o[mf][j][r] = 0.f;
            mrun[mf][j] = -INFINITY; lrun[mf][j] = 0.f;
        }

    const int krow = w * 8 + (l >> 3);
    const int kc16 = l & 7;
    const int vj  = tid & 31;
    const int vd0 = (tid >> 5) * 8;

    for (int c0 = 0; c0 < cP; c0 += 64) {
        __syncthreads();
        #pragma unroll
        for (int p = 0; p < 2; ++p) {
            const int row = p * 32 + krow;
            gload16(K + base + (size_t)(c0 + row) * cE + ((kc16 ^ (row & 7)) << 3),
                    Ks + row * 64 + kc16 * 8);
        }
        #pragma unroll
        for (int p = 0; p < 2; ++p) {
            const int j = p * 32 + vj;
            short8 vv = *(const short8*)(V + base + (size_t)(c0 + j) * cE + vd0);
            char* vb = (char*)Vt;
            #pragma unroll
            for (int e = 0; e < 8; ++e) {
                const int row = vd0 + e;
                *(short*)(vb + row * 128 + ((2 * j) ^ ((row & 7) << 4))) = vv[e];
            }
        }
        __syncthreads();

        f32x4 s[4][4];
        #pragma unroll
        for (int mf = 0; mf < 4; ++mf)
            #pragma unroll
            for (int nf = 0; nf < 4; ++nf)
                #pragma unroll
                for (int r = 0; r < 4; ++r) s[mf][nf][r] = 0.f;

        #pragma unroll
        for (int nf = 0; nf < 4; ++nf) {
            const int row = nf * 16 + l15;
            const char* kb = (const char*)Ks + row * 128;
            const int sw = (row & 7) << 4;
            short8 k0 = *(const short8*)(kb + ((l16 * 16) ^ sw));
            short8 k1 = *(const short8*)(kb + ((64 + l16 * 16) ^ sw));
            #pragma unroll
            for (int mf = 0; mf < 4; ++mf) {
                s[mf][nf] = __builtin_amdgcn_mfma_f32_16x16x32_bf16(qf[mf][0], k0, s[mf][nf], 0, 0, 0);
                s[mf][nf] = __builtin_amdgcn_mfma_f32_16x16x32_bf16(qf[mf][1], k1, s[mf][nf], 0, 0, 0);
            }
        }

        #pragma unroll
        for (int mf = 0; mf < 4; ++mf)
            #pragma unroll
            for (int nf = 0; nf < 4; ++nf)
                #pragma unroll
                for (int r = 0; r < 4; ++r) s[mf][nf][r] *= cSCALE;

        #pragma unroll
        for (int mf = 0; mf < 4; ++mf) {
            #pragma unroll
            for (int r = 0; r < 4; ++r) {
                float rv = fmaxf(fmaxf(s[mf][0][r], s[mf][1][r]),
                                 fmaxf(s[mf][2][r], s[mf][3][r]));
                rv = fmaxf(rv, __shfl_xor(rv, 1));
                rv = fmaxf(rv, __shfl_xor(rv, 2));
                rv = fmaxf(rv, __shfl_xor(rv, 4));
                rv = fmaxf(rv, __shfl_xor(rv, 8));
                const float mn = fmaxf(mrun[mf][r], rv);
                const float al = __expf(mrun[mf][r] - mn);
                mrun[mf][r] = mn;
                float ps = 0.f;
                #pragma unroll
                for (int nf = 0; nf < 4; ++nf) {
                    const float pe = __expf(s[mf][nf][r] - mn);
                    s[mf][nf][r] = pe;
                    ps += pe;
                }
                ps += __shfl_xor(ps, 1);
                ps += __shfl_xor(ps, 2);
                ps += __shfl_xor(ps, 4);
                ps += __shfl_xor(ps, 8);
                lrun[mf][r] = lrun[mf][r] * al + ps;
                #pragma unroll
                for (int df = 0; df < 4; ++df) o[mf][df][r] *= al;
            }
        }

        char* pw = (char*)&Ps[w][0];
        #pragma unroll
        for (int mf = 0; mf < 4; ++mf)
            #pragma unroll
            for (int nf = 0; nf < 4; ++nf)
                #pragma unroll
                for (int r = 0; r < 4; ++r) {
                    const int row = mf * 16 + l16 * 4 + r;
                    *(short*)(pw + row * 128 + (((nf * 16 + l15) * 2) ^ ((row & 7) << 4))) =
                        (short)f2b(s[mf][nf][r]);
                }

        short8 pa[4][2];
        #pragma unroll
        for (int mf = 0; mf < 4; ++mf) {
            const int prow = mf * 16 + l15;
            const char* pb = (const char*)&Ps[w][0] + prow * 128;
            const int sw = (prow & 7) << 4;
            pa[mf][0] = *(const short8*)(pb + ((l16 * 16) ^ sw));
            pa[mf][1] = *(const short8*)(pb + ((64 + l16 * 16) ^ sw));
        }
        #pragma unroll
        for (int df = 0; df < 4; ++df) {
            const int vrow = df * 16 + l15;
            const char* vbb = (const char*)Vt + vrow * 128;
            const int sw = (vrow & 7) << 4;
            short8 v0 = *(const short8*)(vbb + ((l16 * 16) ^ sw));
            short8 v1 = *(const short8*)(vbb + ((64 + l16 * 16) ^ sw));
            #pragma unroll
            for (int mf = 0; mf < 4; ++mf) {
                o[mf][df] = __builtin_amdgcn_mfma_f32_16x16x32_bf16(pa[mf][0], v0, o[mf][df], 0, 0, 0);
                o[mf][df] = __builtin_amdgcn_mfma_f32_16x16x32_bf16(pa[mf][1], v1, o[mf][df], 0, 0, 0);
            }
        }
    }

    #pragma unroll
    for (int mf = 0; mf < 4; ++mf)
        #pragma unroll
        for (int r = 0; r < 4; ++r) {
            const float inv = 1.f / lrun[mf][r];
            const size_t rowoff = base + (size_t)(w * 64 + mf * 16 + l16 * 4 + r) * cE;
            #pragma unroll
            for (int df = 0; df < 4; ++df)
                O[rowoff + df * 16 + l15] = f2b(o[mf][df][r] * inv);
        }
}

// ---------------------------------------------------------------------------
// Temporal causal attention (bf16 I/O): per (b,p,head-group of 6). T=16.
// ---------------------------------------------------------------------------
__global__ __launch_bounds__(128) void temporal_attn_kernel(
    const unsigned short* __restrict__ Q, const unsigned short* __restrict__ Kb,
    const unsigned short* __restrict__ V, unsigned short* __restrict__ O)
{
    const int bid = blockIdx.x;          // (b*P + p)*2 + hg
    const int hg  = bid & 1;
    const int bp  = bid >> 1;
    const int p   = bp % cP;
    const int b   = bp / cP;

    __shared__ float Ks[cT][6][cD + 1];
    __shared__ float Vs[cT][6][cD + 1];

    const size_t framestride = (size_t)cP * cE;
    const size_t base0 = ((size_t)(b * cT) * cP + p) * cE + hg * 384;

    for (int li = threadIdx.x; li < cT * 384; li += 128) {
        const int s = li / 384;
        const int r = li % 384;
        const size_t src = base0 + (size_t)s * framestride + r;
        Ks[s][r / 64][r & 63] = b2f(Kb[src]);
        Vs[s][r / 64][r & 63] = b2f(V[src]);
    }
    __syncthreads();
    if (threadIdx.x >= 96) return;

    const int hh = threadIdx.x >> 4;
    const int t  = threadIdx.x & 15;
    const size_t qoff = ((size_t)(b * cT + t) * cP + p) * cE + hg * 384 + hh * cD;

    float q[cD];
    #pragma unroll
    for (int d = 0; d < cD; d += 8) {
        short8 f = *(const short8*)(Q + qoff + d);
        #pragma unroll
        for (int j = 0; j < 8; ++j) q[d + j] = b2f((unsigned short)f[j]);
    }

    float sc[cT];
    float mx = -INFINITY;
    #pragma unroll
    for (int s = 0; s < cT; ++s) {
        float acc = 0.f;
        #pragma unroll
        for (int d = 0; d < cD; ++d) acc = fmaf(q[d], Ks[s][hh][d], acc);
        sc[s] = (s <= t) ? acc * cSCALE : -INFINITY;
        mx = fmaxf(mx, sc[s]);
    }
    float l = 0.f;
    #pragma unroll
    for (int s = 0; s < cT; ++s) {
        const float e_ = __expf(sc[s] - mx);
        sc[s] = e_;
        l += e_;
    }
    float o[cD];
    #pragma unroll
    for (int d = 0; d < cD; ++d) o[d] = 0.f;
    #pragma unroll
    for (int s = 0; s < cT; ++s) {
        const float pj = sc[s];
        #pragma unroll
        for (int d = 0; d < cD; ++d) o[d] = fmaf(pj, Vs[s][hh][d], o[d]);
    }
    const float invl = 1.f / l;
    unsigned short* op = O + qoff;
    #pragma unroll
    for (int d = 0; d < cD; d += 8) {
        u16x8 f;
        #pragma unroll
        for (int j = 0; j < 8; ++j) f[j] = f2b(o[d + j] * invl);
        *(u16x8*)(op + d) = f;
    }
}

// ---------------------------------------------------------------------------
extern "C" void kernel_launch(void* const* d_in, const int* in_sizes, int n_in,
                              void* d_out, int out_size, void* d_ws, size_t ws_size,
                              hipStream_t stream)
{
    const float* x    = (const float*)d_in[0];
    const float* sq_w = (const float*)d_in[1];
    const float* sk_w = (const float*)d_in[2];
    const float* sv_w = (const float*)d_in[3];
    const float* so_w = (const float*)d_in[4];
    const float* sq_b = (const float*)d_in[5];
    const float* sk_b = (const float*)d_in[6];
    const float* sv_b = (const float*)d_in[7];
    const float* so_b = (const float*)d_in[8];
    const float* sg   = (const float*)d_in[9];
    const float* sb   = (const float*)d_in[10];
    const float* tq_w = (const float*)d_in[11];
    const float* tk_w = (const float*)d_in[12];
    const float* tv_w = (const float*)d_in[13];
    const float* to_w = (const float*)d_in[14];
    const float* tq_b = (const float*)d_in[15];
    const float* tk_b = (const float*)d_in[16];
    const float* tv_b = (const float*)d_in[17];
    const float* to_b = (const float*)d_in[18];
    const float* tg   = (const float*)d_in[19];
    const float* tb   = (const float*)d_in[20];
    const float* w1   = (const float*)d_in[21];
    const float* b1   = (const float*)d_in[22];
    const float* w2   = (const float*)d_in[23];
    const float* b2   = (const float*)d_in[24];
    const float* g    = (const float*)d_in[25];
    const float* bb   = (const float*)d_in[26];

    const size_t NE = (size_t)NTOK * cE;   // 12.58M elements
    const size_t EE = (size_t)cE * cE;     // 589824

    // workspace layout (~245 MB)
    float* W0 = (float*)d_ws;                    // fp32 residual stream [NE]
    float* Wp = W0 + NE;                         // region reused as bf16 R [NE]
    unsigned short* Rb = (unsigned short*)Wp;    // bf16 projection/FFN output
    unsigned short* Xb = (unsigned short*)(Wp + NE);  // bf16 x_cur [NE]
    unsigned short* Qb = Xb + NE;
    unsigned short* Kbuf = Qb + NE;
    unsigned short* Vb = Kbuf + NE;
    unsigned short* Ob = Vb + NE;
    unsigned short* Hb = Qb;                     // bf16 hidden overlays Qb..Ob
    unsigned short* WT = Ob + NE;                // bf16 transposed weights
    unsigned short* sqT = WT;                    // [sq;sk;sv] contiguous
    unsigned short* skT = sqT + EE;
    unsigned short* svT = skT + EE;
    unsigned short* soT = svT + EE;
    unsigned short* tqT = soT + EE;
    unsigned short* tkT = tqT + EE;
    unsigned short* tvT = tkT + EE;
    unsigned short* toT = tvT + EE;
    unsigned short* w1T = toT + EE;              // [DFF][E]
    unsigned short* w2T = w1T + (size_t)cDFF * cE;  // [E][DFF]

    const dim3 blk(256);
    const dim3 blk512(512);
    const dim3 gLN(NTOK);
    const dim3 gQKV(576);                    // 64 M-blocks * 9 N-blocks (256x256)
    const dim3 gFF1(768);                    // 64 * 12 (256x256)
    const dim3 g128(cE / 128, NTOK / 128);   // (6, 128) = 768 blocks (128x128)

    // ---- prep: cast x, transpose+cast all weights to bf16 [N][K] ----
    cast_bf16_kernel<<<dim3(2048), blk, 0, stream>>>(x, Xb, (int)(NE / 4));
    {
        TP8 p;
        p.src[0] = sq_w; p.dst[0] = sqT;
        p.src[1] = sk_w; p.dst[1] = skT;
        p.src[2] = sv_w; p.dst[2] = svT;
        p.src[3] = so_w; p.dst[3] = soT;
        p.src[4] = tq_w; p.dst[4] = tqT;
        p.src[5] = tk_w; p.dst[5] = tkT;
        p.src[6] = tv_w; p.dst[6] = tvT;
        p.src[7] = to_w; p.dst[7] = toT;
        transpose_cast8_kernel<<<dim3(cE / 32, cE / 32, 8), blk, 0, stream>>>(p);
    }
    transpose_cast_kernel<<<dim3(cDFF / 32, cE / 32), blk, 0, stream>>>(w1, w1T, cE, cDFF);
    transpose_cast_kernel<<<dim3(cE / 32, cDFF / 32), blk, 0, stream>>>(w2, w2T, cDFF, cE);

    // ---- Spatial attention block ----
    gemm256w_kernel<1,0,1><<<gQKV, blk512, 0, stream>>>(
        Xb, sqT, sq_b, sk_b, sv_b, Qb, Kbuf, Vb, NTOK, 2304, cE, 9);
    spatial_attn_mfma_kernel<<<dim3(cB * cT * cH), blk, 0, stream>>>(Qb, Kbuf, Vb, Ob);
    gemm128_kernel<1,0><<<g128, blk, 0, stream>>>(Ob, soT, so_b, Rb, NTOK, cE, cE);
    residual_ln_kernel<<<gLN, blk, 0, stream>>>(x, Rb, sg, sb, W0, Xb);

    // ---- Temporal attention block ----
    gemm256w_kernel<1,0,1><<<gQKV, blk512, 0, stream>>>(
        Xb, tqT, tq_b, tk_b, tv_b, Qb, Kbuf, Vb, NTOK, 2304, cE, 9);
    temporal_attn_kernel<<<dim3(cB * cP * 2), dim3(128), 0, stream>>>(Qb, Kbuf, Vb, Ob);
    gemm128_kernel<1,0><<<g128, blk, 0, stream>>>(Ob, toT, to_b, Rb, NTOK, cE, cE);
    residual_ln_kernel<<<gLN, blk, 0, stream>>>(W0, Rb, tg, tb, W0, Xb);

    // ---- FFN ----
    gemm256w_kernel<1,1,0><<<gFF1, blk512, 0, stream>>>(
        Xb, w1T, b1, nullptr, nullptr, Hb, nullptr, nullptr, NTOK, cDFF, cE, 12);
    gemm128_kernel<1,0><<<g128, blk, 0, stream>>>(Hb, w2T, b2, Rb, NTOK, cE, cDFF);
    residual_ln_kernel<<<gLN, blk, 0, stream>>>(W0, Rb, g, bb, (float*)d_out, nullptr);
}